// Round 1
// baseline (4109.783 us; speedup 1.0000x reference)
//
#include <hip/hip_runtime.h>
#include <cstdint>
#include <cstddef>

#define L_SEQ 4096
#define H_DIM 256
#define N_MODES 64
#define BATCH 16

// ---------------------------------------------------------------------------
// Mode precompute: w = exp(dt*A), c2 = 2*C*(w-1)/A   for all NL*H*N modes
// ---------------------------------------------------------------------------
__global__ __launch_bounds__(256) void precompute_modes(
    const float* __restrict__ log_dt,   // [NL][H]
    const float* __restrict__ A_re_log, // [NL][H][N]
    const float* __restrict__ A_im,     // [NL][H][N]
    const float* __restrict__ C_re,     // [NL][H][N]
    const float* __restrict__ C_im,     // [NL][H][N]
    float* __restrict__ wr_, float* __restrict__ wi_,
    float* __restrict__ cr_, float* __restrict__ ci_)
{
    int i = blockIdx.x * 256 + threadIdx.x;       // NL*H*N = 65536
    if (i >= 4 * H_DIM * N_MODES) return;
    int lh = i / N_MODES;
    float dt = expf(log_dt[lh]);
    float Ar = -expf(A_re_log[i]);
    float Ai = A_im[i];
    float dr = Ar * dt, di = Ai * dt;
    float er = expf(dr);
    float wr = er * cosf(di), wi = er * sinf(di);
    float nr = wr - 1.f, ni = wi;                 // exp(dtA) - 1
    float Cr = C_re[i], Ci = C_im[i];
    float pr = Cr * nr - Ci * ni;
    float pi = Cr * ni + Ci * nr;
    float inv = 1.f / (Ar * Ar + Ai * Ai);
    float cr = (pr * Ar + pi * Ai) * inv;         // p / A  via conj(A)/|A|^2
    float ci = (pi * Ar - pr * Ai) * inv;
    wr_[i] = wr; wi_[i] = wi;
    cr_[i] = 2.f * cr; ci_[i] = 2.f * ci;
}

// ---------------------------------------------------------------------------
// Encoder: conv1d('same') + BN(eval) + ReLU, 4 output channels per block
// ---------------------------------------------------------------------------
template<int CI, int K>
__global__ __launch_bounds__(256) void conv_bn_relu(
    const float* __restrict__ in,   // [B][CI][L]
    float* __restrict__ out,        // [B][CO][L]
    const float* __restrict__ w,    // [CO][CI][K]
    const float* __restrict__ cb, const float* __restrict__ g,
    const float* __restrict__ bb, const float* __restrict__ m,
    const float* __restrict__ v, int CO)
{
    __shared__ float wl[4 * CI * K];
    __shared__ float sc[4], sh[4];
    const int co0 = blockIdx.y * 4, b = blockIdx.z;
    const int l = blockIdx.x * 256 + threadIdx.x;
    for (int e = threadIdx.x; e < 4 * CI * K; e += 256)
        wl[e] = w[co0 * CI * K + e];
    if (threadIdx.x < 4) {
        int co = co0 + threadIdx.x;
        float s = g[co] * rsqrtf(v[co] + 1e-5f);
        sc[threadIdx.x] = s;
        sh[threadIdx.x] = (cb[co] - m[co]) * s + bb[co];
    }
    __syncthreads();
    float a0 = 0.f, a1 = 0.f, a2 = 0.f, a3 = 0.f;
    const float* inb = in + (size_t)b * CI * L_SEQ;
    const int OFF = K / 2;
    for (int ci = 0; ci < CI; ++ci) {
        const float* row = inb + (size_t)ci * L_SEQ;
        const float* wrow = &wl[ci * K];
        #pragma unroll
        for (int k = 0; k < K; ++k) {
            int li = l + k - OFF;
            float xv = (li >= 0 && li < L_SEQ) ? row[li] : 0.f;
            a0 = fmaf(xv, wrow[0 * CI * K + k], a0);
            a1 = fmaf(xv, wrow[1 * CI * K + k], a1);
            a2 = fmaf(xv, wrow[2 * CI * K + k], a2);
            a3 = fmaf(xv, wrow[3 * CI * K + k], a3);
        }
    }
    float accs[4] = {a0, a1, a2, a3};
    #pragma unroll
    for (int t = 0; t < 4; ++t) {
        float r = fmaf(accs[t], sc[t], sh[t]);
        out[((size_t)b * CO + co0 + t) * L_SEQ + l] = fmaxf(r, 0.f);
    }
}

// ---------------------------------------------------------------------------
// S4D scan: one wave per (b,h), lane = mode. LDS-transposed contribution sums.
// Epilogue: + D*u, tanh-GELU.
// ---------------------------------------------------------------------------
__global__ __launch_bounds__(128) void s4d_scan(
    const float* __restrict__ u,    // [B][H][L]
    const float* __restrict__ wre, const float* __restrict__ wim,
    const float* __restrict__ c2r, const float* __restrict__ c2i, // [H][N]
    const float* __restrict__ Dv,   // [H]
    float* __restrict__ y)          // [B][H][L]
{
    __shared__ float cmat[2][64][65];
    const int wave = threadIdx.x >> 6;
    const int lane = threadIdx.x & 63;
    const int bh = blockIdx.x * 2 + wave;   // = b*256 + h
    const int h = bh & (H_DIM - 1);
    const float wr = wre[h * 64 + lane], wi = wim[h * 64 + lane];
    const float nwi = -wi;
    const float cr = c2r[h * 64 + lane];
    const float nci = -c2i[h * 64 + lane];
    const float Dh = Dv[h];
    const float* urow = u + (size_t)bh * L_SEQ;
    float* yrow = y + (size_t)bh * L_SEQ;
    float sr = 0.f, si = 0.f;
    for (int l0 = 0; l0 < L_SEQ; l0 += 64) {
        float uv = urow[l0 + lane];
        #pragma unroll
        for (int j = 0; j < 64; ++j) {
            float uj = __shfl(uv, j);
            float t = fmaf(nwi, si, uj);
            float nsr = fmaf(wr, sr, t);
            float nsi = fmaf(wr, si, wi * sr);
            sr = nsr; si = nsi;
            cmat[wave][j][lane] = fmaf(nci, si, cr * sr);
        }
        __syncthreads();
        float acc = 0.f;
        #pragma unroll
        for (int n = 0; n < 64; ++n) acc += cmat[wave][lane][n];
        __syncthreads();
        float yv = fmaf(Dh, uv, acc);
        // tanh-approx GELU (jax.nn.gelu default approximate=True)
        float yc = fmaf(0.044715f * yv, yv * yv, yv);
        float tg = tanhf(0.79788456f * yc);
        yrow[l0 + lane] = 0.5f * yv * (1.f + tg);
    }
}

// ---------------------------------------------------------------------------
// Output linear (H->2H) + GLU + residual, fused.  z never materialized.
// Block: 64 l x 64 o (both GLU halves), fp32 register tiling 4x4 (x2 halves).
// ---------------------------------------------------------------------------
__global__ __launch_bounds__(256) void linear_glu(
    const float* __restrict__ y,    // [B][256][L]
    const float* __restrict__ W,    // [512][256]
    const float* __restrict__ bias, // [512]
    const float* __restrict__ x,    // [B][256][L] residual in
    float* __restrict__ vout)       // [B][256][L]
{
    __shared__ float ws1[16][68], ws2[16][68], ys[16][68];
    const int tx = threadIdx.x & 15;
    const int ty = threadIdx.x >> 4;
    const int l0 = blockIdx.x * 64, o0 = blockIdx.y * 64, b = blockIdx.z;
    const float* yb = y + (size_t)b * H_DIM * L_SEQ;
    float acc1[4][4] = {}, acc2[4][4] = {};
    for (int kk = 0; kk < 256; kk += 16) {
        for (int e = threadIdx.x; e < 1024; e += 256) {
            int i = e >> 4, j = e & 15;
            ws1[j][i] = W[(size_t)(o0 + i) * 256 + kk + j];
            ws2[j][i] = W[(size_t)(o0 + 256 + i) * 256 + kk + j];
        }
        for (int e = threadIdx.x; e < 1024; e += 256) {
            int j = e >> 6, i = e & 63;
            ys[j][i] = yb[(size_t)(kk + j) * L_SEQ + l0 + i];
        }
        __syncthreads();
        #pragma unroll
        for (int j = 0; j < 16; ++j) {
            float w1[4], w2[4], yv[4];
            #pragma unroll
            for (int a = 0; a < 4; ++a) { w1[a] = ws1[j][ty * 4 + a]; w2[a] = ws2[j][ty * 4 + a]; }
            #pragma unroll
            for (int c = 0; c < 4; ++c) yv[c] = ys[j][tx * 4 + c];
            #pragma unroll
            for (int a = 0; a < 4; ++a)
                #pragma unroll
                for (int c = 0; c < 4; ++c) {
                    acc1[a][c] = fmaf(w1[a], yv[c], acc1[a][c]);
                    acc2[a][c] = fmaf(w2[a], yv[c], acc2[a][c]);
                }
        }
        __syncthreads();
    }
    #pragma unroll
    for (int a = 0; a < 4; ++a) {
        int o = o0 + ty * 4 + a;
        float b1 = bias[o], b2 = bias[o + 256];
        #pragma unroll
        for (int c = 0; c < 4; ++c) {
            float z1 = acc1[a][c] + b1;
            float z2 = acc2[a][c] + b2;
            size_t idx = ((size_t)b * H_DIM + o) * L_SEQ + l0 + tx * 4 + c;
            float glu = z1 / (1.f + expf(-z2));
            vout[idx] = glu + x[idx];
        }
    }
}

// ---------------------------------------------------------------------------
// LayerNorm over channel dim (per (b,l)), reads v, writes x.
// ---------------------------------------------------------------------------
__global__ __launch_bounds__(256) void ln_ch(
    const float* __restrict__ vin,  // [B][256][L]
    float* __restrict__ x,          // [B][256][L]
    const float* __restrict__ lg, const float* __restrict__ lb)
{
    const int b = blockIdx.y;
    const int l = blockIdx.x * 256 + threadIdx.x;
    const float* vb = vin + (size_t)b * H_DIM * L_SEQ + l;
    float* xb = x + (size_t)b * H_DIM * L_SEQ + l;
    float sum = 0.f, sq = 0.f;
    for (int h = 0; h < H_DIM; ++h) {
        float vv = vb[(size_t)h * L_SEQ];
        sum += vv;
        sq = fmaf(vv, vv, sq);
    }
    float mean = sum * (1.f / H_DIM);
    float var = sq * (1.f / H_DIM) - mean * mean;
    float rstd = rsqrtf(var + 1e-5f);
    for (int h = 0; h < H_DIM; ++h) {
        float vv = vb[(size_t)h * L_SEQ];
        xb[(size_t)h * L_SEQ] = (vv - mean) * rstd * lg[h] + lb[h];
    }
}

// ---------------------------------------------------------------------------
// Mean over time per (b,h); then tiny decode.
// ---------------------------------------------------------------------------
__global__ __launch_bounds__(256) void pool_mean(
    const float* __restrict__ x, float* __restrict__ meanb)
{
    __shared__ float red[256];
    const int bh = blockIdx.x;
    const float* row = x + (size_t)bh * L_SEQ;
    float s = 0.f;
    for (int i = threadIdx.x; i < L_SEQ; i += 256) s += row[i];
    red[threadIdx.x] = s;
    __syncthreads();
    for (int st = 128; st > 0; st >>= 1) {
        if (threadIdx.x < st) red[threadIdx.x] += red[threadIdx.x + st];
        __syncthreads();
    }
    if (threadIdx.x == 0) meanb[bh] = red[0] * (1.f / L_SEQ);
}

__global__ __launch_bounds__(256) void decode(
    const float* __restrict__ meanb, const float* __restrict__ dw,
    const float* __restrict__ db, float* __restrict__ out)
{
    int i = threadIdx.x;
    if (i >= BATCH * 10) return;
    int b = i / 10, d = i % 10;
    float s = db[d];
    for (int h = 0; h < H_DIM; ++h)
        s = fmaf(meanb[b * H_DIM + h], dw[d * H_DIM + h], s);
    out[i] = s;
}

// ---------------------------------------------------------------------------
extern "C" void kernel_launch(void* const* d_in, const int* in_sizes, int n_in,
                              void* d_out, int out_size, void* d_ws, size_t ws_size,
                              hipStream_t stream)
{
    const float* x_in = (const float*)d_in[0];
    const float* cw[3] = {(const float*)d_in[1], (const float*)d_in[7],  (const float*)d_in[13]};
    const float* cb[3] = {(const float*)d_in[2], (const float*)d_in[8],  (const float*)d_in[14]};
    const float* bg[3] = {(const float*)d_in[3], (const float*)d_in[9],  (const float*)d_in[15]};
    const float* bb[3] = {(const float*)d_in[4], (const float*)d_in[10], (const float*)d_in[16]};
    const float* bm[3] = {(const float*)d_in[5], (const float*)d_in[11], (const float*)d_in[17]};
    const float* bv[3] = {(const float*)d_in[6], (const float*)d_in[12], (const float*)d_in[18]};
    const float* log_dt   = (const float*)d_in[19];
    const float* A_re_log = (const float*)d_in[20];
    const float* A_im     = (const float*)d_in[21];
    const float* C_re     = (const float*)d_in[22];
    const float* C_im     = (const float*)d_in[23];
    const float* Dv       = (const float*)d_in[24];
    const float* out_w    = (const float*)d_in[25];
    const float* out_b    = (const float*)d_in[26];
    const float* ln_g     = (const float*)d_in[27];
    const float* ln_b     = (const float*)d_in[28];
    const float* dec_w    = (const float*)d_in[29];
    const float* dec_b    = (const float*)d_in[30];

    const size_t PLANE = (size_t)BATCH * H_DIM * L_SEQ;  // 16777216 floats
    float* ws   = (float*)d_ws;
    float* xbuf = ws;
    float* ybuf = ws + PLANE;
    float* vbuf = ws + 2 * PLANE;
    float* mwr  = ws + 3 * PLANE;
    float* mwi  = mwr + 4 * H_DIM * N_MODES;
    float* mcr  = mwi + 4 * H_DIM * N_MODES;
    float* mci  = mcr + 4 * H_DIM * N_MODES;
    float* meanb = mci + 4 * H_DIM * N_MODES;

    precompute_modes<<<dim3(256), dim3(256), 0, stream>>>(
        log_dt, A_re_log, A_im, C_re, C_im, mwr, mwi, mcr, mci);

    // Encoder: x_in [16,1,L] -> ybuf [16,64,L] -> vbuf [16,128,L] -> xbuf [16,256,L]
    conv_bn_relu<1, 7><<<dim3(16, 16, 16), 256, 0, stream>>>(
        x_in, ybuf, cw[0], cb[0], bg[0], bb[0], bm[0], bv[0], 64);
    conv_bn_relu<64, 5><<<dim3(16, 32, 16), 256, 0, stream>>>(
        ybuf, vbuf, cw[1], cb[1], bg[1], bb[1], bm[1], bv[1], 128);
    conv_bn_relu<128, 3><<<dim3(16, 64, 16), 256, 0, stream>>>(
        vbuf, xbuf, cw[2], cb[2], bg[2], bb[2], bm[2], bv[2], 256);

    for (int l = 0; l < 4; ++l) {
        const int moff = l * H_DIM * N_MODES;
        s4d_scan<<<dim3(BATCH * H_DIM / 2), dim3(128), 0, stream>>>(
            xbuf, mwr + moff, mwi + moff, mcr + moff, mci + moff,
            Dv + l * H_DIM, ybuf);
        linear_glu<<<dim3(64, 4, 16), dim3(256), 0, stream>>>(
            ybuf, out_w + (size_t)l * 512 * H_DIM, out_b + l * 512, xbuf, vbuf);
        ln_ch<<<dim3(16, 16), dim3(256), 0, stream>>>(
            vbuf, xbuf, ln_g + l * H_DIM, ln_b + l * H_DIM);
    }

    pool_mean<<<dim3(BATCH * H_DIM), dim3(256), 0, stream>>>(xbuf, meanb);
    decode<<<dim3(1), dim3(256), 0, stream>>>(meanb, dec_w, dec_b, (float*)d_out);
}

// Round 2
// 2808.703 us; speedup vs baseline: 1.4632x; 1.4632x over previous
//
#include <hip/hip_runtime.h>
#include <cstdint>
#include <cstddef>

#define L_SEQ 4096
#define H_DIM 256
#define N_MODES 64
#define BATCH 16
#define NCHUNK 8
#define TCHUNK 512

typedef __attribute__((ext_vector_type(8))) short short8v;
typedef __attribute__((ext_vector_type(16))) float f32x16;

__device__ __forceinline__ unsigned short f2bf(float f) {
    unsigned u = __float_as_uint(f);
    u = u + 0x7fff + ((u >> 16) & 1);
    return (unsigned short)(u >> 16);
}
__device__ __forceinline__ float bf2f(unsigned short h) {
    return __uint_as_float(((unsigned)h) << 16);
}
__device__ __forceinline__ float rdlane(float v, int j) {
    return __uint_as_float(__builtin_amdgcn_readlane(__float_as_uint(v), j));
}

// ---------------------------------------------------------------------------
// Mode precompute: w = exp(dt*A), c2 = 2*C*(w-1)/A, wT = w^512
// ---------------------------------------------------------------------------
__global__ __launch_bounds__(256) void precompute_modes(
    const float* __restrict__ log_dt, const float* __restrict__ A_re_log,
    const float* __restrict__ A_im, const float* __restrict__ C_re,
    const float* __restrict__ C_im,
    float* __restrict__ wr_, float* __restrict__ wi_,
    float* __restrict__ cr_, float* __restrict__ ci_,
    float* __restrict__ wTr_, float* __restrict__ wTi_)
{
    int i = blockIdx.x * 256 + threadIdx.x;       // NL*H*N = 65536
    if (i >= 4 * H_DIM * N_MODES) return;
    int lh = i / N_MODES;
    float dt = expf(log_dt[lh]);
    float Ar = -expf(A_re_log[i]);
    float Ai = A_im[i];
    float dr = Ar * dt, di = Ai * dt;
    float er = expf(dr);
    float wr = er * cosf(di), wi = er * sinf(di);
    float nr = wr - 1.f, ni = wi;
    float Cr = C_re[i], Ci = C_im[i];
    float pr = Cr * nr - Ci * ni;
    float pi = Cr * ni + Ci * nr;
    float inv = 1.f / (Ar * Ar + Ai * Ai);
    float cr = (pr * Ar + pi * Ai) * inv;
    float ci = (pi * Ar - pr * Ai) * inv;
    wr_[i] = wr; wi_[i] = wi;
    cr_[i] = 2.f * cr; ci_[i] = 2.f * ci;
    // w^T = exp(dtA * 512)
    float er5 = expf(dr * (float)TCHUNK);
    float an5 = di * (float)TCHUNK;
    wTr_[i] = er5 * cosf(an5);
    wTi_[i] = er5 * sinf(an5);
}

// W -> bf16 hi/lo split
__global__ __launch_bounds__(256) void precompute_wbf(
    const float* __restrict__ W, unsigned short* __restrict__ hi,
    unsigned short* __restrict__ lo)
{
    int i = blockIdx.x * 256 + threadIdx.x;
    if (i >= 4 * 512 * H_DIM) return;
    float f = W[i];
    unsigned short h = f2bf(f);
    hi[i] = h;
    lo[i] = f2bf(f - bf2f(h));
}

// ---------------------------------------------------------------------------
// Encoder: conv1d('same') + BN(eval) + ReLU
// ---------------------------------------------------------------------------
template<int CI, int K>
__global__ __launch_bounds__(256) void conv_bn_relu(
    const float* __restrict__ in, float* __restrict__ out,
    const float* __restrict__ w, const float* __restrict__ cb,
    const float* __restrict__ g, const float* __restrict__ bb,
    const float* __restrict__ m, const float* __restrict__ v, int CO)
{
    __shared__ float wl[4 * CI * K];
    __shared__ float sc[4], sh[4];
    const int co0 = blockIdx.y * 4, b = blockIdx.z;
    const int l = blockIdx.x * 256 + threadIdx.x;
    for (int e = threadIdx.x; e < 4 * CI * K; e += 256)
        wl[e] = w[co0 * CI * K + e];
    if (threadIdx.x < 4) {
        int co = co0 + threadIdx.x;
        float s = g[co] * rsqrtf(v[co] + 1e-5f);
        sc[threadIdx.x] = s;
        sh[threadIdx.x] = (cb[co] - m[co]) * s + bb[co];
    }
    __syncthreads();
    float a0 = 0.f, a1 = 0.f, a2 = 0.f, a3 = 0.f;
    const float* inb = in + (size_t)b * CI * L_SEQ;
    const int OFF = K / 2;
    for (int ci = 0; ci < CI; ++ci) {
        const float* row = inb + (size_t)ci * L_SEQ;
        const float* wrow = &wl[ci * K];
        #pragma unroll
        for (int k = 0; k < K; ++k) {
            int li = l + k - OFF;
            float xv = (li >= 0 && li < L_SEQ) ? row[li] : 0.f;
            a0 = fmaf(xv, wrow[0 * CI * K + k], a0);
            a1 = fmaf(xv, wrow[1 * CI * K + k], a1);
            a2 = fmaf(xv, wrow[2 * CI * K + k], a2);
            a3 = fmaf(xv, wrow[3 * CI * K + k], a3);
        }
    }
    float accs[4] = {a0, a1, a2, a3};
    #pragma unroll
    for (int t = 0; t < 4; ++t) {
        float r = fmaf(accs[t], sc[t], sh[t]);
        out[((size_t)b * CO + co0 + t) * L_SEQ + l] = fmaxf(r, 0.f);
    }
}

// ---------------------------------------------------------------------------
// S4D phase A: chunk-local end states (chunks 0..6 only). wave=(bh,chunk).
// ---------------------------------------------------------------------------
__global__ __launch_bounds__(256) void s4d_state(
    const float* __restrict__ u,
    const float* __restrict__ wre, const float* __restrict__ wim,
    float* __restrict__ AR, float* __restrict__ AI)
{
    const int W = blockIdx.x * 4 + (threadIdx.x >> 6);
    const int lane = threadIdx.x & 63;
    const int bh = W / 7;
    const int c = W - bh * 7;
    const int h = bh & (H_DIM - 1);
    const float wr = wre[h * 64 + lane], wi = wim[h * 64 + lane];
    const float* urow = u + (size_t)bh * L_SEQ + c * TCHUNK;
    float sr = 0.f, si = 0.f;
    float uv = urow[lane];
    for (int l0 = 0; l0 < TCHUNK; l0 += 64) {
        float uvn = (l0 + 64 < TCHUNK) ? urow[l0 + 64 + lane] : 0.f;
        #pragma unroll
        for (int j = 0; j < 64; ++j) {
            float uj = rdlane(uv, j);
            float mm = wi * sr;
            float tmp = fmaf(-wi, si, uj);
            sr = fmaf(wr, sr, tmp);
            si = fmaf(wr, si, mm);
        }
        uv = uvn;
    }
    size_t base = ((size_t)bh * NCHUNK + c) * 64 + lane;
    AR[base] = sr; AI[base] = si;
}

// ---------------------------------------------------------------------------
// S4D combine: in-place; slot k becomes carry-in state for chunk k+1.
// ---------------------------------------------------------------------------
__global__ __launch_bounds__(256) void s4d_combine(
    const float* __restrict__ wTr, const float* __restrict__ wTi,
    float* __restrict__ AR, float* __restrict__ AI)
{
    const int bh = blockIdx.x * 4 + (threadIdx.x >> 6);
    const int lane = threadIdx.x & 63;
    const int h = bh & (H_DIM - 1);
    const float tr = wTr[h * 64 + lane], ti = wTi[h * 64 + lane];
    float Sr = 0.f, Si = 0.f;
    for (int k = 0; k < 7; ++k) {
        size_t base = ((size_t)bh * NCHUNK + k) * 64 + lane;
        float ar = AR[base], ai = AI[base];
        float nr = fmaf(tr, Sr, fmaf(-ti, Si, ar));
        float ni = fmaf(tr, Si, fmaf(ti, Sr, ai));
        AR[base] = nr; AI[base] = ni;
        Sr = nr; Si = ni;
    }
}

// ---------------------------------------------------------------------------
// S4D phase B: output scan per (bh,chunk); 16-step wave-private LDS tiles.
// Epilogue: + D*u, tanh-GELU. No __syncthreads.
// ---------------------------------------------------------------------------
__global__ __launch_bounds__(256) void s4d_scan2(
    const float* __restrict__ u,
    const float* __restrict__ wre, const float* __restrict__ wim,
    const float* __restrict__ c2r, const float* __restrict__ c2i,
    const float* __restrict__ Dv,
    const float* __restrict__ AR, const float* __restrict__ AI,
    float* __restrict__ y)
{
    __shared__ float cmat[4][16][69];
    const int wv = threadIdx.x >> 6;
    const int lane = threadIdx.x & 63;
    const int W = blockIdx.x * 4 + wv;
    const int bh = W >> 3;
    const int c = W & 7;
    const int h = bh & (H_DIM - 1);
    const float wr = wre[h * 64 + lane], wi = wim[h * 64 + lane];
    const float cr = c2r[h * 64 + lane];
    const float nci = -c2i[h * 64 + lane];
    const float Dh = Dv[h];
    const int r = lane & 15, q = lane >> 4;
    float sr = 0.f, si = 0.f;
    if (c > 0) {
        size_t base = ((size_t)bh * NCHUNK + c - 1) * 64 + lane;
        sr = AR[base]; si = AI[base];
    }
    const float* urow = u + (size_t)bh * L_SEQ + c * TCHUNK;
    float* yrow = y + (size_t)bh * L_SEQ + c * TCHUNK;
    float uv = urow[lane];
    for (int l0 = 0; l0 < TCHUNK; l0 += 64) {
        float uvn = (l0 + 64 < TCHUNK) ? urow[l0 + 64 + lane] : 0.f;
        #pragma unroll
        for (int jt = 0; jt < 4; ++jt) {
            #pragma unroll
            for (int j16 = 0; j16 < 16; ++j16) {
                float uj = rdlane(uv, jt * 16 + j16);
                float mm = wi * sr;
                float tmp = fmaf(-wi, si, uj);
                sr = fmaf(wr, sr, tmp);
                si = fmaf(wr, si, mm);
                cmat[wv][j16][lane] = fmaf(nci, si, cr * sr);
            }
            float p0 = 0.f, p1 = 0.f;
            #pragma unroll
            for (int i = 0; i < 16; i += 2) {
                p0 += cmat[wv][r][q * 16 + i];
                p1 += cmat[wv][r][q * 16 + i + 1];
            }
            float ps = p0 + p1;
            ps += __shfl_xor(ps, 16);
            ps += __shfl_xor(ps, 32);
            float uperm = __shfl(uv, jt * 16 + r);
            float yv = fmaf(Dh, uperm, ps);
            float yc = fmaf(0.044715f * yv, yv * yv, yv);
            float tg = tanhf(0.79788456f * yc);
            float outv = 0.5f * yv * (1.f + tg);
            if (q == 0) yrow[l0 + jt * 16 + r] = outv;
        }
        uv = uvn;
    }
}

// ---------------------------------------------------------------------------
// Transpose+convert: y fp32 [B][256][L] -> yT bf16 [B][L][256]
// ---------------------------------------------------------------------------
__global__ __launch_bounds__(256) void transpose_y(
    const float* __restrict__ y, unsigned short* __restrict__ yT)
{
    __shared__ float ld[64][65];
    const int l0 = blockIdx.x * 64, h0 = blockIdx.y * 64, b = blockIdx.z;
    const int wv = threadIdx.x >> 6, lane = threadIdx.x & 63;
    #pragma unroll
    for (int i = 0; i < 16; ++i) {
        int hl = wv * 16 + i;
        ld[hl][lane] = y[((size_t)b * H_DIM + h0 + hl) * L_SEQ + l0 + lane];
    }
    __syncthreads();
    const int lc = threadIdx.x & 63, qq = threadIdx.x >> 6;
    union { unsigned short s[16]; uint4 v[2]; } pk;
    #pragma unroll
    for (int j = 0; j < 16; ++j)
        pk.s[j] = f2bf(ld[qq * 16 + j][lc]);
    uint4* dst = (uint4*)(yT + ((size_t)b * L_SEQ + l0 + lc) * H_DIM + h0 + qq * 16);
    dst[0] = pk.v[0];
    dst[1] = pk.v[1];
}

// ---------------------------------------------------------------------------
// Output linear (H->2H) via MFMA (W split hi/lo bf16, Y bf16) + GLU + residual.
// D[l][o]: A = Yt rows (l), B = W rows (o).  Out v [B][L][256].
// ---------------------------------------------------------------------------
__global__ __launch_bounds__(256) void linear_glu_mfma(
    const unsigned short* __restrict__ Yt,   // [B][L][256] bf16
    const unsigned short* __restrict__ Whi,  // [512][256] bf16
    const unsigned short* __restrict__ Wlo,
    const float* __restrict__ bias,          // [512]
    const float* __restrict__ xres,          // [B][256][L] fp32
    float* __restrict__ vout)                // [B][L][256] fp32
{
    const int lane = threadIdx.x & 63;
    const int w = threadIdx.x >> 6;
    const int l0 = blockIdx.x * 128 + w * 32;
    const int o0 = blockIdx.y * 64;
    const int b = blockIdx.z;
    const int kq = (lane >> 5) * 8;
    const unsigned short* yp = Yt + ((size_t)b * L_SEQ + l0 + (lane & 31)) * H_DIM + kq;
    const int fb0 = o0 + (lane & 31);
    const int fb1 = o0 + 32 + (lane & 31);
    const unsigned short* wh0 = Whi + (size_t)fb0 * H_DIM + kq;
    const unsigned short* wh1 = Whi + (size_t)fb1 * H_DIM + kq;
    const unsigned short* wh2 = Whi + (size_t)(256 + fb0) * H_DIM + kq;
    const unsigned short* wh3 = Whi + (size_t)(256 + fb1) * H_DIM + kq;
    const unsigned short* wl0 = Wlo + (size_t)fb0 * H_DIM + kq;
    const unsigned short* wl1 = Wlo + (size_t)fb1 * H_DIM + kq;
    const unsigned short* wl2 = Wlo + (size_t)(256 + fb0) * H_DIM + kq;
    const unsigned short* wl3 = Wlo + (size_t)(256 + fb1) * H_DIM + kq;

    f32x16 acc0 = {}, acc1 = {}, acc2 = {}, acc3 = {};
    #pragma unroll 2
    for (int kk = 0; kk < H_DIM; kk += 16) {
        short8v a = *(const short8v*)(yp + kk);
        short8v b0 = *(const short8v*)(wh0 + kk);
        short8v b1 = *(const short8v*)(wh1 + kk);
        short8v b2 = *(const short8v*)(wh2 + kk);
        short8v b3 = *(const short8v*)(wh3 + kk);
        short8v c0 = *(const short8v*)(wl0 + kk);
        short8v c1 = *(const short8v*)(wl1 + kk);
        short8v c2 = *(const short8v*)(wl2 + kk);
        short8v c3 = *(const short8v*)(wl3 + kk);
        acc0 = __builtin_amdgcn_mfma_f32_32x32x16_bf16(a, b0, acc0, 0, 0, 0);
        acc1 = __builtin_amdgcn_mfma_f32_32x32x16_bf16(a, b1, acc1, 0, 0, 0);
        acc2 = __builtin_amdgcn_mfma_f32_32x32x16_bf16(a, b2, acc2, 0, 0, 0);
        acc3 = __builtin_amdgcn_mfma_f32_32x32x16_bf16(a, b3, acc3, 0, 0, 0);
        acc0 = __builtin_amdgcn_mfma_f32_32x32x16_bf16(a, c0, acc0, 0, 0, 0);
        acc1 = __builtin_amdgcn_mfma_f32_32x32x16_bf16(a, c1, acc1, 0, 0, 0);
        acc2 = __builtin_amdgcn_mfma_f32_32x32x16_bf16(a, c2, acc2, 0, 0, 0);
        acc3 = __builtin_amdgcn_mfma_f32_32x32x16_bf16(a, c3, acc3, 0, 0, 0);
    }
    // epilogue: pairs (acc0,acc2)->o_idx=fb0 ; (acc1,acc3)->o_idx=fb1
    const int hl = 4 * (lane >> 5);
    #pragma unroll
    for (int p = 0; p < 2; ++p) {
        const f32x16& z1a = p ? acc1 : acc0;
        const f32x16& z2a = p ? acc3 : acc2;
        int o_idx = p ? fb1 : fb0;
        float b1v = bias[o_idx], b2v = bias[256 + o_idx];
        #pragma unroll
        for (int rr = 0; rr < 16; ++rr) {
            int lidx = l0 + (rr & 3) + 8 * (rr >> 2) + hl;
            float z1 = z1a[rr] + b1v;
            float z2 = z2a[rr] + b2v;
            float glu = z1 / (1.f + expf(-z2));
            float xr = xres[((size_t)b * H_DIM + o_idx) * L_SEQ + lidx];
            vout[((size_t)b * L_SEQ + lidx) * H_DIM + o_idx] = glu + xr;
        }
    }
}

// ---------------------------------------------------------------------------
// LayerNorm over channel dim. Reads v [B][L][256], writes x [B][256][L].
// ---------------------------------------------------------------------------
__global__ __launch_bounds__(256) void ln_ch2(
    const float* __restrict__ vin, float* __restrict__ xhl,
    const float* __restrict__ lg, const float* __restrict__ lb)
{
    __shared__ float ld[16][257];
    const int w = threadIdx.x >> 6, lane = threadIdx.x & 63;
    const int b = blockIdx.y, l0 = blockIdx.x * 16;
    float4 g4 = *(const float4*)(lg + lane * 4);
    float4 b4 = *(const float4*)(lb + lane * 4);
    #pragma unroll
    for (int rr = 0; rr < 4; ++rr) {
        int row = rr * 4 + w;
        float4 xv = *(const float4*)(vin + ((size_t)b * L_SEQ + l0 + row) * H_DIM + lane * 4);
        float s = xv.x + xv.y + xv.z + xv.w;
        float sq = xv.x * xv.x + xv.y * xv.y + xv.z * xv.z + xv.w * xv.w;
        #pragma unroll
        for (int st = 1; st < 64; st <<= 1) {
            s += __shfl_xor(s, st);
            sq += __shfl_xor(sq, st);
        }
        float mean = s * (1.f / H_DIM);
        float var = sq * (1.f / H_DIM) - mean * mean;
        float rstd = rsqrtf(var + 1e-5f);
        ld[row][lane * 4 + 0] = (xv.x - mean) * rstd * g4.x + b4.x;
        ld[row][lane * 4 + 1] = (xv.y - mean) * rstd * g4.y + b4.y;
        ld[row][lane * 4 + 2] = (xv.z - mean) * rstd * g4.z + b4.z;
        ld[row][lane * 4 + 3] = (xv.w - mean) * rstd * g4.w + b4.w;
    }
    __syncthreads();
    const int t = threadIdx.x;   // h index
    float* dst = xhl + ((size_t)b * H_DIM + t) * L_SEQ + l0;
    #pragma unroll
    for (int jj = 0; jj < 4; ++jj) {
        float4 o;
        o.x = ld[jj * 4 + 0][t];
        o.y = ld[jj * 4 + 1][t];
        o.z = ld[jj * 4 + 2][t];
        o.w = ld[jj * 4 + 3][t];
        *(float4*)(dst + jj * 4) = o;
    }
}

// ---------------------------------------------------------------------------
// Mean over time per (b,h); then tiny decode.
// ---------------------------------------------------------------------------
__global__ __launch_bounds__(256) void pool_mean(
    const float* __restrict__ x, float* __restrict__ meanb)
{
    __shared__ float red[256];
    const int bh = blockIdx.x;
    const float* row = x + (size_t)bh * L_SEQ;
    float s = 0.f;
    for (int i = threadIdx.x; i < L_SEQ; i += 256) s += row[i];
    red[threadIdx.x] = s;
    __syncthreads();
    for (int st = 128; st > 0; st >>= 1) {
        if (threadIdx.x < st) red[threadIdx.x] += red[threadIdx.x + st];
        __syncthreads();
    }
    if (threadIdx.x == 0) meanb[bh] = red[0] * (1.f / L_SEQ);
}

__global__ __launch_bounds__(256) void decode(
    const float* __restrict__ meanb, const float* __restrict__ dw,
    const float* __restrict__ db, float* __restrict__ out)
{
    int i = threadIdx.x;
    if (i >= BATCH * 10) return;
    int b = i / 10, d = i % 10;
    float s = db[d];
    for (int h = 0; h < H_DIM; ++h)
        s = fmaf(meanb[b * H_DIM + h], dw[d * H_DIM + h], s);
    out[i] = s;
}

// ---------------------------------------------------------------------------
extern "C" void kernel_launch(void* const* d_in, const int* in_sizes, int n_in,
                              void* d_out, int out_size, void* d_ws, size_t ws_size,
                              hipStream_t stream)
{
    const float* x_in = (const float*)d_in[0];
    const float* cw[3] = {(const float*)d_in[1], (const float*)d_in[7],  (const float*)d_in[13]};
    const float* cb[3] = {(const float*)d_in[2], (const float*)d_in[8],  (const float*)d_in[14]};
    const float* bg[3] = {(const float*)d_in[3], (const float*)d_in[9],  (const float*)d_in[15]};
    const float* bb[3] = {(const float*)d_in[4], (const float*)d_in[10], (const float*)d_in[16]};
    const float* bm[3] = {(const float*)d_in[5], (const float*)d_in[11], (const float*)d_in[17]};
    const float* bv[3] = {(const float*)d_in[6], (const float*)d_in[12], (const float*)d_in[18]};
    const float* log_dt   = (const float*)d_in[19];
    const float* A_re_log = (const float*)d_in[20];
    const float* A_im     = (const float*)d_in[21];
    const float* C_re     = (const float*)d_in[22];
    const float* C_im     = (const float*)d_in[23];
    const float* Dv       = (const float*)d_in[24];
    const float* out_w    = (const float*)d_in[25];
    const float* out_b    = (const float*)d_in[26];
    const float* ln_g     = (const float*)d_in[27];
    const float* ln_b     = (const float*)d_in[28];
    const float* dec_w    = (const float*)d_in[29];
    const float* dec_b    = (const float*)d_in[30];

    const size_t PLANE = (size_t)BATCH * H_DIM * L_SEQ;       // 16,777,216 floats
    float* ws = (float*)d_ws;
    float* xhl  = ws;                                         // [B][256][L] fp32
    float* yv   = ws + PLANE;                                 // y / v / conv temps
    unsigned short* yT = (unsigned short*)(ws + 2 * PLANE);   // [B][L][256] bf16
    float* AR = ws + 2 * PLANE + PLANE / 2;                   // 2,097,152
    float* AI = AR + (size_t)BATCH * H_DIM * NCHUNK * 64;
    unsigned short* Whi = (unsigned short*)(AI + (size_t)BATCH * H_DIM * NCHUNK * 64);
    unsigned short* Wlo = Whi + 4 * 512 * H_DIM;
    float* modes = (float*)(Wlo + 4 * 512 * H_DIM);
    float* mwr = modes, *mwi = modes + 65536, *mcr = modes + 2 * 65536,
         *mci = modes + 3 * 65536, *mtr = modes + 4 * 65536, *mti = modes + 5 * 65536;
    float* meanb = modes + 6 * 65536;

    precompute_modes<<<256, 256, 0, stream>>>(log_dt, A_re_log, A_im, C_re, C_im,
                                              mwr, mwi, mcr, mci, mtr, mti);
    precompute_wbf<<<2048, 256, 0, stream>>>(out_w, Whi, Wlo);

    // Encoder: x_in -> c1(yv) -> c2(yv+4.2M) -> xhl
    float* c1 = yv;
    float* c2 = yv + (size_t)BATCH * 64 * L_SEQ;
    conv_bn_relu<1, 7><<<dim3(16, 16, 16), 256, 0, stream>>>(
        x_in, c1, cw[0], cb[0], bg[0], bb[0], bm[0], bv[0], 64);
    conv_bn_relu<64, 5><<<dim3(16, 32, 16), 256, 0, stream>>>(
        c1, c2, cw[1], cb[1], bg[1], bb[1], bm[1], bv[1], 128);
    conv_bn_relu<128, 3><<<dim3(16, 64, 16), 256, 0, stream>>>(
        c2, xhl, cw[2], cb[2], bg[2], bb[2], bm[2], bv[2], 256);

    for (int l = 0; l < 4; ++l) {
        const int moff = l * H_DIM * N_MODES;
        s4d_state<<<dim3(BATCH * H_DIM * 7 / 4), 256, 0, stream>>>(
            xhl, mwr + moff, mwi + moff, AR, AI);
        s4d_combine<<<dim3(BATCH * H_DIM / 4), 256, 0, stream>>>(
            mtr + moff, mti + moff, AR, AI);
        s4d_scan2<<<dim3(BATCH * H_DIM * NCHUNK / 4), 256, 0, stream>>>(
            xhl, mwr + moff, mwi + moff, mcr + moff, mci + moff,
            Dv + l * H_DIM, AR, AI, yv);
        transpose_y<<<dim3(64, 4, 16), 256, 0, stream>>>(yv, yT);
        linear_glu_mfma<<<dim3(32, 4, 16), 256, 0, stream>>>(
            yT, Whi + (size_t)l * 512 * H_DIM, Wlo + (size_t)l * 512 * H_DIM,
            out_b + l * 512, xhl, yv);
        ln_ch2<<<dim3(256, 16), 256, 0, stream>>>(
            yv, xhl, ln_g + l * H_DIM, ln_b + l * H_DIM);
    }

    pool_mean<<<dim3(BATCH * H_DIM), 256, 0, stream>>>(xhl, meanb);
    decode<<<dim3(1), 256, 0, stream>>>(meanb, dec_w, dec_b, (float*)d_out);
}

// Round 3
// 2587.899 us; speedup vs baseline: 1.5881x; 1.0853x over previous
//
#include <hip/hip_runtime.h>
#include <cstdint>
#include <cstddef>

#define L_SEQ 4096
#define H_DIM 256
#define N_MODES 64
#define BATCH 16
#define NCHUNK 8
#define TCHUNK 512

typedef __attribute__((ext_vector_type(8))) short short8v;
typedef __attribute__((ext_vector_type(16))) float f32x16;

__device__ __forceinline__ unsigned short f2bf(float f) {
    unsigned u = __float_as_uint(f);
    u = u + 0x7fff + ((u >> 16) & 1);
    return (unsigned short)(u >> 16);
}
__device__ __forceinline__ float bf2f(unsigned short h) {
    return __uint_as_float(((unsigned)h) << 16);
}
__device__ __forceinline__ float rdlane(float v, int j) {
    return __uint_as_float(__builtin_amdgcn_readlane(__float_as_uint(v), j));
}

// ---------------------------------------------------------------------------
// Mode precompute: w = exp(dt*A), c2 = 2*C*(w-1)/A, wT = w^512
// ---------------------------------------------------------------------------
__global__ __launch_bounds__(256) void precompute_modes(
    const float* __restrict__ log_dt, const float* __restrict__ A_re_log,
    const float* __restrict__ A_im, const float* __restrict__ C_re,
    const float* __restrict__ C_im,
    float* __restrict__ wr_, float* __restrict__ wi_,
    float* __restrict__ cr_, float* __restrict__ ci_,
    float* __restrict__ wTr_, float* __restrict__ wTi_)
{
    int i = blockIdx.x * 256 + threadIdx.x;       // NL*H*N = 65536
    if (i >= 4 * H_DIM * N_MODES) return;
    int lh = i / N_MODES;
    float dt = expf(log_dt[lh]);
    float Ar = -expf(A_re_log[i]);
    float Ai = A_im[i];
    float dr = Ar * dt, di = Ai * dt;
    float er = expf(dr);
    float wr = er * cosf(di), wi = er * sinf(di);
    float nr = wr - 1.f, ni = wi;
    float Cr = C_re[i], Ci = C_im[i];
    float pr = Cr * nr - Ci * ni;
    float pi = Cr * ni + Ci * nr;
    float inv = 1.f / (Ar * Ar + Ai * Ai);
    float cr = (pr * Ar + pi * Ai) * inv;
    float ci = (pi * Ar - pr * Ai) * inv;
    wr_[i] = wr; wi_[i] = wi;
    cr_[i] = 2.f * cr; ci_[i] = 2.f * ci;
    float er5 = expf(dr * (float)TCHUNK);
    float an5 = di * (float)TCHUNK;
    wTr_[i] = er5 * cosf(an5);
    wTi_[i] = er5 * sinf(an5);
}

// ---------------------------------------------------------------------------
// W -> packed MFMA B-fragment order, bf16 hi/lo planes.
// Layout per layer: [2][16 ob][16 kk][64 lane][8]  (hi plane then lo plane)
// value = W[o = ob*32 + (lane&31)][k = kk*16 + (lane>>5)*8 + j]
// ---------------------------------------------------------------------------
__global__ __launch_bounds__(256) void precompute_wpk(
    const float* __restrict__ W, unsigned short* __restrict__ Wpk)
{
    int t = blockIdx.x * 256 + threadIdx.x;       // 4*16*16*64 = 65536
    if (t >= 4 * 16 * 16 * 64) return;
    int lane = t & 63;
    int kk = (t >> 6) & 15;
    int ob = (t >> 10) & 15;
    int layer = t >> 14;
    int o = ob * 32 + (lane & 31);
    int k0 = kk * 16 + (lane >> 5) * 8;
    const float* src = W + ((size_t)layer * 512 + o) * H_DIM + k0;
    union { unsigned short s[8]; uint4 v; } hi, lo;
    #pragma unroll
    for (int j = 0; j < 8; ++j) {
        float f = src[j];
        hi.s[j] = f2bf(f);
        lo.s[j] = f2bf(f - bf2f(hi.s[j]));
    }
    size_t base = (size_t)layer * 262144 + ((size_t)((ob * 16 + kk) * 64 + lane) * 8);
    *(uint4*)(Wpk + base) = hi.v;
    *(uint4*)(Wpk + base + 131072) = lo.v;
}

// ---------------------------------------------------------------------------
// Fast conv1d('same') + BN(eval) + ReLU.
// Block = 256 thr = 4 waves; wave owns 8 output channels (uniform -> s_loads);
// lane owns 4 consecutive l via 12-wide register window (3 overlapped float4).
// ---------------------------------------------------------------------------
template<int CI, int K>
__global__ __launch_bounds__(256) void conv_bn_relu_f(
    const float* __restrict__ in, float* __restrict__ out,
    const float* __restrict__ wg, const float* __restrict__ cb,
    const float* __restrict__ g, const float* __restrict__ bb,
    const float* __restrict__ m, const float* __restrict__ v, int CO)
{
    const int wv = threadIdx.x >> 6, lane = threadIdx.x & 63;
    const int b = blockIdx.z;
    const int l0 = blockIdx.x * 256;
    const int co0 = __builtin_amdgcn_readfirstlane(blockIdx.y * 32 + wv * 8);
    const int l = l0 + lane * 4;
    const int OFF = K / 2;
    float acc[8][4] = {};
    const bool interior = (blockIdx.x > 0) && (blockIdx.x < gridDim.x - 1);
    const float* inb = in + (size_t)b * CI * L_SEQ;

    if (interior) {
        for (int ci = 0; ci < CI; ++ci) {
            const float* row = inb + (size_t)ci * L_SEQ + l;
            float4 A = *(const float4*)(row - 4);
            float4 Bv = *(const float4*)(row);
            float4 Cv = *(const float4*)(row + 4);
            float win[12] = {A.x, A.y, A.z, A.w, Bv.x, Bv.y, Bv.z, Bv.w,
                             Cv.x, Cv.y, Cv.z, Cv.w};
            #pragma unroll
            for (int cc = 0; cc < 8; ++cc) {
                #pragma unroll
                for (int k = 0; k < K; ++k) {
                    float wk = wg[((size_t)(co0 + cc) * CI + ci) * K + k];
                    #pragma unroll
                    for (int j = 0; j < 4; ++j)
                        acc[cc][j] = fmaf(win[4 + j + k - OFF], wk, acc[cc][j]);
                }
            }
        }
    } else {
        for (int ci = 0; ci < CI; ++ci) {
            const float* row = inb + (size_t)ci * L_SEQ;
            float win[12];
            #pragma unroll
            for (int d = 0; d < 12; ++d) {
                int li = l - 4 + d;
                win[d] = (li >= 0 && li < L_SEQ) ? row[li] : 0.f;
            }
            #pragma unroll
            for (int cc = 0; cc < 8; ++cc) {
                #pragma unroll
                for (int k = 0; k < K; ++k) {
                    float wk = wg[((size_t)(co0 + cc) * CI + ci) * K + k];
                    #pragma unroll
                    for (int j = 0; j < 4; ++j)
                        acc[cc][j] = fmaf(win[4 + j + k - OFF], wk, acc[cc][j]);
                }
            }
        }
    }
    #pragma unroll
    for (int cc = 0; cc < 8; ++cc) {
        int co = co0 + cc;
        float s = g[co] * rsqrtf(v[co] + 1e-5f);
        float sh = (cb[co] - m[co]) * s + bb[co];
        float4 o4;
        o4.x = fmaxf(fmaf(acc[cc][0], s, sh), 0.f);
        o4.y = fmaxf(fmaf(acc[cc][1], s, sh), 0.f);
        o4.z = fmaxf(fmaf(acc[cc][2], s, sh), 0.f);
        o4.w = fmaxf(fmaf(acc[cc][3], s, sh), 0.f);
        *(float4*)(out + ((size_t)b * CO + co) * L_SEQ + l) = o4;
    }
}

// ---------------------------------------------------------------------------
// S4D phase A: chunk-local end states (chunks 0..6 only). wave=(bh,chunk).
// ---------------------------------------------------------------------------
__global__ __launch_bounds__(256) void s4d_state(
    const float* __restrict__ u,
    const float* __restrict__ wre, const float* __restrict__ wim,
    float* __restrict__ AR, float* __restrict__ AI)
{
    const int W = blockIdx.x * 4 + (threadIdx.x >> 6);
    const int lane = threadIdx.x & 63;
    const int bh = W / 7;
    const int c = W - bh * 7;
    const int h = bh & (H_DIM - 1);
    const float wr = wre[h * 64 + lane], wi = wim[h * 64 + lane];
    const float* urow = u + (size_t)bh * L_SEQ + c * TCHUNK;
    float sr = 0.f, si = 0.f;
    float uv = urow[lane];
    for (int l0 = 0; l0 < TCHUNK; l0 += 64) {
        float uvn = (l0 + 64 < TCHUNK) ? urow[l0 + 64 + lane] : 0.f;
        #pragma unroll
        for (int j = 0; j < 64; ++j) {
            float uj = rdlane(uv, j);
            float mm = wi * sr;
            float tmp = fmaf(-wi, si, uj);
            sr = fmaf(wr, sr, tmp);
            si = fmaf(wr, si, mm);
        }
        uv = uvn;
    }
    size_t base = ((size_t)bh * NCHUNK + c) * 64 + lane;
    AR[base] = sr; AI[base] = si;
}

// ---------------------------------------------------------------------------
// S4D combine: in-place; slot k becomes carry-in state for chunk k+1.
// ---------------------------------------------------------------------------
__global__ __launch_bounds__(256) void s4d_combine(
    const float* __restrict__ wTr, const float* __restrict__ wTi,
    float* __restrict__ AR, float* __restrict__ AI)
{
    const int bh = blockIdx.x * 4 + (threadIdx.x >> 6);
    const int lane = threadIdx.x & 63;
    const int h = bh & (H_DIM - 1);
    const float tr = wTr[h * 64 + lane], ti = wTi[h * 64 + lane];
    float Sr = 0.f, Si = 0.f;
    for (int k = 0; k < 7; ++k) {
        size_t base = ((size_t)bh * NCHUNK + k) * 64 + lane;
        float ar = AR[base], ai = AI[base];
        float nr = fmaf(tr, Sr, fmaf(-ti, Si, ar));
        float ni = fmaf(tr, Si, fmaf(ti, Sr, ai));
        AR[base] = nr; AI[base] = ni;
        Sr = nr; Si = ni;
    }
}

// ---------------------------------------------------------------------------
// S4D phase B: output scan per (bh,chunk); 16-step wave-private LDS tiles.
// Epilogue: + D*u, tanh-GELU. No __syncthreads.
// ---------------------------------------------------------------------------
__global__ __launch_bounds__(256) void s4d_scan2(
    const float* __restrict__ u,
    const float* __restrict__ wre, const float* __restrict__ wim,
    const float* __restrict__ c2r, const float* __restrict__ c2i,
    const float* __restrict__ Dv,
    const float* __restrict__ AR, const float* __restrict__ AI,
    float* __restrict__ y)
{
    __shared__ float cmat[4][16][69];
    const int wv = threadIdx.x >> 6;
    const int lane = threadIdx.x & 63;
    const int W = blockIdx.x * 4 + wv;
    const int bh = W >> 3;
    const int c = W & 7;
    const int h = bh & (H_DIM - 1);
    const float wr = wre[h * 64 + lane], wi = wim[h * 64 + lane];
    const float cr = c2r[h * 64 + lane];
    const float nci = -c2i[h * 64 + lane];
    const float Dh = Dv[h];
    const int r = lane & 15, q = lane >> 4;
    float sr = 0.f, si = 0.f;
    if (c > 0) {
        size_t base = ((size_t)bh * NCHUNK + c - 1) * 64 + lane;
        sr = AR[base]; si = AI[base];
    }
    const float* urow = u + (size_t)bh * L_SEQ + c * TCHUNK;
    float* yrow = y + (size_t)bh * L_SEQ + c * TCHUNK;
    float uv = urow[lane];
    for (int l0 = 0; l0 < TCHUNK; l0 += 64) {
        float uvn = (l0 + 64 < TCHUNK) ? urow[l0 + 64 + lane] : 0.f;
        #pragma unroll
        for (int jt = 0; jt < 4; ++jt) {
            #pragma unroll
            for (int j16 = 0; j16 < 16; ++j16) {
                float uj = rdlane(uv, jt * 16 + j16);
                float mm = wi * sr;
                float tmp = fmaf(-wi, si, uj);
                sr = fmaf(wr, sr, tmp);
                si = fmaf(wr, si, mm);
                cmat[wv][j16][lane] = fmaf(nci, si, cr * sr);
            }
            float p0 = 0.f, p1 = 0.f;
            #pragma unroll
            for (int i = 0; i < 16; i += 2) {
                p0 += cmat[wv][r][q * 16 + i];
                p1 += cmat[wv][r][q * 16 + i + 1];
            }
            float ps = p0 + p1;
            ps += __shfl_xor(ps, 16);
            ps += __shfl_xor(ps, 32);
            float uperm = __shfl(uv, jt * 16 + r);
            float yv = fmaf(Dh, uperm, ps);
            float yc = fmaf(0.044715f * yv, yv * yv, yv);
            float tg = tanhf(0.79788456f * yc);
            float outv = 0.5f * yv * (1.f + tg);
            if (q == 0) yrow[l0 + jt * 16 + r] = outv;
        }
        uv = uvn;
    }
}

// ---------------------------------------------------------------------------
// Transpose+convert: y fp32 [B][256][L] -> yT bf16 [B][L][256]
// ---------------------------------------------------------------------------
__global__ __launch_bounds__(256) void transpose_y(
    const float* __restrict__ y, unsigned short* __restrict__ yT)
{
    __shared__ float ld[64][65];
    const int l0 = blockIdx.x * 64, h0 = blockIdx.y * 64, b = blockIdx.z;
    const int wv = threadIdx.x >> 6, lane = threadIdx.x & 63;
    #pragma unroll
    for (int i = 0; i < 16; ++i) {
        int hl = wv * 16 + i;
        ld[hl][lane] = y[((size_t)b * H_DIM + h0 + hl) * L_SEQ + l0 + lane];
    }
    __syncthreads();
    const int lc = threadIdx.x & 63, qq = threadIdx.x >> 6;
    union { unsigned short s[16]; uint4 v[2]; } pk;
    #pragma unroll
    for (int j = 0; j < 16; ++j)
        pk.s[j] = f2bf(ld[qq * 16 + j][lc]);
    uint4* dst = (uint4*)(yT + ((size_t)b * L_SEQ + l0 + lc) * H_DIM + h0 + qq * 16);
    dst[0] = pk.v[0];
    dst[1] = pk.v[1];
}

// ---------------------------------------------------------------------------
// Output linear (H->2H) via MFMA, LDS-staged A (XOR-swizzled), packed W.
// Block = 32 l rows x all 512 outputs; wave w owns o-blocks {2w,2w+1,2w+8,2w+9}.
// Epilogue: bias + GLU only (residual deferred to ln_fuse). Coalesced stores.
// ---------------------------------------------------------------------------
__global__ __launch_bounds__(256) void linear_glu_mfma2(
    const unsigned short* __restrict__ Yt,   // [B][L][256] bf16
    const unsigned short* __restrict__ Wpk,  // packed, hi plane + lo at +131072
    const float* __restrict__ bias,          // [512]
    float* __restrict__ vout)                // [B][L][256] fp32, pure GLU
{
    __shared__ __align__(16) unsigned short As[32 * 256];
    const int lane = threadIdx.x & 63;
    const int wv = threadIdx.x >> 6;
    const int b = blockIdx.y;
    const int l0 = blockIdx.x * 32;

    // stage A tile (32 rows x 256 k bf16 = 16KB), XOR-swizzled
    const char* ybase = (const char*)(Yt + ((size_t)b * L_SEQ + l0) * H_DIM);
    #pragma unroll
    for (int p = 0; p < 4; ++p) {
        int ofs = (threadIdx.x + p * 256) * 16;
        int row = ofs >> 9;
        int swz = ofs ^ ((row & 7) << 4);
        *(uint4*)((char*)As + swz) = *(const uint4*)(ybase + ofs);
    }
    __syncthreads();

    const int ob0 = 2 * wv, ob1 = 2 * wv + 1;
    const int r = lane & 31;
    f32x16 acc0 = {}, acc1 = {}, acc2 = {}, acc3 = {};
    #pragma unroll 4
    for (int kk = 0; kk < 16; ++kk) {
        int abyte = (r << 9) | (kk * 32 + (lane >> 5) * 16);
        abyte ^= ((r & 7) << 4);
        short8v a = *(const short8v*)((char*)As + abyte);
        const unsigned short* w0 = Wpk + (((ob0 * 16 + kk) * 64 + lane) * 8);
        const unsigned short* w1 = Wpk + (((ob1 * 16 + kk) * 64 + lane) * 8);
        const unsigned short* w2 = Wpk + ((((ob0 + 8) * 16 + kk) * 64 + lane) * 8);
        const unsigned short* w3 = Wpk + ((((ob1 + 8) * 16 + kk) * 64 + lane) * 8);
        short8v h0 = *(const short8v*)w0;
        short8v h1 = *(const short8v*)w1;
        short8v h2 = *(const short8v*)w2;
        short8v h3 = *(const short8v*)w3;
        short8v e0 = *(const short8v*)(w0 + 131072);
        short8v e1 = *(const short8v*)(w1 + 131072);
        short8v e2 = *(const short8v*)(w2 + 131072);
        short8v e3 = *(const short8v*)(w3 + 131072);
        acc0 = __builtin_amdgcn_mfma_f32_32x32x16_bf16(a, h0, acc0, 0, 0, 0);
        acc1 = __builtin_amdgcn_mfma_f32_32x32x16_bf16(a, h1, acc1, 0, 0, 0);
        acc2 = __builtin_amdgcn_mfma_f32_32x32x16_bf16(a, h2, acc2, 0, 0, 0);
        acc3 = __builtin_amdgcn_mfma_f32_32x32x16_bf16(a, h3, acc3, 0, 0, 0);
        acc0 = __builtin_amdgcn_mfma_f32_32x32x16_bf16(a, e0, acc0, 0, 0, 0);
        acc1 = __builtin_amdgcn_mfma_f32_32x32x16_bf16(a, e1, acc1, 0, 0, 0);
        acc2 = __builtin_amdgcn_mfma_f32_32x32x16_bf16(a, e2, acc2, 0, 0, 0);
        acc3 = __builtin_amdgcn_mfma_f32_32x32x16_bf16(a, e3, acc3, 0, 0, 0);
    }
    // epilogue: (acc0,acc2) and (acc1,acc3) are (z1,z2) GLU pairs
    #pragma unroll
    for (int p = 0; p < 2; ++p) {
        const f32x16& z1v = p ? acc1 : acc0;
        const f32x16& z2v = p ? acc3 : acc2;
        int o = (p ? ob1 : ob0) * 32 + (lane & 31);
        float b1 = bias[o], b2 = bias[o + 256];
        #pragma unroll
        for (int rr = 0; rr < 16; ++rr) {
            int ll = l0 + (rr & 3) + 8 * (rr >> 2) + 4 * (lane >> 5);
            float z1 = z1v[rr] + b1;
            float z2 = z2v[rr] + b2;
            vout[((size_t)b * L_SEQ + ll) * H_DIM + o] = z1 / (1.f + expf(-z2));
        }
    }
}

// ---------------------------------------------------------------------------
// Fused residual + LayerNorm over channel dim.
// Reads vin [B][L][256] (GLU out) + xhl [B][256][L] (residual, via LDS
// transpose); writes x_new = LN(v + x) back to xhl [B][256][L].
// ---------------------------------------------------------------------------
__global__ __launch_bounds__(256) void ln_fuse(
    const float* __restrict__ vin, float* __restrict__ xhl,
    const float* __restrict__ lg, const float* __restrict__ lb)
{
    __shared__ float ld[16][260];
    const int w = threadIdx.x >> 6, lane = threadIdx.x & 63;
    const int b = blockIdx.y, l0 = blockIdx.x * 16;
    // phase A: load residual tile x[h][l0..l0+15] -> ld[l][h]
    {
        const float* src = xhl + ((size_t)b * H_DIM + threadIdx.x) * L_SEQ + l0;
        #pragma unroll
        for (int u4 = 0; u4 < 4; ++u4) {
            float4 q = *(const float4*)(src + u4 * 4);
            ld[u4 * 4 + 0][threadIdx.x] = q.x;
            ld[u4 * 4 + 1][threadIdx.x] = q.y;
            ld[u4 * 4 + 2][threadIdx.x] = q.z;
            ld[u4 * 4 + 3][threadIdx.x] = q.w;
        }
    }
    __syncthreads();
    // phase B: per l-row: v+x, stats over 256 h via wave shuffle, normalize
    float4 g4 = *(const float4*)(lg + lane * 4);
    float4 b4 = *(const float4*)(lb + lane * 4);
    #pragma unroll
    for (int rr = 0; rr < 4; ++rr) {
        int row = rr * 4 + w;
        float4 xv = *(const float4*)(vin + ((size_t)b * L_SEQ + l0 + row) * H_DIM + lane * 4);
        xv.x += ld[row][lane * 4 + 0];
        xv.y += ld[row][lane * 4 + 1];
        xv.z += ld[row][lane * 4 + 2];
        xv.w += ld[row][lane * 4 + 3];
        float s = xv.x + xv.y + xv.z + xv.w;
        float sq = xv.x * xv.x + xv.y * xv.y + xv.z * xv.z + xv.w * xv.w;
        #pragma unroll
        for (int st = 1; st < 64; st <<= 1) {
            s += __shfl_xor(s, st);
            sq += __shfl_xor(sq, st);
        }
        float mean = s * (1.f / H_DIM);
        float var = sq * (1.f / H_DIM) - mean * mean;
        float rstd = rsqrtf(var + 1e-5f);
        ld[row][lane * 4 + 0] = (xv.x - mean) * rstd * g4.x + b4.x;
        ld[row][lane * 4 + 1] = (xv.y - mean) * rstd * g4.y + b4.y;
        ld[row][lane * 4 + 2] = (xv.z - mean) * rstd * g4.z + b4.z;
        ld[row][lane * 4 + 3] = (xv.w - mean) * rstd * g4.w + b4.w;
    }
    __syncthreads();
    // phase C: write back transposed
    {
        float* dst = xhl + ((size_t)b * H_DIM + threadIdx.x) * L_SEQ + l0;
        #pragma unroll
        for (int u4 = 0; u4 < 4; ++u4) {
            float4 o;
            o.x = ld[u4 * 4 + 0][threadIdx.x];
            o.y = ld[u4 * 4 + 1][threadIdx.x];
            o.z = ld[u4 * 4 + 2][threadIdx.x];
            o.w = ld[u4 * 4 + 3][threadIdx.x];
            *(float4*)(dst + u4 * 4) = o;
        }
    }
}

// ---------------------------------------------------------------------------
// Mean over time per (b,h); then tiny decode.
// ---------------------------------------------------------------------------
__global__ __launch_bounds__(256) void pool_mean(
    const float* __restrict__ x, float* __restrict__ meanb)
{
    __shared__ float red[256];
    const int bh = blockIdx.x;
    const float* row = x + (size_t)bh * L_SEQ;
    float s = 0.f;
    for (int i = threadIdx.x; i < L_SEQ; i += 256) s += row[i];
    red[threadIdx.x] = s;
    __syncthreads();
    for (int st = 128; st > 0; st >>= 1) {
        if (threadIdx.x < st) red[threadIdx.x] += red[threadIdx.x + st];
        __syncthreads();
    }
    if (threadIdx.x == 0) meanb[bh] = red[0] * (1.f / L_SEQ);
}

__global__ __launch_bounds__(256) void decode(
    const float* __restrict__ meanb, const float* __restrict__ dw,
    const float* __restrict__ db, float* __restrict__ out)
{
    int i = threadIdx.x;
    if (i >= BATCH * 10) return;
    int b = i / 10, d = i % 10;
    float s = db[d];
    for (int h = 0; h < H_DIM; ++h)
        s = fmaf(meanb[b * H_DIM + h], dw[d * H_DIM + h], s);
    out[i] = s;
}

// ---------------------------------------------------------------------------
extern "C" void kernel_launch(void* const* d_in, const int* in_sizes, int n_in,
                              void* d_out, int out_size, void* d_ws, size_t ws_size,
                              hipStream_t stream)
{
    const float* x_in = (const float*)d_in[0];
    const float* cw[3] = {(const float*)d_in[1], (const float*)d_in[7],  (const float*)d_in[13]};
    const float* cb[3] = {(const float*)d_in[2], (const float*)d_in[8],  (const float*)d_in[14]};
    const float* bg[3] = {(const float*)d_in[3], (const float*)d_in[9],  (const float*)d_in[15]};
    const float* bb[3] = {(const float*)d_in[4], (const float*)d_in[10], (const float*)d_in[16]};
    const float* bm[3] = {(const float*)d_in[5], (const float*)d_in[11], (const float*)d_in[17]};
    const float* bv[3] = {(const float*)d_in[6], (const float*)d_in[12], (const float*)d_in[18]};
    const float* log_dt   = (const float*)d_in[19];
    const float* A_re_log = (const float*)d_in[20];
    const float* A_im     = (const float*)d_in[21];
    const float* C_re     = (const float*)d_in[22];
    const float* C_im     = (const float*)d_in[23];
    const float* Dv       = (const float*)d_in[24];
    const float* out_w    = (const float*)d_in[25];
    const float* out_b    = (const float*)d_in[26];
    const float* ln_g     = (const float*)d_in[27];
    const float* ln_b     = (const float*)d_in[28];
    const float* dec_w    = (const float*)d_in[29];
    const float* dec_b    = (const float*)d_in[30];

    const size_t PLANE = (size_t)BATCH * H_DIM * L_SEQ;       // 16,777,216 floats
    float* ws = (float*)d_ws;
    float* xhl  = ws;                                         // [B][256][L] fp32
    float* yv   = ws + PLANE;                                 // y / GLU out / conv temps
    unsigned short* yT = (unsigned short*)(ws + 2 * PLANE);   // [B][L][256] bf16
    float* AR = ws + 2 * PLANE + PLANE / 2;
    float* AI = AR + (size_t)BATCH * H_DIM * NCHUNK * 64;
    unsigned short* Wpk = (unsigned short*)(AI + (size_t)BATCH * H_DIM * NCHUNK * 64);
    float* modes = (float*)(Wpk + 4 * 262144);
    float* mwr = modes, *mwi = modes + 65536, *mcr = modes + 2 * 65536,
         *mci = modes + 3 * 65536, *mtr = modes + 4 * 65536, *mti = modes + 5 * 65536;
    float* meanb = modes + 6 * 65536;

    precompute_modes<<<256, 256, 0, stream>>>(log_dt, A_re_log, A_im, C_re, C_im,
                                              mwr, mwi, mcr, mci, mtr, mti);
    precompute_wpk<<<256, 256, 0, stream>>>(out_w, Wpk);

    // Encoder: x_in -> c1(yv) -> c2(yv+4.2M) -> xhl
    float* c1 = yv;
    float* c2 = yv + (size_t)BATCH * 64 * L_SEQ;
    conv_bn_relu_f<1, 7><<<dim3(16, 2, 16), 256, 0, stream>>>(
        x_in, c1, cw[0], cb[0], bg[0], bb[0], bm[0], bv[0], 64);
    conv_bn_relu_f<64, 5><<<dim3(16, 4, 16), 256, 0, stream>>>(
        c1, c2, cw[1], cb[1], bg[1], bb[1], bm[1], bv[1], 128);
    conv_bn_relu_f<128, 3><<<dim3(16, 8, 16), 256, 0, stream>>>(
        c2, xhl, cw[2], cb[2], bg[2], bb[2], bm[2], bv[2], 256);

    for (int l = 0; l < 4; ++l) {
        const int moff = l * H_DIM * N_MODES;
        s4d_state<<<dim3(BATCH * H_DIM * 7 / 4), 256, 0, stream>>>(
            xhl, mwr + moff, mwi + moff, AR, AI);
        s4d_combine<<<dim3(BATCH * H_DIM / 4), 256, 0, stream>>>(
            mtr + moff, mti + moff, AR, AI);
        s4d_scan2<<<dim3(BATCH * H_DIM * NCHUNK / 4), 256, 0, stream>>>(
            xhl, mwr + moff, mwi + moff, mcr + moff, mci + moff,
            Dv + l * H_DIM, AR, AI, yv);
        transpose_y<<<dim3(64, 4, 16), 256, 0, stream>>>(yv, yT);
        linear_glu_mfma2<<<dim3(128, 16), 256, 0, stream>>>(
            yT, Wpk + (size_t)l * 262144, out_b + l * 512, yv);
        ln_fuse<<<dim3(256, 16), 256, 0, stream>>>(
            yv, xhl, ln_g + l * H_DIM, ln_b + l * H_DIM);
    }

    pool_mean<<<dim3(BATCH * H_DIM), 256, 0, stream>>>(xhl, meanb);
    decode<<<dim3(1), 256, 0, stream>>>(meanb, dec_w, dec_b, (float*)d_out);
}

// Round 4
// 2192.345 us; speedup vs baseline: 1.8746x; 1.1804x over previous
//
#include <hip/hip_runtime.h>
#include <cstdint>
#include <cstddef>

#define L_SEQ 4096
#define H_DIM 256
#define N_MODES 64
#define BATCH 16
#define NCHUNK 8
#define TCHUNK 512
#define LPAD (L_SEQ + 8)

typedef __attribute__((ext_vector_type(8))) short short8v;
typedef __attribute__((ext_vector_type(16))) float f32x16;

__device__ __forceinline__ unsigned short f2bf(float f) {
    unsigned u = __float_as_uint(f);
    u = u + 0x7fff + ((u >> 16) & 1);
    return (unsigned short)(u >> 16);
}
__device__ __forceinline__ float bf2f(unsigned short h) {
    return __uint_as_float(((unsigned)h) << 16);
}
__device__ __forceinline__ float rdlane(float v, int j) {
    return __uint_as_float(__builtin_amdgcn_readlane(__float_as_uint(v), j));
}

// ---------------------------------------------------------------------------
// Mode precompute: w = exp(dt*A), c2 = 2*C*(w-1)/A, wT = w^512
// ---------------------------------------------------------------------------
__global__ __launch_bounds__(256) void precompute_modes(
    const float* __restrict__ log_dt, const float* __restrict__ A_re_log,
    const float* __restrict__ A_im, const float* __restrict__ C_re,
    const float* __restrict__ C_im,
    float* __restrict__ wr_, float* __restrict__ wi_,
    float* __restrict__ cr_, float* __restrict__ ci_,
    float* __restrict__ wTr_, float* __restrict__ wTi_)
{
    int i = blockIdx.x * 256 + threadIdx.x;       // NL*H*N = 65536
    if (i >= 4 * H_DIM * N_MODES) return;
    int lh = i / N_MODES;
    float dt = expf(log_dt[lh]);
    float Ar = -expf(A_re_log[i]);
    float Ai = A_im[i];
    float dr = Ar * dt, di = Ai * dt;
    float er = expf(dr);
    float wr = er * cosf(di), wi = er * sinf(di);
    float nr = wr - 1.f, ni = wi;
    float Cr = C_re[i], Ci = C_im[i];
    float pr = Cr * nr - Ci * ni;
    float pi = Cr * ni + Ci * nr;
    float inv = 1.f / (Ar * Ar + Ai * Ai);
    float cr = (pr * Ar + pi * Ai) * inv;
    float ci = (pi * Ar - pr * Ai) * inv;
    wr_[i] = wr; wi_[i] = wi;
    cr_[i] = 2.f * cr; ci_[i] = 2.f * ci;
    float er5 = expf(dr * (float)TCHUNK);
    float an5 = di * (float)TCHUNK;
    wTr_[i] = er5 * cosf(an5);
    wTi_[i] = er5 * sinf(an5);
}

// ---------------------------------------------------------------------------
// W -> packed MFMA B-fragment order, bf16 hi/lo planes.
// ---------------------------------------------------------------------------
__global__ __launch_bounds__(256) void precompute_wpk(
    const float* __restrict__ W, unsigned short* __restrict__ Wpk)
{
    int t = blockIdx.x * 256 + threadIdx.x;       // 4*16*16*64 = 65536
    if (t >= 4 * 16 * 16 * 64) return;
    int lane = t & 63;
    int kk = (t >> 6) & 15;
    int ob = (t >> 10) & 15;
    int layer = t >> 14;
    int o = ob * 32 + (lane & 31);
    int k0 = kk * 16 + (lane >> 5) * 8;
    const float* src = W + ((size_t)layer * 512 + o) * H_DIM + k0;
    union { unsigned short s[8]; uint4 v; } hi, lo;
    #pragma unroll
    for (int j = 0; j < 8; ++j) {
        float f = src[j];
        hi.s[j] = f2bf(f);
        lo.s[j] = f2bf(f - bf2f(hi.s[j]));
    }
    size_t base = (size_t)layer * 262144 + ((size_t)((ob * 16 + kk) * 64 + lane) * 8);
    *(uint4*)(Wpk + base) = hi.v;
    *(uint4*)(Wpk + base + 131072) = lo.v;
}

// ---------------------------------------------------------------------------
// Fast conv1d('same') + BN(eval) + ReLU.
// PIN: input rows padded to LPAD with 4-elem zero halo each side (branch-free).
// POUT: output rows padded likewise; this kernel zeroes the halo it owns.
// Wave owns 8 output channels (uniform weights -> s_load); lane owns 4 l.
// ---------------------------------------------------------------------------
template<int CI, int K, bool PIN, bool POUT>
__global__ __launch_bounds__(256) void conv_bn_relu_f(
    const float* __restrict__ in, float* __restrict__ out,
    const float* __restrict__ wg, const float* __restrict__ cb,
    const float* __restrict__ g, const float* __restrict__ bb,
    const float* __restrict__ m, const float* __restrict__ v, int CO)
{
    const int wv = threadIdx.x >> 6, lane = threadIdx.x & 63;
    const int b = blockIdx.z;
    const int co0 = __builtin_amdgcn_readfirstlane(blockIdx.y * 32 + wv * 8);
    const int l = blockIdx.x * 256 + lane * 4;
    const int ILD = PIN ? LPAD : L_SEQ;
    const int OLD = POUT ? LPAD : L_SEQ;
    const int OFF = K / 2;
    float acc[8][4] = {};
    const float* inb = in + (size_t)b * CI * ILD + (PIN ? 4 : 0);

    if (PIN) {
        #pragma unroll 2
        for (int ci = 0; ci < CI; ++ci) {
            const float* row = inb + (size_t)ci * ILD + l;
            float4 A = *(const float4*)(row - 4);
            float4 Bv = *(const float4*)(row);
            float4 Cv = *(const float4*)(row + 4);
            float win[12] = {A.x, A.y, A.z, A.w, Bv.x, Bv.y, Bv.z, Bv.w,
                             Cv.x, Cv.y, Cv.z, Cv.w};
            #pragma unroll
            for (int cc = 0; cc < 8; ++cc) {
                #pragma unroll
                for (int k = 0; k < K; ++k) {
                    float wk = wg[((size_t)(co0 + cc) * CI + ci) * K + k];
                    #pragma unroll
                    for (int j = 0; j < 4; ++j)
                        acc[cc][j] = fmaf(win[4 + j + k - OFF], wk, acc[cc][j]);
                }
            }
        }
    } else {
        for (int ci = 0; ci < CI; ++ci) {
            const float* row = inb + (size_t)ci * ILD;
            float win[12];
            #pragma unroll
            for (int d = 0; d < 12; ++d) {
                int li = l - 4 + d;
                win[d] = (li >= 0 && li < L_SEQ) ? row[li] : 0.f;
            }
            #pragma unroll
            for (int cc = 0; cc < 8; ++cc) {
                #pragma unroll
                for (int k = 0; k < K; ++k) {
                    float wk = wg[((size_t)(co0 + cc) * CI + ci) * K + k];
                    #pragma unroll
                    for (int j = 0; j < 4; ++j)
                        acc[cc][j] = fmaf(win[4 + j + k - OFF], wk, acc[cc][j]);
                }
            }
        }
    }
    #pragma unroll
    for (int cc = 0; cc < 8; ++cc) {
        int co = co0 + cc;
        float s = g[co] * rsqrtf(v[co] + 1e-5f);
        float sh = (cb[co] - m[co]) * s + bb[co];
        float* orow = out + ((size_t)b * CO + co) * OLD + (POUT ? 4 : 0);
        float4 o4;
        o4.x = fmaxf(fmaf(acc[cc][0], s, sh), 0.f);
        o4.y = fmaxf(fmaf(acc[cc][1], s, sh), 0.f);
        o4.z = fmaxf(fmaf(acc[cc][2], s, sh), 0.f);
        o4.w = fmaxf(fmaf(acc[cc][3], s, sh), 0.f);
        *(float4*)(orow + l) = o4;
        if (POUT) {
            if (blockIdx.x == 0 && lane == 0)
                *(float4*)(orow - 4) = make_float4(0.f, 0.f, 0.f, 0.f);
            if (blockIdx.x == gridDim.x - 1 && lane == 63)
                *(float4*)(orow + L_SEQ) = make_float4(0.f, 0.f, 0.f, 0.f);
        }
    }
}

// ---------------------------------------------------------------------------
// S4D phase A: chunk-local end states (chunks 0..6 only). wave=(bh,chunk).
// ---------------------------------------------------------------------------
__global__ __launch_bounds__(256) void s4d_state(
    const float* __restrict__ u,
    const float* __restrict__ wre, const float* __restrict__ wim,
    float* __restrict__ AR, float* __restrict__ AI)
{
    const int W = blockIdx.x * 4 + (threadIdx.x >> 6);
    const int lane = threadIdx.x & 63;
    const int bh = W / 7;
    const int c = W - bh * 7;
    const int h = bh & (H_DIM - 1);
    const float wr = wre[h * 64 + lane], wi = wim[h * 64 + lane];
    const float* urow = u + (size_t)bh * L_SEQ + c * TCHUNK;
    float sr = 0.f, si = 0.f;
    float uv = urow[lane];
    for (int l0 = 0; l0 < TCHUNK; l0 += 64) {
        float uvn = (l0 + 64 < TCHUNK) ? urow[l0 + 64 + lane] : 0.f;
        #pragma unroll
        for (int j = 0; j < 64; ++j) {
            float uj = rdlane(uv, j);
            float mm = wi * sr;
            float tmp = fmaf(-wi, si, uj);
            sr = fmaf(wr, sr, tmp);
            si = fmaf(wr, si, mm);
        }
        uv = uvn;
    }
    size_t base = ((size_t)bh * NCHUNK + c) * 64 + lane;
    AR[base] = sr; AI[base] = si;
}

// ---------------------------------------------------------------------------
// S4D combine: in-place; slot k becomes carry-in state for chunk k+1.
// ---------------------------------------------------------------------------
__global__ __launch_bounds__(256) void s4d_combine(
    const float* __restrict__ wTr, const float* __restrict__ wTi,
    float* __restrict__ AR, float* __restrict__ AI)
{
    const int bh = blockIdx.x * 4 + (threadIdx.x >> 6);
    const int lane = threadIdx.x & 63;
    const int h = bh & (H_DIM - 1);
    const float tr = wTr[h * 64 + lane], ti = wTi[h * 64 + lane];
    float Sr = 0.f, Si = 0.f;
    for (int k = 0; k < 7; ++k) {
        size_t base = ((size_t)bh * NCHUNK + k) * 64 + lane;
        float ar = AR[base], ai = AI[base];
        float nr = fmaf(tr, Sr, fmaf(-ti, Si, ar));
        float ni = fmaf(tr, Si, fmaf(ti, Sr, ai));
        AR[base] = nr; AI[base] = ni;
        Sr = nr; Si = ni;
    }
}

// ---------------------------------------------------------------------------
// S4D phase B: output scan per (bh,chunk); 16-step wave-private LDS tiles.
// Epilogue: + D*u, tanh-GELU, bf16 store ([B][H][L]). No __syncthreads.
// ---------------------------------------------------------------------------
__global__ __launch_bounds__(256) void s4d_scan2(
    const float* __restrict__ u,
    const float* __restrict__ wre, const float* __restrict__ wim,
    const float* __restrict__ c2r, const float* __restrict__ c2i,
    const float* __restrict__ Dv,
    const float* __restrict__ AR, const float* __restrict__ AI,
    unsigned short* __restrict__ ybf)
{
    __shared__ float cmat[4][16][69];
    const int wv = threadIdx.x >> 6;
    const int lane = threadIdx.x & 63;
    const int W = blockIdx.x * 4 + wv;
    const int bh = W >> 3;
    const int c = W & 7;
    const int h = bh & (H_DIM - 1);
    const float wr = wre[h * 64 + lane], wi = wim[h * 64 + lane];
    const float cr = c2r[h * 64 + lane];
    const float nci = -c2i[h * 64 + lane];
    const float Dh = Dv[h];
    const int r = lane & 15, q = lane >> 4;
    float sr = 0.f, si = 0.f;
    if (c > 0) {
        size_t base = ((size_t)bh * NCHUNK + c - 1) * 64 + lane;
        sr = AR[base]; si = AI[base];
    }
    const float* urow = u + (size_t)bh * L_SEQ + c * TCHUNK;
    unsigned short* yrow = ybf + (size_t)bh * L_SEQ + c * TCHUNK;
    float uv = urow[lane];
    for (int l0 = 0; l0 < TCHUNK; l0 += 64) {
        float uvn = (l0 + 64 < TCHUNK) ? urow[l0 + 64 + lane] : 0.f;
        #pragma unroll
        for (int jt = 0; jt < 4; ++jt) {
            #pragma unroll
            for (int j16 = 0; j16 < 16; ++j16) {
                float uj = rdlane(uv, jt * 16 + j16);
                float mm = wi * sr;
                float tmp = fmaf(-wi, si, uj);
                sr = fmaf(wr, sr, tmp);
                si = fmaf(wr, si, mm);
                cmat[wv][j16][lane] = fmaf(nci, si, cr * sr);
            }
            float p0 = 0.f, p1 = 0.f;
            #pragma unroll
            for (int i = 0; i < 16; i += 2) {
                p0 += cmat[wv][r][q * 16 + i];
                p1 += cmat[wv][r][q * 16 + i + 1];
            }
            float ps = p0 + p1;
            ps += __shfl_xor(ps, 16);
            ps += __shfl_xor(ps, 32);
            float uperm = __shfl(uv, jt * 16 + r);
            float yv = fmaf(Dh, uperm, ps);
            float yc = fmaf(0.044715f * yv, yv * yv, yv);
            float tg = tanhf(0.79788456f * yc);
            float outv = 0.5f * yv * (1.f + tg);
            if (q == 0) yrow[l0 + jt * 16 + r] = f2bf(outv);
        }
        uv = uvn;
    }
}

// ---------------------------------------------------------------------------
// Output linear (H->2H) via MFMA; A-tile LDS-transposed from y bf16 [B][H][L].
// Block = 32 l rows x all 512 outputs; wave w owns o-blocks {2w,2w+1,2w+8,2w+9}.
// Epilogue: bias + GLU only (residual deferred to ln_fuse). Coalesced stores.
// ---------------------------------------------------------------------------
__global__ __launch_bounds__(256) void linear_glu_mfma2(
    const unsigned short* __restrict__ ybf,  // [B][H][L] bf16
    const unsigned short* __restrict__ Wpk,  // packed, hi plane + lo at +131072
    const float* __restrict__ bias,          // [512]
    float* __restrict__ vout)                // [B][L][256] fp32, pure GLU
{
    __shared__ __align__(16) unsigned short As[32 * 256];  // [l][k], XOR swizzled
    const int lane = threadIdx.x & 63;
    const int wv = threadIdx.x >> 6;
    const int b = blockIdx.y;
    const int l0 = blockIdx.x * 32;

    // stage+transpose: read 4 uint4 (coalesced rows of y), scatter ushorts
    const unsigned short* ybase = ybf + (size_t)b * H_DIM * L_SEQ + l0;
    #pragma unroll
    for (int p = 0; p < 4; ++p) {
        int e = threadIdx.x + p * 256;        // 0..1023
        int hh = e >> 2, c4 = e & 3;
        union { uint4 v; unsigned short s[8]; } qv;
        qv.v = *(const uint4*)(ybase + (size_t)hh * L_SEQ + c4 * 8);
        #pragma unroll
        for (int j = 0; j < 8; ++j) {
            int lloc = c4 * 8 + j;
            int byteoff = (lloc << 9) + hh * 2;
            byteoff ^= ((lloc & 7) << 4);
            *(unsigned short*)((char*)As + byteoff) = qv.s[j];
        }
    }
    __syncthreads();

    const int ob0 = 2 * wv, ob1 = 2 * wv + 1;
    const int r = lane & 31;
    f32x16 acc0 = {}, acc1 = {}, acc2 = {}, acc3 = {};
    #pragma unroll 4
    for (int kk = 0; kk < 16; ++kk) {
        int abyte = (r << 9) | (kk * 32 + (lane >> 5) * 16);
        abyte ^= ((r & 7) << 4);
        short8v a = *(const short8v*)((char*)As + abyte);
        const unsigned short* w0 = Wpk + (((ob0 * 16 + kk) * 64 + lane) * 8);
        const unsigned short* w1 = Wpk + (((ob1 * 16 + kk) * 64 + lane) * 8);
        const unsigned short* w2 = Wpk + ((((ob0 + 8) * 16 + kk) * 64 + lane) * 8);
        const unsigned short* w3 = Wpk + ((((ob1 + 8) * 16 + kk) * 64 + lane) * 8);
        short8v h0 = *(const short8v*)w0;
        short8v h1 = *(const short8v*)w1;
        short8v h2 = *(const short8v*)w2;
        short8v h3 = *(const short8v*)w3;
        short8v e0 = *(const short8v*)(w0 + 131072);
        short8v e1 = *(const short8v*)(w1 + 131072);
        short8v e2 = *(const short8v*)(w2 + 131072);
        short8v e3 = *(const short8v*)(w3 + 131072);
        acc0 = __builtin_amdgcn_mfma_f32_32x32x16_bf16(a, h0, acc0, 0, 0, 0);
        acc1 = __builtin_amdgcn_mfma_f32_32x32x16_bf16(a, h1, acc1, 0, 0, 0);
        acc2 = __builtin_amdgcn_mfma_f32_32x32x16_bf16(a, h2, acc2, 0, 0, 0);
        acc3 = __builtin_amdgcn_mfma_f32_32x32x16_bf16(a, h3, acc3, 0, 0, 0);
        acc0 = __builtin_amdgcn_mfma_f32_32x32x16_bf16(a, e0, acc0, 0, 0, 0);
        acc1 = __builtin_amdgcn_mfma_f32_32x32x16_bf16(a, e1, acc1, 0, 0, 0);
        acc2 = __builtin_amdgcn_mfma_f32_32x32x16_bf16(a, e2, acc2, 0, 0, 0);
        acc3 = __builtin_amdgcn_mfma_f32_32x32x16_bf16(a, e3, acc3, 0, 0, 0);
    }
    #pragma unroll
    for (int p = 0; p < 2; ++p) {
        const f32x16& z1v = p ? acc1 : acc0;
        const f32x16& z2v = p ? acc3 : acc2;
        int o = (p ? ob1 : ob0) * 32 + (lane & 31);
        float b1 = bias[o], b2 = bias[o + 256];
        #pragma unroll
        for (int rr = 0; rr < 16; ++rr) {
            int ll = l0 + (rr & 3) + 8 * (rr >> 2) + 4 * (lane >> 5);
            float z1 = z1v[rr] + b1;
            float z2 = z2v[rr] + b2;
            vout[((size_t)b * L_SEQ + ll) * H_DIM + o] = z1 / (1.f + expf(-z2));
        }
    }
}

// ---------------------------------------------------------------------------
// Fused residual + LayerNorm over channel dim.
// Reads vin [B][L][256] (GLU out) + xhl [B][256][L] (residual, via LDS
// transpose); writes x_new = LN(v + x) back to xhl [B][256][L].
// ---------------------------------------------------------------------------
__global__ __launch_bounds__(256) void ln_fuse(
    const float* __restrict__ vin, float* __restrict__ xhl,
    const float* __restrict__ lg, const float* __restrict__ lb)
{
    __shared__ float ld[16][260];
    const int w = threadIdx.x >> 6, lane = threadIdx.x & 63;
    const int b = blockIdx.y, l0 = blockIdx.x * 16;
    {
        const float* src = xhl + ((size_t)b * H_DIM + threadIdx.x) * L_SEQ + l0;
        #pragma unroll
        for (int u4 = 0; u4 < 4; ++u4) {
            float4 q = *(const float4*)(src + u4 * 4);
            ld[u4 * 4 + 0][threadIdx.x] = q.x;
            ld[u4 * 4 + 1][threadIdx.x] = q.y;
            ld[u4 * 4 + 2][threadIdx.x] = q.z;
            ld[u4 * 4 + 3][threadIdx.x] = q.w;
        }
    }
    __syncthreads();
    float4 g4 = *(const float4*)(lg + lane * 4);
    float4 b4 = *(const float4*)(lb + lane * 4);
    #pragma unroll
    for (int rr = 0; rr < 4; ++rr) {
        int row = rr * 4 + w;
        float4 xv = *(const float4*)(vin + ((size_t)b * L_SEQ + l0 + row) * H_DIM + lane * 4);
        xv.x += ld[row][lane * 4 + 0];
        xv.y += ld[row][lane * 4 + 1];
        xv.z += ld[row][lane * 4 + 2];
        xv.w += ld[row][lane * 4 + 3];
        float s = xv.x + xv.y + xv.z + xv.w;
        float sq = xv.x * xv.x + xv.y * xv.y + xv.z * xv.z + xv.w * xv.w;
        #pragma unroll
        for (int st = 1; st < 64; st <<= 1) {
            s += __shfl_xor(s, st);
            sq += __shfl_xor(sq, st);
        }
        float mean = s * (1.f / H_DIM);
        float var = sq * (1.f / H_DIM) - mean * mean;
        float rstd = rsqrtf(var + 1e-5f);
        ld[row][lane * 4 + 0] = (xv.x - mean) * rstd * g4.x + b4.x;
        ld[row][lane * 4 + 1] = (xv.y - mean) * rstd * g4.y + b4.y;
        ld[row][lane * 4 + 2] = (xv.z - mean) * rstd * g4.z + b4.z;
        ld[row][lane * 4 + 3] = (xv.w - mean) * rstd * g4.w + b4.w;
    }
    __syncthreads();
    {
        float* dst = xhl + ((size_t)b * H_DIM + threadIdx.x) * L_SEQ + l0;
        #pragma unroll
        for (int u4 = 0; u4 < 4; ++u4) {
            float4 o;
            o.x = ld[u4 * 4 + 0][threadIdx.x];
            o.y = ld[u4 * 4 + 1][threadIdx.x];
            o.z = ld[u4 * 4 + 2][threadIdx.x];
            o.w = ld[u4 * 4 + 3][threadIdx.x];
            *(float4*)(dst + u4 * 4) = o;
        }
    }
}

// ---------------------------------------------------------------------------
// Mean over time per (b,h); then tiny decode.
// ---------------------------------------------------------------------------
__global__ __launch_bounds__(256) void pool_mean(
    const float* __restrict__ x, float* __restrict__ meanb)
{
    __shared__ float red[256];
    const int bh = blockIdx.x;
    const float* row = x + (size_t)bh * L_SEQ;
    float s = 0.f;
    for (int i = threadIdx.x; i < L_SEQ; i += 256) s += row[i];
    red[threadIdx.x] = s;
    __syncthreads();
    for (int st = 128; st > 0; st >>= 1) {
        if (threadIdx.x < st) red[threadIdx.x] += red[threadIdx.x + st];
        __syncthreads();
    }
    if (threadIdx.x == 0) meanb[bh] = red[0] * (1.f / L_SEQ);
}

__global__ __launch_bounds__(256) void decode(
    const float* __restrict__ meanb, const float* __restrict__ dw,
    const float* __restrict__ db, float* __restrict__ out)
{
    int i = threadIdx.x;
    if (i >= BATCH * 10) return;
    int b = i / 10, d = i % 10;
    float s = db[d];
    for (int h = 0; h < H_DIM; ++h)
        s = fmaf(meanb[b * H_DIM + h], dw[d * H_DIM + h], s);
    out[i] = s;
}

// ---------------------------------------------------------------------------
extern "C" void kernel_launch(void* const* d_in, const int* in_sizes, int n_in,
                              void* d_out, int out_size, void* d_ws, size_t ws_size,
                              hipStream_t stream)
{
    const float* x_in = (const float*)d_in[0];
    const float* cw[3] = {(const float*)d_in[1], (const float*)d_in[7],  (const float*)d_in[13]};
    const float* cb[3] = {(const float*)d_in[2], (const float*)d_in[8],  (const float*)d_in[14]};
    const float* bg[3] = {(const float*)d_in[3], (const float*)d_in[9],  (const float*)d_in[15]};
    const float* bb[3] = {(const float*)d_in[4], (const float*)d_in[10], (const float*)d_in[16]};
    const float* bm[3] = {(const float*)d_in[5], (const float*)d_in[11], (const float*)d_in[17]};
    const float* bv[3] = {(const float*)d_in[6], (const float*)d_in[12], (const float*)d_in[18]};
    const float* log_dt   = (const float*)d_in[19];
    const float* A_re_log = (const float*)d_in[20];
    const float* A_im     = (const float*)d_in[21];
    const float* C_re     = (const float*)d_in[22];
    const float* C_im     = (const float*)d_in[23];
    const float* Dv       = (const float*)d_in[24];
    const float* out_w    = (const float*)d_in[25];
    const float* out_b    = (const float*)d_in[26];
    const float* ln_g     = (const float*)d_in[27];
    const float* ln_b     = (const float*)d_in[28];
    const float* dec_w    = (const float*)d_in[29];
    const float* dec_b    = (const float*)d_in[30];

    const size_t PLANE = (size_t)BATCH * H_DIM * L_SEQ;       // 16,777,216 floats
    float* ws = (float*)d_ws;
    float* xhl  = ws;                                         // [B][256][L] fp32
    float* yv   = ws + PLANE;                                 // conv temps / GLU out
    unsigned short* ybf = (unsigned short*)(ws + 2 * PLANE);  // [B][H][L] bf16
    float* AR = ws + 2 * PLANE + PLANE / 2;
    float* AI = AR + (size_t)BATCH * H_DIM * NCHUNK * 64;
    unsigned short* Wpk = (unsigned short*)(AI + (size_t)BATCH * H_DIM * NCHUNK * 64);
    float* modes = (float*)(Wpk + 4 * 262144);
    float* mwr = modes, *mwi = modes + 65536, *mcr = modes + 2 * 65536,
         *mci = modes + 3 * 65536, *mtr = modes + 4 * 65536, *mti = modes + 5 * 65536;
    float* meanb = modes + 6 * 65536;

    precompute_modes<<<256, 256, 0, stream>>>(log_dt, A_re_log, A_im, C_re, C_im,
                                              mwr, mwi, mcr, mci, mtr, mti);
    precompute_wpk<<<256, 256, 0, stream>>>(out_w, Wpk);

    // Encoder: x_in -> c1p (padded) -> c2p (padded) -> xhl
    float* c1p = yv;                                          // 16*64*LPAD
    float* c2p = yv + (size_t)BATCH * 64 * LPAD;              // 16*128*LPAD
    conv_bn_relu_f<1, 7, false, true><<<dim3(16, 2, 16), 256, 0, stream>>>(
        x_in, c1p, cw[0], cb[0], bg[0], bb[0], bm[0], bv[0], 64);
    conv_bn_relu_f<64, 5, true, true><<<dim3(16, 4, 16), 256, 0, stream>>>(
        c1p, c2p, cw[1], cb[1], bg[1], bb[1], bm[1], bv[1], 128);
    conv_bn_relu_f<128, 3, true, false><<<dim3(16, 8, 16), 256, 0, stream>>>(
        c2p, xhl, cw[2], cb[2], bg[2], bb[2], bm[2], bv[2], 256);

    for (int l = 0; l < 4; ++l) {
        const int moff = l * H_DIM * N_MODES;
        s4d_state<<<dim3(BATCH * H_DIM * 7 / 4), 256, 0, stream>>>(
            xhl, mwr + moff, mwi + moff, AR, AI);
        s4d_combine<<<dim3(BATCH * H_DIM / 4), 256, 0, stream>>>(
            mtr + moff, mti + moff, AR, AI);
        s4d_scan2<<<dim3(BATCH * H_DIM * NCHUNK / 4), 256, 0, stream>>>(
            xhl, mwr + moff, mwi + moff, mcr + moff, mci + moff,
            Dv + l * H_DIM, AR, AI, ybf);
        linear_glu_mfma2<<<dim3(128, 16), 256, 0, stream>>>(
            ybf, Wpk + (size_t)l * 262144, out_b + l * 512, yv);
        ln_fuse<<<dim3(256, 16), 256, 0, stream>>>(
            yv, xhl, ln_g + l * H_DIM, ln_b + l * H_DIM);
    }

    pool_mean<<<dim3(BATCH * H_DIM), 256, 0, stream>>>(xhl, meanb);
    decode<<<dim3(1), 256, 0, stream>>>(meanb, dec_w, dec_b, (float*)d_out);
}

// Round 5
// 1601.140 us; speedup vs baseline: 2.5668x; 1.3692x over previous
//
#include <hip/hip_runtime.h>
#include <cstdint>
#include <cstddef>

#define L_SEQ 4096
#define H_DIM 256
#define N_MODES 64
#define BATCH 16
#define QCH 128
#define NCHUNK 32
#define LPAD (L_SEQ + 8)

typedef __attribute__((ext_vector_type(8))) short short8v;
typedef __attribute__((ext_vector_type(16))) float f32x16;

__device__ __forceinline__ unsigned short f2bf(float f) {
    unsigned u = __float_as_uint(f);
    u = u + 0x7fff + ((u >> 16) & 1);
    return (unsigned short)(u >> 16);
}
__device__ __forceinline__ float bf2f(unsigned short h) {
    return __uint_as_float(((unsigned)h) << 16);
}

// packed B-fragment position for 32x32x16 bf16: entry (k, col)
__device__ __forceinline__ int bpos(int k, int col) {
    return ((col >> 5) * 8 + (k >> 4)) * 512 + ((col & 31) + 32 * ((k >> 3) & 1)) * 8 + (k & 7);
}
__device__ __forceinline__ void wpack(unsigned short* M, int k, int col, float v) {
    int p = bpos(k, col);
    unsigned short hi = f2bf(v);
    M[p] = hi;
    M[p + 16384] = f2bf(v - bf2f(hi));
}

// ---------------------------------------------------------------------------
// Per-layer S4D matrices: V (states), E (inter-chunk), Ktab (Toeplitz gen), wQ.
// 1 wave per h, lane = mode n. p walks w^d.
// ---------------------------------------------------------------------------
__global__ __launch_bounds__(256) void mats_gen(
    const float* __restrict__ log_dt, const float* __restrict__ A_re_log,
    const float* __restrict__ A_im, const float* __restrict__ C_re,
    const float* __restrict__ C_im, const float* __restrict__ Dv, int layer,
    unsigned short* __restrict__ Vpk, unsigned short* __restrict__ Epk,
    float* __restrict__ Ktab, float* __restrict__ wqbuf)
{
    const int wv = threadIdx.x >> 6, n = threadIdx.x & 63;
    const int h = blockIdx.x * 4 + wv;
    const int idx = (layer * H_DIM + h) * N_MODES + n;
    float dt = expf(log_dt[layer * H_DIM + h]);
    float Ar = -expf(A_re_log[idx]);
    float Ai = A_im[idx];
    float dr = Ar * dt, di = Ai * dt;
    float er = expf(dr);
    float wr = er * cosf(di), wi = er * sinf(di);
    float nr = wr - 1.f, ni = wi;
    float Cr = C_re[idx], Ci = C_im[idx];
    float pr_ = Cr * nr - Ci * ni;
    float pi_ = Cr * ni + Ci * nr;
    float inv = 1.f / (Ar * Ar + Ai * Ai);
    float c2r = 2.f * (pr_ * Ar + pi_ * Ai) * inv;
    float c2i = 2.f * (pi_ * Ar - pr_ * Ai) * inv;
    float Dh = Dv[layer * H_DIM + h];
    unsigned short* Vh = Vpk + h * 32768;
    unsigned short* Eh = Epk + h * 32768;
    float pr = 1.f, pi = 0.f;                       // p = w^d
    for (int d = 0; d <= QCH; ++d) {
        float qr = c2r * pr - c2i * pi;             // q = c2 * w^d
        float qi = c2r * pi + c2i * pr;
        if (d <= QCH - 1) {
            int t = QCH - 1 - d;                    // V[t][2n]=Re(w^{127-t})
            wpack(Vh, t, 2 * n, pr);
            wpack(Vh, t, 2 * n + 1, pi);
            float s = qr;                           // K[d] = Re(sum c2 w^d)
            #pragma unroll
            for (int st = 1; st < 64; st <<= 1) s += __shfl_xor(s, st);
            if (n == 0) Ktab[h * QCH + d] = s + (d == 0 ? Dh : 0.f);
        }
        if (d >= 1) {
            int t = d - 1;                          // E[2n][t]=Re(c2 w^{t+1})
            wpack(Eh, 2 * n, t, qr);
            wpack(Eh, 2 * n + 1, t, -qi);
        }
        if (d == QCH) {
            wqbuf[(h * 64 + n) * 2 + 0] = pr;       // wQ = w^128
            wqbuf[(h * 64 + n) * 2 + 1] = pi;
        }
        float npr = pr * wr - pi * wi;
        float npi = pr * wi + pi * wr;
        pr = npr; pi = npi;
    }
}

// ---------------------------------------------------------------------------
// Fill packed Toeplitz T from Ktab: B[j][t] = K'[t-j] (t>=j).
// ---------------------------------------------------------------------------
__global__ __launch_bounds__(256) void tfill(
    const float* __restrict__ Ktab, unsigned short* __restrict__ Tpk)
{
    int t0 = blockIdx.x * 256 + threadIdx.x;   // 256h x 2048 groups
    int h = t0 >> 11;
    int g = t0 & 2047;
    int nt = g >> 9;
    int ks = (g >> 6) & 7;
    int lane8 = g & 63;
    int col = nt * 32 + (lane8 & 31);
    int k0 = ks * 16 + (lane8 >> 5) * 8;
    const float* Kh = Ktab + h * QCH;
    union { unsigned short s[8]; uint4 v; } hi, lo;
    #pragma unroll
    for (int j = 0; j < 8; ++j) {
        int d = col - (k0 + j);
        float val = (d >= 0) ? Kh[d] : 0.f;
        hi.s[j] = f2bf(val);
        lo.s[j] = f2bf(val - bf2f(hi.s[j]));
    }
    unsigned short* dst = Tpk + h * 32768 + (nt * 8 + ks) * 512 + lane8 * 8;
    *(uint4*)dst = hi.v;
    *(uint4*)(dst + 16384) = lo.v;
}

// ---------------------------------------------------------------------------
// Conv1d('same') + BN(eval) + ReLU (validated round-4 version).
// ---------------------------------------------------------------------------
template<int CI, int K, bool PIN, bool POUT>
__global__ __launch_bounds__(256) void conv_bn_relu_f(
    const float* __restrict__ in, float* __restrict__ out,
    const float* __restrict__ wg, const float* __restrict__ cb,
    const float* __restrict__ g, const float* __restrict__ bb,
    const float* __restrict__ m, const float* __restrict__ v, int CO)
{
    const int wv = threadIdx.x >> 6, lane = threadIdx.x & 63;
    const int b = blockIdx.z;
    const int co0 = __builtin_amdgcn_readfirstlane(blockIdx.y * 32 + wv * 8);
    const int l = blockIdx.x * 256 + lane * 4;
    const int ILD = PIN ? LPAD : L_SEQ;
    const int OLD = POUT ? LPAD : L_SEQ;
    const int OFF = K / 2;
    float acc[8][4] = {};
    const float* inb = in + (size_t)b * CI * ILD + (PIN ? 4 : 0);

    if (PIN) {
        #pragma unroll 2
        for (int ci = 0; ci < CI; ++ci) {
            const float* row = inb + (size_t)ci * ILD + l;
            float4 A = *(const float4*)(row - 4);
            float4 Bv = *(const float4*)(row);
            float4 Cv = *(const float4*)(row + 4);
            float win[12] = {A.x, A.y, A.z, A.w, Bv.x, Bv.y, Bv.z, Bv.w,
                             Cv.x, Cv.y, Cv.z, Cv.w};
            #pragma unroll
            for (int cc = 0; cc < 8; ++cc) {
                #pragma unroll
                for (int k = 0; k < K; ++k) {
                    float wk = wg[((size_t)(co0 + cc) * CI + ci) * K + k];
                    #pragma unroll
                    for (int j = 0; j < 4; ++j)
                        acc[cc][j] = fmaf(win[4 + j + k - OFF], wk, acc[cc][j]);
                }
            }
        }
    } else {
        for (int ci = 0; ci < CI; ++ci) {
            const float* row = inb + (size_t)ci * ILD;
            float win[12];
            #pragma unroll
            for (int d = 0; d < 12; ++d) {
                int li = l - 4 + d;
                win[d] = (li >= 0 && li < L_SEQ) ? row[li] : 0.f;
            }
            #pragma unroll
            for (int cc = 0; cc < 8; ++cc) {
                #pragma unroll
                for (int k = 0; k < K; ++k) {
                    float wk = wg[((size_t)(co0 + cc) * CI + ci) * K + k];
                    #pragma unroll
                    for (int j = 0; j < 4; ++j)
                        acc[cc][j] = fmaf(win[4 + j + k - OFF], wk, acc[cc][j]);
                }
            }
        }
    }
    #pragma unroll
    for (int cc = 0; cc < 8; ++cc) {
        int co = co0 + cc;
        float s = g[co] * rsqrtf(v[co] + 1e-5f);
        float sh = (cb[co] - m[co]) * s + bb[co];
        float* orow = out + ((size_t)b * CO + co) * OLD + (POUT ? 4 : 0);
        float4 o4;
        o4.x = fmaxf(fmaf(acc[cc][0], s, sh), 0.f);
        o4.y = fmaxf(fmaf(acc[cc][1], s, sh), 0.f);
        o4.z = fmaxf(fmaf(acc[cc][2], s, sh), 0.f);
        o4.w = fmaxf(fmaf(acc[cc][3], s, sh), 0.f);
        *(float4*)(orow + l) = o4;
        if (POUT) {
            if (blockIdx.x == 0 && lane == 0)
                *(float4*)(orow - 4) = make_float4(0.f, 0.f, 0.f, 0.f);
            if (blockIdx.x == gridDim.x - 1 && lane == 63)
                *(float4*)(orow + L_SEQ) = make_float4(0.f, 0.f, 0.f, 0.f);
        }
    }
}

// ---------------------------------------------------------------------------
// S4D states GEMM: S[(b,c), n'] = sum_t u[(b,c), t] * V[t][n'].  Per-h batched.
// Block: 4 waves, M-tile 128 (4 b x 32 c), K=128, N=128. A staged hi/lo in LDS.
// ---------------------------------------------------------------------------
__global__ __launch_bounds__(256) void s4d_gemm_states(
    const float* __restrict__ u, const unsigned short* __restrict__ Vpk,
    float* __restrict__ Sbuf)
{
    __shared__ __align__(16) unsigned short As0[16384];
    __shared__ __align__(16) unsigned short As1[16384];
    const int h = blockIdx.y;
    const int b0 = blockIdx.x * 4;
    const int wv = threadIdx.x >> 6, lane = threadIdx.x & 63;
    const float* ub = u + ((size_t)b0 * H_DIM + h) * L_SEQ;
    #pragma unroll
    for (int i = 0; i < 16; ++i) {
        int idx = threadIdx.x + i * 256;
        int bl = idx >> 10;
        int pos = (idx & 1023) * 4;
        float4 q = *(const float4*)(ub + (size_t)bl * H_DIM * L_SEQ + pos);
        int m = bl * 32 + (pos >> 7);
        int k = pos & 127;
        int byte0 = (m * 256 + k * 2) ^ ((m & 7) << 4);
        ushort4 hv, lv;
        hv.x = f2bf(q.x); lv.x = f2bf(q.x - bf2f(hv.x));
        hv.y = f2bf(q.y); lv.y = f2bf(q.y - bf2f(hv.y));
        hv.z = f2bf(q.z); lv.z = f2bf(q.z - bf2f(hv.z));
        hv.w = f2bf(q.w); lv.w = f2bf(q.w - bf2f(hv.w));
        *(ushort4*)((char*)As0 + byte0) = hv;
        *(ushort4*)((char*)As1 + byte0) = lv;
    }
    __syncthreads();
    const unsigned short* Vh = Vpk + h * 32768;
    f32x16 acc0 = {}, acc1 = {}, acc2 = {}, acc3 = {};
    #pragma unroll
    for (int ks = 0; ks < 8; ++ks) {
        int abyte = ((32 * wv + (lane & 31)) * 256 + (ks * 16 + (lane >> 5) * 8) * 2)
                    ^ ((lane & 7) << 4);
        short8v ah = *(const short8v*)((const char*)As0 + abyte);
        short8v al = *(const short8v*)((const char*)As1 + abyte);
        const unsigned short* vb = Vh + ks * 512 + lane * 8;
        short8v b0h = *(const short8v*)(vb);
        short8v b1h = *(const short8v*)(vb + 4096);
        short8v b2h = *(const short8v*)(vb + 8192);
        short8v b3h = *(const short8v*)(vb + 12288);
        short8v b0l = *(const short8v*)(vb + 16384);
        short8v b1l = *(const short8v*)(vb + 20480);
        short8v b2l = *(const short8v*)(vb + 24576);
        short8v b3l = *(const short8v*)(vb + 28672);
        acc0 = __builtin_amdgcn_mfma_f32_32x32x16_bf16(ah, b0h, acc0, 0, 0, 0);
        acc1 = __builtin_amdgcn_mfma_f32_32x32x16_bf16(ah, b1h, acc1, 0, 0, 0);
        acc2 = __builtin_amdgcn_mfma_f32_32x32x16_bf16(ah, b2h, acc2, 0, 0, 0);
        acc3 = __builtin_amdgcn_mfma_f32_32x32x16_bf16(ah, b3h, acc3, 0, 0, 0);
        acc0 = __builtin_amdgcn_mfma_f32_32x32x16_bf16(ah, b0l, acc0, 0, 0, 0);
        acc1 = __builtin_amdgcn_mfma_f32_32x32x16_bf16(ah, b1l, acc1, 0, 0, 0);
        acc2 = __builtin_amdgcn_mfma_f32_32x32x16_bf16(ah, b2l, acc2, 0, 0, 0);
        acc3 = __builtin_amdgcn_mfma_f32_32x32x16_bf16(ah, b3l, acc3, 0, 0, 0);
        acc0 = __builtin_amdgcn_mfma_f32_32x32x16_bf16(al, b0h, acc0, 0, 0, 0);
        acc1 = __builtin_amdgcn_mfma_f32_32x32x16_bf16(al, b1h, acc1, 0, 0, 0);
        acc2 = __builtin_amdgcn_mfma_f32_32x32x16_bf16(al, b2h, acc2, 0, 0, 0);
        acc3 = __builtin_amdgcn_mfma_f32_32x32x16_bf16(al, b3h, acc3, 0, 0, 0);
    }
    float* Sh = Sbuf + ((size_t)h * 16 + b0) * 4096;
    #pragma unroll
    for (int nt = 0; nt < 4; ++nt) {
        const f32x16& a = nt == 0 ? acc0 : nt == 1 ? acc1 : nt == 2 ? acc2 : acc3;
        int col = nt * 32 + (lane & 31);
        #pragma unroll
        for (int r = 0; r < 16; ++r) {
            int m = 32 * wv + (r & 3) + 8 * (r >> 2) + 4 * (lane >> 5);
            Sh[(size_t)m * 128 + col] = a[r];
        }
    }
}

// ---------------------------------------------------------------------------
// Prefix combine (in place): P[c] = wQ*P[c-1] + S[c-1], P[0] = 0.
// ---------------------------------------------------------------------------
__global__ __launch_bounds__(256) void s4d_combine2(
    const float* __restrict__ wqbuf, float* __restrict__ Sbuf)
{
    const int n = threadIdx.x & 63;
    const int hb = blockIdx.x * 4 + (threadIdx.x >> 6);
    const float2 wq = *(const float2*)(wqbuf + ((hb >> 4) * 64 + n) * 2);
    float* base = Sbuf + (size_t)hb * 4096 + 2 * n;
    float Pr = 0.f, Pi = 0.f;
    for (int c = 0; c < NCHUNK; ++c) {
        float2 s = *(const float2*)(base + c * 128);
        *(float2*)(base + c * 128) = make_float2(Pr, Pi);
        float npr = fmaf(wq.x, Pr, fmaf(-wq.y, Pi, s.x));
        float npi = fmaf(wq.x, Pi, fmaf(wq.y, Pr, s.y));
        Pr = npr; Pi = npi;
    }
}

// ---------------------------------------------------------------------------
// S4D output GEMM: y[(b,c), t] = P x E  +  u x T   (+GELU, bf16 store).
// Two K-phases share one LDS A-tile buffer.
// ---------------------------------------------------------------------------
__global__ __launch_bounds__(256) void s4d_gemm_out(
    const float* __restrict__ u, const float* __restrict__ Pbuf,
    const unsigned short* __restrict__ Epk, const unsigned short* __restrict__ Tpk,
    unsigned short* __restrict__ ybf)
{
    __shared__ __align__(16) unsigned short As0[16384];
    __shared__ __align__(16) unsigned short As1[16384];
    const int h = blockIdx.y;
    const int b0 = blockIdx.x * 4;
    const int wv = threadIdx.x >> 6, lane = threadIdx.x & 63;
    f32x16 acc0 = {}, acc1 = {}, acc2 = {}, acc3 = {};

    // ---- phase 1: P-tile (contiguous) x E
    {
        const float* Ph = Pbuf + ((size_t)h * 16 + b0) * 4096;
        #pragma unroll
        for (int i = 0; i < 16; ++i) {
            int idx = threadIdx.x + i * 256;
            float4 q = *(const float4*)(Ph + (size_t)idx * 4);
            int m = idx >> 5;
            int k = (idx & 31) * 4;
            int byte0 = (m * 256 + k * 2) ^ ((m & 7) << 4);
            ushort4 hv, lv;
            hv.x = f2bf(q.x); lv.x = f2bf(q.x - bf2f(hv.x));
            hv.y = f2bf(q.y); lv.y = f2bf(q.y - bf2f(hv.y));
            hv.z = f2bf(q.z); lv.z = f2bf(q.z - bf2f(hv.z));
            hv.w = f2bf(q.w); lv.w = f2bf(q.w - bf2f(hv.w));
            *(ushort4*)((char*)As0 + byte0) = hv;
            *(ushort4*)((char*)As1 + byte0) = lv;
        }
        __syncthreads();
        const unsigned short* Eh = Epk + h * 32768;
        #pragma unroll
        for (int ks = 0; ks < 8; ++ks) {
            int abyte = ((32 * wv + (lane & 31)) * 256 + (ks * 16 + (lane >> 5) * 8) * 2)
                        ^ ((lane & 7) << 4);
            short8v ah = *(const short8v*)((const char*)As0 + abyte);
            short8v al = *(const short8v*)((const char*)As1 + abyte);
            const unsigned short* eb = Eh + ks * 512 + lane * 8;
            short8v b0h = *(const short8v*)(eb);
            short8v b1h = *(const short8v*)(eb + 4096);
            short8v b2h = *(const short8v*)(eb + 8192);
            short8v b3h = *(const short8v*)(eb + 12288);
            short8v b0l = *(const short8v*)(eb + 16384);
            short8v b1l = *(const short8v*)(eb + 20480);
            short8v b2l = *(const short8v*)(eb + 24576);
            short8v b3l = *(const short8v*)(eb + 28672);
            acc0 = __builtin_amdgcn_mfma_f32_32x32x16_bf16(ah, b0h, acc0, 0, 0, 0);
            acc1 = __builtin_amdgcn_mfma_f32_32x32x16_bf16(ah, b1h, acc1, 0, 0, 0);
            acc2 = __builtin_amdgcn_mfma_f32_32x32x16_bf16(ah, b2h, acc2, 0, 0, 0);
            acc3 = __builtin_amdgcn_mfma_f32_32x32x16_bf16(ah, b3h, acc3, 0, 0, 0);
            acc0 = __builtin_amdgcn_mfma_f32_32x32x16_bf16(ah, b0l, acc0, 0, 0, 0);
            acc1 = __builtin_amdgcn_mfma_f32_32x32x16_bf16(ah, b1l, acc1, 0, 0, 0);
            acc2 = __builtin_amdgcn_mfma_f32_32x32x16_bf16(ah, b2l, acc2, 0, 0, 0);
            acc3 = __builtin_amdgcn_mfma_f32_32x32x16_bf16(ah, b3l, acc3, 0, 0, 0);
            acc0 = __builtin_amdgcn_mfma_f32_32x32x16_bf16(al, b0h, acc0, 0, 0, 0);
            acc1 = __builtin_amdgcn_mfma_f32_32x32x16_bf16(al, b1h, acc1, 0, 0, 0);
            acc2 = __builtin_amdgcn_mfma_f32_32x32x16_bf16(al, b2h, acc2, 0, 0, 0);
            acc3 = __builtin_amdgcn_mfma_f32_32x32x16_bf16(al, b3h, acc3, 0, 0, 0);
        }
        __syncthreads();
    }

    // ---- phase 2: u-tile x T
    {
        const float* ub = u + ((size_t)b0 * H_DIM + h) * L_SEQ;
        #pragma unroll
        for (int i = 0; i < 16; ++i) {
            int idx = threadIdx.x + i * 256;
            int bl = idx >> 10;
            int pos = (idx & 1023) * 4;
            float4 q = *(const float4*)(ub + (size_t)bl * H_DIM * L_SEQ + pos);
            int m = bl * 32 + (pos >> 7);
            int k = pos & 127;
            int byte0 = (m * 256 + k * 2) ^ ((m & 7) << 4);
            ushort4 hv, lv;
            hv.x = f2bf(q.x); lv.x = f2bf(q.x - bf2f(hv.x));
            hv.y = f2bf(q.y); lv.y = f2bf(q.y - bf2f(hv.y));
            hv.z = f2bf(q.z); lv.z = f2bf(q.z - bf2f(hv.z));
            hv.w = f2bf(q.w); lv.w = f2bf(q.w - bf2f(hv.w));
            *(ushort4*)((char*)As0 + byte0) = hv;
            *(ushort4*)((char*)As1 + byte0) = lv;
        }
        __syncthreads();
        const unsigned short* Th = Tpk + h * 32768;
        #pragma unroll
        for (int ks = 0; ks < 8; ++ks) {
            int abyte = ((32 * wv + (lane & 31)) * 256 + (ks * 16 + (lane >> 5) * 8) * 2)
                        ^ ((lane & 7) << 4);
            short8v ah = *(const short8v*)((const char*)As0 + abyte);
            short8v al = *(const short8v*)((const char*)As1 + abyte);
            const unsigned short* tb = Th + ks * 512 + lane * 8;
            short8v b0h = *(const short8v*)(tb);
            short8v b1h = *(const short8v*)(tb + 4096);
            short8v b2h = *(const short8v*)(tb + 8192);
            short8v b3h = *(const short8v*)(tb + 12288);
            short8v b0l = *(const short8v*)(tb + 16384);
            short8v b1l = *(const short8v*)(tb + 20480);
            short8v b2l = *(const short8v*)(tb + 24576);
            short8v b3l = *(const short8v*)(tb + 28672);
            acc0 = __builtin_amdgcn_mfma_f32_32x32x16_bf16(ah, b0h, acc0, 0, 0, 0);
            acc1 = __builtin_amdgcn_mfma_f32_32x32x16_bf16(ah, b1h, acc1, 0, 0, 0);
            acc2 = __builtin_amdgcn_mfma_f32_32x32x16_bf16(ah, b2h, acc2, 0, 0, 0);
            acc3 = __builtin_amdgcn_mfma_f32_32x32x16_bf16(ah, b3h, acc3, 0, 0, 0);
            acc0 = __builtin_amdgcn_mfma_f32_32x32x16_bf16(ah, b0l, acc0, 0, 0, 0);
            acc1 = __builtin_amdgcn_mfma_f32_32x32x16_bf16(ah, b1l, acc1, 0, 0, 0);
            acc2 = __builtin_amdgcn_mfma_f32_32x32x16_bf16(ah, b2l, acc2, 0, 0, 0);
            acc3 = __builtin_amdgcn_mfma_f32_32x32x16_bf16(ah, b3l, acc3, 0, 0, 0);
            acc0 = __builtin_amdgcn_mfma_f32_32x32x16_bf16(al, b0h, acc0, 0, 0, 0);
            acc1 = __builtin_amdgcn_mfma_f32_32x32x16_bf16(al, b1h, acc1, 0, 0, 0);
            acc2 = __builtin_amdgcn_mfma_f32_32x32x16_bf16(al, b2h, acc2, 0, 0, 0);
            acc3 = __builtin_amdgcn_mfma_f32_32x32x16_bf16(al, b3h, acc3, 0, 0, 0);
        }
    }

    // ---- epilogue: GELU -> bf16 store to ybf[b][h][c*128 + t]
    #pragma unroll
    for (int nt = 0; nt < 4; ++nt) {
        const f32x16& a = nt == 0 ? acc0 : nt == 1 ? acc1 : nt == 2 ? acc2 : acc3;
        int t = nt * 32 + (lane & 31);
        #pragma unroll
        for (int r = 0; r < 16; ++r) {
            int m = 32 * wv + (r & 3) + 8 * (r >> 2) + 4 * (lane >> 5);
            int bl = m >> 5, c = m & 31;
            float yv = a[r];
            float yc = fmaf(0.044715f * yv, yv * yv, yv);
            float tg = tanhf(0.79788456f * yc);
            float outv = 0.5f * yv * (1.f + tg);
            ybf[((size_t)(b0 + bl) * H_DIM + h) * L_SEQ + c * QCH + t] = f2bf(outv);
        }
    }
}

// ---------------------------------------------------------------------------
// W -> packed MFMA B-fragment order, bf16 hi/lo planes (GLU linear).
// ---------------------------------------------------------------------------
__global__ __launch_bounds__(256) void precompute_wpk(
    const float* __restrict__ W, unsigned short* __restrict__ Wpk)
{
    int t = blockIdx.x * 256 + threadIdx.x;
    if (t >= 4 * 16 * 16 * 64) return;
    int lane = t & 63;
    int kk = (t >> 6) & 15;
    int ob = (t >> 10) & 15;
    int layer = t >> 14;
    int o = ob * 32 + (lane & 31);
    int k0 = kk * 16 + (lane >> 5) * 8;
    const float* src = W + ((size_t)layer * 512 + o) * H_DIM + k0;
    union { unsigned short s[8]; uint4 v; } hi, lo;
    #pragma unroll
    for (int j = 0; j < 8; ++j) {
        float f = src[j];
        hi.s[j] = f2bf(f);
        lo.s[j] = f2bf(f - bf2f(hi.s[j]));
    }
    size_t base = (size_t)layer * 262144 + ((size_t)((ob * 16 + kk) * 64 + lane) * 8);
    *(uint4*)(Wpk + base) = hi.v;
    *(uint4*)(Wpk + base + 131072) = lo.v;
}

// ---------------------------------------------------------------------------
// Output linear (H->2H) via MFMA; A LDS-transposed from y bf16 [B][H][L].
// ---------------------------------------------------------------------------
__global__ __launch_bounds__(256) void linear_glu_mfma2(
    const unsigned short* __restrict__ ybf,
    const unsigned short* __restrict__ Wpk,
    const float* __restrict__ bias,
    float* __restrict__ vout)
{
    __shared__ __align__(16) unsigned short As[32 * 256];
    const int lane = threadIdx.x & 63;
    const int wv = threadIdx.x >> 6;
    const int b = blockIdx.y;
    const int l0 = blockIdx.x * 32;

    const unsigned short* ybase = ybf + (size_t)b * H_DIM * L_SEQ + l0;
    #pragma unroll
    for (int p = 0; p < 4; ++p) {
        int e = threadIdx.x + p * 256;
        int hh = e >> 2, c4 = e & 3;
        union { uint4 v; unsigned short s[8]; } qv;
        qv.v = *(const uint4*)(ybase + (size_t)hh * L_SEQ + c4 * 8);
        #pragma unroll
        for (int j = 0; j < 8; ++j) {
            int lloc = c4 * 8 + j;
            int byteoff = (lloc << 9) + hh * 2;
            byteoff ^= ((lloc & 7) << 4);
            *(unsigned short*)((char*)As + byteoff) = qv.s[j];
        }
    }
    __syncthreads();

    const int ob0 = 2 * wv, ob1 = 2 * wv + 1;
    const int r = lane & 31;
    f32x16 acc0 = {}, acc1 = {}, acc2 = {}, acc3 = {};
    #pragma unroll 4
    for (int kk = 0; kk < 16; ++kk) {
        int abyte = (r << 9) | (kk * 32 + (lane >> 5) * 16);
        abyte ^= ((r & 7) << 4);
        short8v a = *(const short8v*)((char*)As + abyte);
        const unsigned short* w0 = Wpk + (((ob0 * 16 + kk) * 64 + lane) * 8);
        const unsigned short* w1 = Wpk + (((ob1 * 16 + kk) * 64 + lane) * 8);
        const unsigned short* w2 = Wpk + ((((ob0 + 8) * 16 + kk) * 64 + lane) * 8);
        const unsigned short* w3 = Wpk + ((((ob1 + 8) * 16 + kk) * 64 + lane) * 8);
        short8v h0 = *(const short8v*)w0;
        short8v h1 = *(const short8v*)w1;
        short8v h2 = *(const short8v*)w2;
        short8v h3 = *(const short8v*)w3;
        short8v e0 = *(const short8v*)(w0 + 131072);
        short8v e1 = *(const short8v*)(w1 + 131072);
        short8v e2 = *(const short8v*)(w2 + 131072);
        short8v e3 = *(const short8v*)(w3 + 131072);
        acc0 = __builtin_amdgcn_mfma_f32_32x32x16_bf16(a, h0, acc0, 0, 0, 0);
        acc1 = __builtin_amdgcn_mfma_f32_32x32x16_bf16(a, h1, acc1, 0, 0, 0);
        acc2 = __builtin_amdgcn_mfma_f32_32x32x16_bf16(a, h2, acc2, 0, 0, 0);
        acc3 = __builtin_amdgcn_mfma_f32_32x32x16_bf16(a, h3, acc3, 0, 0, 0);
        acc0 = __builtin_amdgcn_mfma_f32_32x32x16_bf16(a, e0, acc0, 0, 0, 0);
        acc1 = __builtin_amdgcn_mfma_f32_32x32x16_bf16(a, e1, acc1, 0, 0, 0);
        acc2 = __builtin_amdgcn_mfma_f32_32x32x16_bf16(a, e2, acc2, 0, 0, 0);
        acc3 = __builtin_amdgcn_mfma_f32_32x32x16_bf16(a, e3, acc3, 0, 0, 0);
    }
    #pragma unroll
    for (int p = 0; p < 2; ++p) {
        const f32x16& z1v = p ? acc1 : acc0;
        const f32x16& z2v = p ? acc3 : acc2;
        int o = (p ? ob1 : ob0) * 32 + (lane & 31);
        float b1 = bias[o], b2 = bias[o + 256];
        #pragma unroll
        for (int rr = 0; rr < 16; ++rr) {
            int ll = l0 + (rr & 3) + 8 * (rr >> 2) + 4 * (lane >> 5);
            float z1 = z1v[rr] + b1;
            float z2 = z2v[rr] + b2;
            vout[((size_t)b * L_SEQ + ll) * H_DIM + o] = z1 / (1.f + expf(-z2));
        }
    }
}

// ---------------------------------------------------------------------------
// Fused residual + LayerNorm over channel dim.
// ---------------------------------------------------------------------------
__global__ __launch_bounds__(256) void ln_fuse(
    const float* __restrict__ vin, float* __restrict__ xhl,
    const float* __restrict__ lg, const float* __restrict__ lb)
{
    __shared__ float ld[16][260];
    const int w = threadIdx.x >> 6, lane = threadIdx.x & 63;
    const int b = blockIdx.y, l0 = blockIdx.x * 16;
    {
        const float* src = xhl + ((size_t)b * H_DIM + threadIdx.x) * L_SEQ + l0;
        #pragma unroll
        for (int u4 = 0; u4 < 4; ++u4) {
            float4 q = *(const float4*)(src + u4 * 4);
            ld[u4 * 4 + 0][threadIdx.x] = q.x;
            ld[u4 * 4 + 1][threadIdx.x] = q.y;
            ld[u4 * 4 + 2][threadIdx.x] = q.z;
            ld[u4 * 4 + 3][threadIdx.x] = q.w;
        }
    }
    __syncthreads();
    float4 g4 = *(const float4*)(lg + lane * 4);
    float4 b4 = *(const float4*)(lb + lane * 4);
    #pragma unroll
    for (int rr = 0; rr < 4; ++rr) {
        int row = rr * 4 + w;
        float4 xv = *(const float4*)(vin + ((size_t)b * L_SEQ + l0 + row) * H_DIM + lane * 4);
        xv.x += ld[row][lane * 4 + 0];
        xv.y += ld[row][lane * 4 + 1];
        xv.z += ld[row][lane * 4 + 2];
        xv.w += ld[row][lane * 4 + 3];
        float s = xv.x + xv.y + xv.z + xv.w;
        float sq = xv.x * xv.x + xv.y * xv.y + xv.z * xv.z + xv.w * xv.w;
        #pragma unroll
        for (int st = 1; st < 64; st <<= 1) {
            s += __shfl_xor(s, st);
            sq += __shfl_xor(sq, st);
        }
        float mean = s * (1.f / H_DIM);
        float var = sq * (1.f / H_DIM) - mean * mean;
        float rstd = rsqrtf(var + 1e-5f);
        ld[row][lane * 4 + 0] = (xv.x - mean) * rstd * g4.x + b4.x;
        ld[row][lane * 4 + 1] = (xv.y - mean) * rstd * g4.y + b4.y;
        ld[row][lane * 4 + 2] = (xv.z - mean) * rstd * g4.z + b4.z;
        ld[row][lane * 4 + 3] = (xv.w - mean) * rstd * g4.w + b4.w;
    }
    __syncthreads();
    {
        float* dst = xhl + ((size_t)b * H_DIM + threadIdx.x) * L_SEQ + l0;
        #pragma unroll
        for (int u4 = 0; u4 < 4; ++u4) {
            float4 o;
            o.x = ld[u4 * 4 + 0][threadIdx.x];
            o.y = ld[u4 * 4 + 1][threadIdx.x];
            o.z = ld[u4 * 4 + 2][threadIdx.x];
            o.w = ld[u4 * 4 + 3][threadIdx.x];
            *(float4*)(dst + u4 * 4) = o;
        }
    }
}

// ---------------------------------------------------------------------------
__global__ __launch_bounds__(256) void pool_mean(
    const float* __restrict__ x, float* __restrict__ meanb)
{
    __shared__ float red[256];
    const int bh = blockIdx.x;
    const float* row = x + (size_t)bh * L_SEQ;
    float s = 0.f;
    for (int i = threadIdx.x; i < L_SEQ; i += 256) s += row[i];
    red[threadIdx.x] = s;
    __syncthreads();
    for (int st = 128; st > 0; st >>= 1) {
        if (threadIdx.x < st) red[threadIdx.x] += red[threadIdx.x + st];
        __syncthreads();
    }
    if (threadIdx.x == 0) meanb[bh] = red[0] * (1.f / L_SEQ);
}

__global__ __launch_bounds__(256) void decode(
    const float* __restrict__ meanb, const float* __restrict__ dw,
    const float* __restrict__ db, float* __restrict__ out)
{
    int i = threadIdx.x;
    if (i >= BATCH * 10) return;
    int b = i / 10, d = i % 10;
    float s = db[d];
    for (int h = 0; h < H_DIM; ++h)
        s = fmaf(meanb[b * H_DIM + h], dw[d * H_DIM + h], s);
    out[i] = s;
}

// ---------------------------------------------------------------------------
extern "C" void kernel_launch(void* const* d_in, const int* in_sizes, int n_in,
                              void* d_out, int out_size, void* d_ws, size_t ws_size,
                              hipStream_t stream)
{
    const float* x_in = (const float*)d_in[0];
    const float* cw[3] = {(const float*)d_in[1], (const float*)d_in[7],  (const float*)d_in[13]};
    const float* cb[3] = {(const float*)d_in[2], (const float*)d_in[8],  (const float*)d_in[14]};
    const float* bg[3] = {(const float*)d_in[3], (const float*)d_in[9],  (const float*)d_in[15]};
    const float* bb[3] = {(const float*)d_in[4], (const float*)d_in[10], (const float*)d_in[16]};
    const float* bm[3] = {(const float*)d_in[5], (const float*)d_in[11], (const float*)d_in[17]};
    const float* bv[3] = {(const float*)d_in[6], (const float*)d_in[12], (const float*)d_in[18]};
    const float* log_dt   = (const float*)d_in[19];
    const float* A_re_log = (const float*)d_in[20];
    const float* A_im     = (const float*)d_in[21];
    const float* C_re     = (const float*)d_in[22];
    const float* C_im     = (const float*)d_in[23];
    const float* Dv       = (const float*)d_in[24];
    const float* out_w    = (const float*)d_in[25];
    const float* out_b    = (const float*)d_in[26];
    const float* ln_g     = (const float*)d_in[27];
    const float* ln_b     = (const float*)d_in[28];
    const float* dec_w    = (const float*)d_in[29];
    const float* dec_b    = (const float*)d_in[30];

    const size_t PLANE = (size_t)BATCH * H_DIM * L_SEQ;       // 16,777,216 floats
    float* ws = (float*)d_ws;
    float* xhl = ws;                                          // [B][256][L] fp32
    float* X   = ws + PLANE;          // conv temps -> per-layer matrices -> GLU out
    unsigned short* ybf = (unsigned short*)(ws + 2 * PLANE);  // [B][H][L] bf16
    float* Sbuf = ws + 2 * PLANE + PLANE / 2;                 // states/prefix, PLANE floats
    float* tail = ws + 3 * PLANE + PLANE / 2;
    unsigned short* Wpk = (unsigned short*)tail;              // 1,048,576 us
    float* Ktab  = tail + 524288;                             // 32768
    float* wqbuf = Ktab + 32768;                              // 32768
    float* meanb = wqbuf + 32768;

    unsigned short* X_us = (unsigned short*)X;
    unsigned short* Vpk = X_us;
    unsigned short* Epk = X_us + 8388608;
    unsigned short* Tpk = X_us + 16777216;

    precompute_wpk<<<256, 256, 0, stream>>>(out_w, Wpk);

    // Encoder: x_in -> c1p (padded) -> c2p (padded) -> xhl
    float* c1p = X;
    float* c2p = X + (size_t)BATCH * 64 * LPAD;
    conv_bn_relu_f<1, 7, false, true><<<dim3(16, 2, 16), 256, 0, stream>>>(
        x_in, c1p, cw[0], cb[0], bg[0], bb[0], bm[0], bv[0], 64);
    conv_bn_relu_f<64, 5, true, true><<<dim3(16, 4, 16), 256, 0, stream>>>(
        c1p, c2p, cw[1], cb[1], bg[1], bb[1], bm[1], bv[1], 128);
    conv_bn_relu_f<128, 3, true, false><<<dim3(16, 8, 16), 256, 0, stream>>>(
        c2p, xhl, cw[2], cb[2], bg[2], bb[2], bm[2], bv[2], 256);

    for (int l = 0; l < 4; ++l) {
        mats_gen<<<64, 256, 0, stream>>>(log_dt, A_re_log, A_im, C_re, C_im, Dv, l,
                                         Vpk, Epk, Ktab, wqbuf);
        tfill<<<2048, 256, 0, stream>>>(Ktab, Tpk);
        s4d_gemm_states<<<dim3(4, 256), 256, 0, stream>>>(xhl, Vpk, Sbuf);
        s4d_combine2<<<1024, 256, 0, stream>>>(wqbuf, Sbuf);
        s4d_gemm_out<<<dim3(4, 256), 256, 0, stream>>>(xhl, Sbuf, Epk, Tpk, ybf);
        linear_glu_mfma2<<<dim3(128, 16), 256, 0, stream>>>(
            ybf, Wpk + (size_t)l * 262144, out_b + l * 512, X);
        ln_fuse<<<dim3(256, 16), 256, 0, stream>>>(
            X, xhl, ln_g + l * H_DIM, ln_b + l * H_DIM);
    }

    pool_mean<<<dim3(BATCH * H_DIM), 256, 0, stream>>>(xhl, meanb);
    decode<<<dim3(1), 256, 0, stream>>>(meanb, dec_w, dec_b, (float*)d_out);
}

// Round 6
// 1339.999 us; speedup vs baseline: 3.0670x; 1.1949x over previous
//
#include <hip/hip_runtime.h>
#include <cstdint>
#include <cstddef>

#define L_SEQ 4096
#define H_DIM 256
#define N_MODES 64
#define BATCH 16
#define QCH 128
#define NCHUNK 32
#define LPAD (L_SEQ + 8)

typedef __attribute__((ext_vector_type(8))) short short8v;
typedef __attribute__((ext_vector_type(16))) float f32x16;

#define MFMA32(a, b, c) __builtin_amdgcn_mfma_f32_32x32x16_bf16((a), (b), (c), 0, 0, 0)

__device__ __forceinline__ unsigned short f2bf(float f) {
    unsigned u = __float_as_uint(f);
    u = u + 0x7fff + ((u >> 16) & 1);
    return (unsigned short)(u >> 16);
}
__device__ __forceinline__ float bf2f(unsigned short h) {
    return __uint_as_float(((unsigned)h) << 16);
}

// packed B-fragment position for 32x32x16 bf16: entry (k, col)
__device__ __forceinline__ int bpos(int k, int col) {
    return ((col >> 5) * 8 + (k >> 4)) * 512 + ((col & 31) + 32 * ((k >> 3) & 1)) * 8 + (k & 7);
}
__device__ __forceinline__ void wpack(unsigned short* M, int k, int col, float v) {
    int p = bpos(k, col);
    unsigned short hi = f2bf(v);
    M[p] = hi;
    M[p + 16384] = f2bf(v - bf2f(hi));
}

// ---------------------------------------------------------------------------
// Per-layer S4D matrices: V (states), E (inter-chunk), Ktab (Toeplitz gen), wQ.
// ---------------------------------------------------------------------------
__global__ __launch_bounds__(256) void mats_gen(
    const float* __restrict__ log_dt, const float* __restrict__ A_re_log,
    const float* __restrict__ A_im, const float* __restrict__ C_re,
    const float* __restrict__ C_im, const float* __restrict__ Dv, int layer,
    unsigned short* __restrict__ Vpk, unsigned short* __restrict__ Epk,
    float* __restrict__ Ktab, float* __restrict__ wqbuf)
{
    const int wv = threadIdx.x >> 6, n = threadIdx.x & 63;
    const int h = blockIdx.x * 4 + wv;
    const int idx = (layer * H_DIM + h) * N_MODES + n;
    float dt = expf(log_dt[layer * H_DIM + h]);
    float Ar = -expf(A_re_log[idx]);
    float Ai = A_im[idx];
    float dr = Ar * dt, di = Ai * dt;
    float er = expf(dr);
    float wr = er * cosf(di), wi = er * sinf(di);
    float nr = wr - 1.f, ni = wi;
    float Cr = C_re[idx], Ci = C_im[idx];
    float pr_ = Cr * nr - Ci * ni;
    float pi_ = Cr * ni + Ci * nr;
    float inv = 1.f / (Ar * Ar + Ai * Ai);
    float c2r = 2.f * (pr_ * Ar + pi_ * Ai) * inv;
    float c2i = 2.f * (pi_ * Ar - pr_ * Ai) * inv;
    float Dh = Dv[layer * H_DIM + h];
    unsigned short* Vh = Vpk + h * 32768;
    unsigned short* Eh = Epk + h * 32768;
    float pr = 1.f, pi = 0.f;                       // p = w^d
    for (int d = 0; d <= QCH; ++d) {
        float qr = c2r * pr - c2i * pi;             // q = c2 * w^d
        float qi = c2r * pi + c2i * pr;
        if (d <= QCH - 1) {
            int t = QCH - 1 - d;
            wpack(Vh, t, 2 * n, pr);
            wpack(Vh, t, 2 * n + 1, pi);
            float s = qr;
            #pragma unroll
            for (int st = 1; st < 64; st <<= 1) s += __shfl_xor(s, st);
            if (n == 0) Ktab[h * QCH + d] = s + (d == 0 ? Dh : 0.f);
        }
        if (d >= 1) {
            int t = d - 1;
            wpack(Eh, 2 * n, t, qr);
            wpack(Eh, 2 * n + 1, t, -qi);
        }
        if (d == QCH) {
            wqbuf[(h * 64 + n) * 2 + 0] = pr;
            wqbuf[(h * 64 + n) * 2 + 1] = pi;
        }
        float npr = pr * wr - pi * wi;
        float npi = pr * wi + pi * wr;
        pr = npr; pi = npi;
    }
}

// ---------------------------------------------------------------------------
// Fill packed Toeplitz T from Ktab.
// ---------------------------------------------------------------------------
__global__ __launch_bounds__(256) void tfill(
    const float* __restrict__ Ktab, unsigned short* __restrict__ Tpk)
{
    int t0 = blockIdx.x * 256 + threadIdx.x;
    int h = t0 >> 11;
    int g = t0 & 2047;
    int nt = g >> 9;
    int ks = (g >> 6) & 7;
    int lane8 = g & 63;
    int col = nt * 32 + (lane8 & 31);
    int k0 = ks * 16 + (lane8 >> 5) * 8;
    const float* Kh = Ktab + h * QCH;
    union { unsigned short s[8]; uint4 v; } hi, lo;
    #pragma unroll
    for (int j = 0; j < 8; ++j) {
        int d = col - (k0 + j);
        float val = (d >= 0) ? Kh[d] : 0.f;
        hi.s[j] = f2bf(val);
        lo.s[j] = f2bf(val - bf2f(hi.s[j]));
    }
    unsigned short* dst = Tpk + h * 32768 + (nt * 8 + ks) * 512 + lane8 * 8;
    *(uint4*)dst = hi.v;
    *(uint4*)(dst + 16384) = lo.v;
}

// ---------------------------------------------------------------------------
// Conv weight pack (BN-folded) into MFMA B-frag order per shift k, + bias.
// ---------------------------------------------------------------------------
template<int CI, int K, int CO>
__global__ __launch_bounds__(256) void pack_conv(
    const float* __restrict__ wg, const float* __restrict__ g,
    const float* __restrict__ v, const float* __restrict__ cb,
    const float* __restrict__ m, const float* __restrict__ bb,
    unsigned short* __restrict__ Wc, float* __restrict__ Bs)
{
    constexpr int NT = CO / 32, KS = CI / 16;
    int t = blockIdx.x * 256 + threadIdx.x;
    if (t < CO) Bs[t] = (cb[t] - m[t]) * g[t] * rsqrtf(v[t] + 1e-5f) + bb[t];
    if (t >= K * NT * KS * 64) return;
    int lane = t & 63;
    int rest = t >> 6;
    int ks = rest % KS;
    int nt = (rest / KS) % NT;
    int k = rest / (KS * NT);
    int co = nt * 32 + (lane & 31);
    int ci0 = ks * 16 + (lane >> 5) * 8;
    float s = g[co] * rsqrtf(v[co] + 1e-5f);
    union { unsigned short s_[8]; uint4 v_; } hi, lo;
    #pragma unroll
    for (int j = 0; j < 8; ++j) {
        float f = wg[((size_t)co * CI + ci0 + j) * K + k] * s;
        hi.s_[j] = f2bf(f);
        lo.s_[j] = f2bf(f - bf2f(hi.s_[j]));
    }
    size_t base = ((size_t)(k * NT + nt) * KS + ks) * 512 + lane * 8;
    *(uint4*)(Wc + base) = hi.v_;
    *(uint4*)(Wc + base + (size_t)K * NT * KS * 512) = lo.v_;
}

// ---------------------------------------------------------------------------
// Conv1 (CI=1): keep validated VALU version.
// ---------------------------------------------------------------------------
template<int CI, int K>
__global__ __launch_bounds__(256) void conv_bn_relu_f(
    const float* __restrict__ in, float* __restrict__ out,
    const float* __restrict__ wg, const float* __restrict__ cb,
    const float* __restrict__ g, const float* __restrict__ bb,
    const float* __restrict__ m, const float* __restrict__ v, int CO)
{
    const int wv = threadIdx.x >> 6, lane = threadIdx.x & 63;
    const int b = blockIdx.z;
    const int co0 = __builtin_amdgcn_readfirstlane(blockIdx.y * 32 + wv * 8);
    const int l = blockIdx.x * 256 + lane * 4;
    const int OFF = K / 2;
    float acc[8][4] = {};
    const float* inb = in + (size_t)b * CI * L_SEQ;
    for (int ci = 0; ci < CI; ++ci) {
        const float* row = inb + (size_t)ci * L_SEQ;
        float win[12];
        #pragma unroll
        for (int d = 0; d < 12; ++d) {
            int li = l - 4 + d;
            win[d] = (li >= 0 && li < L_SEQ) ? row[li] : 0.f;
        }
        #pragma unroll
        for (int cc = 0; cc < 8; ++cc) {
            #pragma unroll
            for (int k = 0; k < K; ++k) {
                float wk = wg[((size_t)(co0 + cc) * CI + ci) * K + k];
                #pragma unroll
                for (int j = 0; j < 4; ++j)
                    acc[cc][j] = fmaf(win[4 + j + k - OFF], wk, acc[cc][j]);
            }
        }
    }
    #pragma unroll
    for (int cc = 0; cc < 8; ++cc) {
        int co = co0 + cc;
        float s = g[co] * rsqrtf(v[co] + 1e-5f);
        float sh = (cb[co] - m[co]) * s + bb[co];
        float* orow = out + ((size_t)b * CO + co) * LPAD + 4;
        float4 o4;
        o4.x = fmaxf(fmaf(acc[cc][0], s, sh), 0.f);
        o4.y = fmaxf(fmaf(acc[cc][1], s, sh), 0.f);
        o4.z = fmaxf(fmaf(acc[cc][2], s, sh), 0.f);
        o4.w = fmaxf(fmaf(acc[cc][3], s, sh), 0.f);
        *(float4*)(orow + l) = o4;
        if (blockIdx.x == 0 && lane == 0)
            *(float4*)(orow - 4) = make_float4(0.f, 0.f, 0.f, 0.f);
        if (blockIdx.x == gridDim.x - 1 && lane == 63)
            *(float4*)(orow + L_SEQ) = make_float4(0.f, 0.f, 0.f, 0.f);
    }
}

// ---------------------------------------------------------------------------
// Conv via MFMA implicit GEMM. Block = 32 l x CO for one b.
// A: in[ci][l0-4..l0+35] transposed to LDS [40 l][CI] hi/lo bf16, XOR-swizzled.
// B: packed conv weights per shift k (BN scale folded). 3-product bf16 split.
// Epilogue: +bias, ReLU, transpose through LDS, coalesced row stores.
// ---------------------------------------------------------------------------
template<int CI, int K, int CO, bool POUT>
__global__ __launch_bounds__(256) void conv_mfma(
    const float* __restrict__ in, float* __restrict__ out,
    const unsigned short* __restrict__ Wc, const float* __restrict__ Bs)
{
    constexpr int NT = CO / 32, KS = CI / 16, OBS = NT / 4, OFF = K / 2;
    constexpr int PLSZ = K * NT * KS * 512;
    __shared__ __align__(16) unsigned short A0[40 * CI];
    __shared__ __align__(16) unsigned short A1[40 * CI];
    __shared__ float vt[32][CO + 4];
    const int b = blockIdx.y, l0 = blockIdx.x * 32;
    const int wv = threadIdx.x >> 6, lane = threadIdx.x & 63;
    const float* inb = in + (size_t)b * CI * LPAD + l0;   // = element l0-4 (halo +4)
    for (int e = threadIdx.x; e < CI * 10; e += 256) {
        int ci = e / 10, f4 = e - ci * 10;
        float4 q = *(const float4*)(inb + (size_t)ci * LPAD + f4 * 4);
        #pragma unroll
        for (int j = 0; j < 4; ++j) {
            int row = f4 * 4 + j;
            int bo = ((row * CI + ci) * 2) ^ ((row & 7) << 4);
            float f = (&q.x)[j];
            unsigned short h = f2bf(f);
            *(unsigned short*)((char*)A0 + bo) = h;
            *(unsigned short*)((char*)A1 + bo) = f2bf(f - bf2f(h));
        }
    }
    __syncthreads();
    f32x16 acc0 = {}, acc1 = {};
    #pragma unroll
    for (int k = 0; k < K; ++k) {
        #pragma unroll
        for (int ks = 0; ks < KS; ++ks) {
            int row = (lane & 31) + 4 + k - OFF;
            int abyte = ((row * CI + ks * 16 + (lane >> 5) * 8) * 2) ^ ((row & 7) << 4);
            short8v ah = *(const short8v*)((const char*)A0 + abyte);
            short8v al = *(const short8v*)((const char*)A1 + abyte);
            {
                const unsigned short* wb = Wc + ((size_t)(k * NT + wv * OBS) * KS + ks) * 512 + lane * 8;
                short8v bh = *(const short8v*)wb;
                short8v bl = *(const short8v*)(wb + PLSZ);
                acc0 = MFMA32(ah, bh, acc0);
                acc0 = MFMA32(ah, bl, acc0);
                acc0 = MFMA32(al, bh, acc0);
            }
            if constexpr (OBS == 2) {
                const unsigned short* wb = Wc + ((size_t)(k * NT + wv * OBS + 1) * KS + ks) * 512 + lane * 8;
                short8v bh = *(const short8v*)wb;
                short8v bl = *(const short8v*)(wb + PLSZ);
                acc1 = MFMA32(ah, bh, acc1);
                acc1 = MFMA32(ah, bl, acc1);
                acc1 = MFMA32(al, bh, acc1);
            }
        }
    }
    {
        int co = (wv * OBS) * 32 + (lane & 31);
        float bs = Bs[co];
        #pragma unroll
        for (int r = 0; r < 16; ++r) {
            int lr = (r & 3) + 8 * (r >> 2) + 4 * (lane >> 5);
            vt[lr][co] = fmaxf(acc0[r] + bs, 0.f);
        }
        if constexpr (OBS == 2) {
            int co1 = co + 32;
            float bs1 = Bs[co1];
            #pragma unroll
            for (int r = 0; r < 16; ++r) {
                int lr = (r & 3) + 8 * (r >> 2) + 4 * (lane >> 5);
                vt[lr][co1] = fmaxf(acc1[r] + bs1, 0.f);
            }
        }
    }
    __syncthreads();
    if constexpr (CO == 256) {
        float* orow = out + ((size_t)b * CO + threadIdx.x) * (POUT ? LPAD : L_SEQ)
                      + (POUT ? 4 : 0) + l0;
        #pragma unroll
        for (int u4 = 0; u4 < 8; ++u4) {
            float4 o;
            o.x = vt[u4 * 4 + 0][threadIdx.x];
            o.y = vt[u4 * 4 + 1][threadIdx.x];
            o.z = vt[u4 * 4 + 2][threadIdx.x];
            o.w = vt[u4 * 4 + 3][threadIdx.x];
            *(float4*)(orow + u4 * 4) = o;
        }
    } else {   // CO == 128, POUT assumed true
        int co = threadIdx.x & 127, lh = threadIdx.x >> 7;
        float* rowb = out + ((size_t)b * CO + co) * LPAD;
        float* orow = rowb + 4 + l0 + lh * 16;
        #pragma unroll
        for (int u4 = 0; u4 < 4; ++u4) {
            float4 o;
            o.x = vt[lh * 16 + u4 * 4 + 0][co];
            o.y = vt[lh * 16 + u4 * 4 + 1][co];
            o.z = vt[lh * 16 + u4 * 4 + 2][co];
            o.w = vt[lh * 16 + u4 * 4 + 3][co];
            *(float4*)(orow + u4 * 4) = o;
        }
        if (blockIdx.x == 0 && lh == 0)
            *(float4*)(rowb) = make_float4(0.f, 0.f, 0.f, 0.f);
        if (blockIdx.x == gridDim.x - 1 && lh == 1)
            *(float4*)(rowb + 4 + L_SEQ) = make_float4(0.f, 0.f, 0.f, 0.f);
    }
}

// ---------------------------------------------------------------------------
// S4D states GEMM + fused chunk-prefix. Writes P directly (carry-in states).
// Block: one h, 4 b (wave=b), all 32 chunks. LDS reused: staging -> S/P tile.
// ---------------------------------------------------------------------------
__global__ __launch_bounds__(256) void s4d_gemm_states(
    const float* __restrict__ u, const unsigned short* __restrict__ Vpk,
    const float* __restrict__ wqbuf, float* __restrict__ Pbuf)
{
    __shared__ __align__(16) char smem[65536];
    unsigned short* As0 = (unsigned short*)smem;
    unsigned short* As1 = (unsigned short*)(smem + 32768);
    float* Sl = (float*)smem;
    const int h = blockIdx.y;
    const int b0 = blockIdx.x * 4;
    const int wv = threadIdx.x >> 6, lane = threadIdx.x & 63;
    const float* ub = u + ((size_t)b0 * H_DIM + h) * L_SEQ;
    #pragma unroll
    for (int i = 0; i < 16; ++i) {
        int idx = threadIdx.x + i * 256;
        int bl = idx >> 10;
        int pos = (idx & 1023) * 4;
        float4 q = *(const float4*)(ub + (size_t)bl * H_DIM * L_SEQ + pos);
        int m = bl * 32 + (pos >> 7);
        int k = pos & 127;
        int byte0 = (m * 256 + k * 2) ^ ((m & 7) << 4);
        ushort4 hv, lv;
        hv.x = f2bf(q.x); lv.x = f2bf(q.x - bf2f(hv.x));
        hv.y = f2bf(q.y); lv.y = f2bf(q.y - bf2f(hv.y));
        hv.z = f2bf(q.z); lv.z = f2bf(q.z - bf2f(hv.z));
        hv.w = f2bf(q.w); lv.w = f2bf(q.w - bf2f(hv.w));
        *(ushort4*)((char*)As0 + byte0) = hv;
        *(ushort4*)((char*)As1 + byte0) = lv;
    }
    __syncthreads();
    const unsigned short* Vh = Vpk + h * 32768;
    f32x16 acc0 = {}, acc1 = {}, acc2 = {}, acc3 = {};
    #pragma unroll
    for (int ks = 0; ks < 8; ++ks) {
        int abyte = ((32 * wv + (lane & 31)) * 256 + (ks * 16 + (lane >> 5) * 8) * 2)
                    ^ ((lane & 7) << 4);
        short8v ah = *(const short8v*)((const char*)As0 + abyte);
        short8v al = *(const short8v*)((const char*)As1 + abyte);
        const unsigned short* vb = Vh + ks * 512 + lane * 8;
        short8v b0h = *(const short8v*)(vb);
        short8v b1h = *(const short8v*)(vb + 4096);
        short8v b2h = *(const short8v*)(vb + 8192);
        short8v b3h = *(const short8v*)(vb + 12288);
        short8v b0l = *(const short8v*)(vb + 16384);
        short8v b1l = *(const short8v*)(vb + 20480);
        short8v b2l = *(const short8v*)(vb + 24576);
        short8v b3l = *(const short8v*)(vb + 28672);
        acc0 = MFMA32(ah, b0h, acc0);
        acc1 = MFMA32(ah, b1h, acc1);
        acc2 = MFMA32(ah, b2h, acc2);
        acc3 = MFMA32(ah, b3h, acc3);
        acc0 = MFMA32(ah, b0l, acc0);
        acc1 = MFMA32(ah, b1l, acc1);
        acc2 = MFMA32(ah, b2l, acc2);
        acc3 = MFMA32(ah, b3l, acc3);
        acc0 = MFMA32(al, b0h, acc0);
        acc1 = MFMA32(al, b1h, acc1);
        acc2 = MFMA32(al, b2h, acc2);
        acc3 = MFMA32(al, b3h, acc3);
    }
    __syncthreads();          // all staging reads done before overwrite
    #pragma unroll
    for (int nt = 0; nt < 4; ++nt) {
        const f32x16& a = nt == 0 ? acc0 : nt == 1 ? acc1 : nt == 2 ? acc2 : acc3;
        int col = nt * 32 + (lane & 31);
        #pragma unroll
        for (int r = 0; r < 16; ++r) {
            int c = (r & 3) + 8 * (r >> 2) + 4 * (lane >> 5);
            Sl[wv * 4096 + c * 128 + col] = a[r];
        }
    }
    // per-wave serial prefix over chunks; lane = mode n (cols 2n, 2n+1)
    {
        const float2 wq = *(const float2*)(wqbuf + ((size_t)h * 64 + lane) * 2);
        float* base = Sl + wv * 4096 + 2 * lane;
        float Pr = 0.f, Pi = 0.f;
        for (int c = 0; c < NCHUNK; ++c) {
            float2 s = *(const float2*)(base + c * 128);
            *(float2*)(base + c * 128) = make_float2(Pr, Pi);
            float npr = fmaf(wq.x, Pr, fmaf(-wq.y, Pi, s.x));
            float npi = fmaf(wq.x, Pi, fmaf(wq.y, Pr, s.y));
            Pr = npr; Pi = npi;
        }
    }
    __syncthreads();
    float4* gdst = (float4*)(Pbuf + ((size_t)h * 16 + b0) * 4096);
    const float4* gsrc = (const float4*)Sl;
    #pragma unroll
    for (int i = 0; i < 16; ++i) gdst[threadIdx.x + i * 256] = gsrc[threadIdx.x + i * 256];
}

// ---------------------------------------------------------------------------
// S4D output GEMM: y = P x E + u x T  (+GELU, bf16 store).
// ---------------------------------------------------------------------------
__global__ __launch_bounds__(256) void s4d_gemm_out(
    const float* __restrict__ u, const float* __restrict__ Pbuf,
    const unsigned short* __restrict__ Epk, const unsigned short* __restrict__ Tpk,
    unsigned short* __restrict__ ybf)
{
    __shared__ __align__(16) unsigned short As0[16384];
    __shared__ __align__(16) unsigned short As1[16384];
    const int h = blockIdx.y;
    const int b0 = blockIdx.x * 4;
    const int wv = threadIdx.x >> 6, lane = threadIdx.x & 63;
    f32x16 acc0 = {}, acc1 = {}, acc2 = {}, acc3 = {};

    {   // phase 1: P x E
        const float* Ph = Pbuf + ((size_t)h * 16 + b0) * 4096;
        #pragma unroll
        for (int i = 0; i < 16; ++i) {
            int idx = threadIdx.x + i * 256;
            float4 q = *(const float4*)(Ph + (size_t)idx * 4);
            int m = idx >> 5;
            int k = (idx & 31) * 4;
            int byte0 = (m * 256 + k * 2) ^ ((m & 7) << 4);
            ushort4 hv, lv;
            hv.x = f2bf(q.x); lv.x = f2bf(q.x - bf2f(hv.x));
            hv.y = f2bf(q.y); lv.y = f2bf(q.y - bf2f(hv.y));
            hv.z = f2bf(q.z); lv.z = f2bf(q.z - bf2f(hv.z));
            hv.w = f2bf(q.w); lv.w = f2bf(q.w - bf2f(hv.w));
            *(ushort4*)((char*)As0 + byte0) = hv;
            *(ushort4*)((char*)As1 + byte0) = lv;
        }
        __syncthreads();
        const unsigned short* Eh = Epk + h * 32768;
        #pragma unroll
        for (int ks = 0; ks < 8; ++ks) {
            int abyte = ((32 * wv + (lane & 31)) * 256 + (ks * 16 + (lane >> 5) * 8) * 2)
                        ^ ((lane & 7) << 4);
            short8v ah = *(const short8v*)((const char*)As0 + abyte);
            short8v al = *(const short8v*)((const char*)As1 + abyte);
            const unsigned short* eb = Eh + ks * 512 + lane * 8;
            short8v b0h = *(const short8v*)(eb);
            short8v b1h = *(const short8v*)(eb + 4096);
            short8v b2h = *(const short8v*)(eb + 8192);
            short8v b3h = *(const short8v*)(eb + 12288);
            short8v b0l = *(const short8v*)(eb + 16384);
            short8v b1l = *(const short8v*)(eb + 20480);
            short8v b2l = *(const short8v*)(eb + 24576);
            short8v b3l = *(const short8v*)(eb + 28672);
            acc0 = MFMA32(ah, b0h, acc0);
            acc1 = MFMA32(ah, b1h, acc1);
            acc2 = MFMA32(ah, b2h, acc2);
            acc3 = MFMA32(ah, b3h, acc3);
            acc0 = MFMA32(ah, b0l, acc0);
            acc1 = MFMA32(ah, b1l, acc1);
            acc2 = MFMA32(ah, b2l, acc2);
            acc3 = MFMA32(ah, b3l, acc3);
            acc0 = MFMA32(al, b0h, acc0);
            acc1 = MFMA32(al, b1h, acc1);
            acc2 = MFMA32(al, b2h, acc2);
            acc3 = MFMA32(al, b3h, acc3);
        }
        __syncthreads();
    }
    {   // phase 2: u x T
        const float* ub = u + ((size_t)b0 * H_DIM + h) * L_SEQ;
        #pragma unroll
        for (int i = 0; i < 16; ++i) {
            int idx = threadIdx.x + i * 256;
            int bl = idx >> 10;
            int pos = (idx & 1023) * 4;
            float4 q = *(const float4*)(ub + (size_t)bl * H_DIM * L_SEQ + pos);
            int m = bl * 32 + (pos >> 7);
            int k = pos & 127;
            int byte0 = (m * 256 + k * 2) ^ ((m & 7) << 4);
            ushort4 hv, lv;
            hv.x = f2bf(q.x); lv.x = f2bf(q.x - bf2f(hv.x));
            hv.y = f2bf(q.y); lv.y = f2bf(q.y - bf2f(hv.y));
            hv.z = f2bf(q.z); lv.z = f2bf(q.z - bf2f(hv.z));
            hv.w = f2bf(q.w); lv.w = f2bf(q.w - bf2f(hv.w));
            *(ushort4*)((char*)As0 + byte0) = hv;
            *(ushort4*)((char*)As1 + byte0) = lv;
        }
        __syncthreads();
        const unsigned short* Th = Tpk + h * 32768;
        #pragma unroll
        for (int ks = 0; ks < 8; ++ks) {
            int abyte = ((32 * wv + (lane & 31)) * 256 + (ks * 16 + (lane >> 5) * 8) * 2)
                        ^ ((lane & 7) << 4);
            short8v ah = *(const short8v*)((const char*)As0 + abyte);
            short8v al = *(const short8v*)((const char*)As1 + abyte);
            const unsigned short* tb = Th + ks * 512 + lane * 8;
            short8v b0h = *(const short8v*)(tb);
            short8v b1h = *(const short8v*)(tb + 4096);
            short8v b2h = *(const short8v*)(tb + 8192);
            short8v b3h = *(const short8v*)(tb + 12288);
            short8v b0l = *(const short8v*)(tb + 16384);
            short8v b1l = *(const short8v*)(tb + 20480);
            short8v b2l = *(const short8v*)(tb + 24576);
            short8v b3l = *(const short8v*)(tb + 28672);
            acc0 = MFMA32(ah, b0h, acc0);
            acc1 = MFMA32(ah, b1h, acc1);
            acc2 = MFMA32(ah, b2h, acc2);
            acc3 = MFMA32(ah, b3h, acc3);
            acc0 = MFMA32(ah, b0l, acc0);
            acc1 = MFMA32(ah, b1l, acc1);
            acc2 = MFMA32(ah, b2l, acc2);
            acc3 = MFMA32(ah, b3l, acc3);
            acc0 = MFMA32(al, b0h, acc0);
            acc1 = MFMA32(al, b1h, acc1);
            acc2 = MFMA32(al, b2h, acc2);
            acc3 = MFMA32(al, b3h, acc3);
        }
    }
    #pragma unroll
    for (int nt = 0; nt < 4; ++nt) {
        const f32x16& a = nt == 0 ? acc0 : nt == 1 ? acc1 : nt == 2 ? acc2 : acc3;
        int t = nt * 32 + (lane & 31);
        #pragma unroll
        for (int r = 0; r < 16; ++r) {
            int m = 32 * wv + (r & 3) + 8 * (r >> 2) + 4 * (lane >> 5);
            int bl = m >> 5, c = m & 31;
            float yv = a[r];
            float yc = fmaf(0.044715f * yv, yv * yv, yv);
            float tg = tanhf(0.79788456f * yc);
            float outv = 0.5f * yv * (1.f + tg);
            ybf[((size_t)(b0 + bl) * H_DIM + h) * L_SEQ + c * QCH + t] = f2bf(outv);
        }
    }
}

// ---------------------------------------------------------------------------
// W -> packed MFMA B-fragment order, bf16 hi/lo planes (GLU linear).
// ---------------------------------------------------------------------------
__global__ __launch_bounds__(256) void precompute_wpk(
    const float* __restrict__ W, unsigned short* __restrict__ Wpk)
{
    int t = blockIdx.x * 256 + threadIdx.x;
    if (t >= 4 * 16 * 16 * 64) return;
    int lane = t & 63;
    int kk = (t >> 6) & 15;
    int ob = (t >> 10) & 15;
    int layer = t >> 14;
    int o = ob * 32 + (lane & 31);
    int k0 = kk * 16 + (lane >> 5) * 8;
    const float* src = W + ((size_t)layer * 512 + o) * H_DIM + k0;
    union { unsigned short s[8]; uint4 v; } hi, lo;
    #pragma unroll
    for (int j = 0; j < 8; ++j) {
        float f = src[j];
        hi.s[j] = f2bf(f);
        lo.s[j] = f2bf(f - bf2f(hi.s[j]));
    }
    size_t base = (size_t)layer * 262144 + ((size_t)((ob * 16 + kk) * 64 + lane) * 8);
    *(uint4*)(Wpk + base) = hi.v;
    *(uint4*)(Wpk + base + 131072) = lo.v;
}

// ---------------------------------------------------------------------------
// Output linear (H->2H) MFMA + GLU + residual + LayerNorm, all fused.
// Block = 32 l x all 512 outputs -> 256 GLU chans; LN over chans is in-block.
// Writes x_new = LN(glu + x) to xhl [B][256][L].
// ---------------------------------------------------------------------------
__global__ __launch_bounds__(256) void linear_glu_ln(
    const unsigned short* __restrict__ ybf,
    const unsigned short* __restrict__ Wpk,
    const float* __restrict__ bias,
    const float* __restrict__ lg, const float* __restrict__ lb,
    float* __restrict__ xhl)
{
    __shared__ __align__(16) unsigned short As[32 * 256];
    __shared__ float vt[32][260];
    const int lane = threadIdx.x & 63;
    const int wv = threadIdx.x >> 6;
    const int b = blockIdx.y;
    const int l0 = blockIdx.x * 32;

    const unsigned short* ybase = ybf + (size_t)b * H_DIM * L_SEQ + l0;
    #pragma unroll
    for (int p = 0; p < 4; ++p) {
        int e = threadIdx.x + p * 256;
        int hh = e >> 2, c4 = e & 3;
        union { uint4 v; unsigned short s[8]; } qv;
        qv.v = *(const uint4*)(ybase + (size_t)hh * L_SEQ + c4 * 8);
        #pragma unroll
        for (int j = 0; j < 8; ++j) {
            int lloc = c4 * 8 + j;
            int byteoff = (lloc << 9) + hh * 2;
            byteoff ^= ((lloc & 7) << 4);
            *(unsigned short*)((char*)As + byteoff) = qv.s[j];
        }
    }
    __syncthreads();

    const int ob0 = 2 * wv, ob1 = 2 * wv + 1;
    const int r = lane & 31;
    f32x16 acc0 = {}, acc1 = {}, acc2 = {}, acc3 = {};
    #pragma unroll 4
    for (int kk = 0; kk < 16; ++kk) {
        int abyte = (r << 9) | (kk * 32 + (lane >> 5) * 16);
        abyte ^= ((r & 7) << 4);
        short8v a = *(const short8v*)((char*)As + abyte);
        const unsigned short* w0 = Wpk + (((ob0 * 16 + kk) * 64 + lane) * 8);
        const unsigned short* w1 = Wpk + (((ob1 * 16 + kk) * 64 + lane) * 8);
        const unsigned short* w2 = Wpk + ((((ob0 + 8) * 16 + kk) * 64 + lane) * 8);
        const unsigned short* w3 = Wpk + ((((ob1 + 8) * 16 + kk) * 64 + lane) * 8);
        short8v h0 = *(const short8v*)w0;
        short8v h1 = *(const short8v*)w1;
        short8v h2 = *(const short8v*)w2;
        short8v h3 = *(const short8v*)w3;
        short8v e0 = *(const short8v*)(w0 + 131072);
        short8v e1 = *(const short8v*)(w1 + 131072);
        short8v e2 = *(const short8v*)(w2 + 131072);
        short8v e3 = *(const short8v*)(w3 + 131072);
        acc0 = MFMA32(a, h0, acc0);
        acc1 = MFMA32(a, h1, acc1);
        acc2 = MFMA32(a, h2, acc2);
        acc3 = MFMA32(a, h3, acc3);
        acc0 = MFMA32(a, e0, acc0);
        acc1 = MFMA32(a, e1, acc1);
        acc2 = MFMA32(a, e2, acc2);
        acc3 = MFMA32(a, e3, acc3);
    }
    // GLU -> vt[l_loc][o]
    #pragma unroll
    for (int p = 0; p < 2; ++p) {
        const f32x16& z1v = p ? acc1 : acc0;
        const f32x16& z2v = p ? acc3 : acc2;
        int o = (p ? ob1 : ob0) * 32 + (lane & 31);
        float b1 = bias[o], b2 = bias[o + 256];
        #pragma unroll
        for (int rr = 0; rr < 16; ++rr) {
            int lloc = (rr & 3) + 8 * (rr >> 2) + 4 * (lane >> 5);
            float z1 = z1v[rr] + b1;
            float z2 = z2v[rr] + b2;
            vt[lloc][o] = z1 / (1.f + expf(-z2));
        }
    }
    __syncthreads();
    // residual add: thread t owns h = t, 32 l values
    {
        const float* xr = xhl + ((size_t)b * H_DIM + threadIdx.x) * L_SEQ + l0;
        #pragma unroll
        for (int u4 = 0; u4 < 8; ++u4) {
            float4 q = *(const float4*)(xr + u4 * 4);
            vt[u4 * 4 + 0][threadIdx.x] += q.x;
            vt[u4 * 4 + 1][threadIdx.x] += q.y;
            vt[u4 * 4 + 2][threadIdx.x] += q.z;
            vt[u4 * 4 + 3][threadIdx.x] += q.w;
        }
    }
    __syncthreads();
    // LN per l-row (8 rows per wave), normalize in place
    {
        float4 g4 = *(const float4*)(lg + lane * 4);
        float4 b4 = *(const float4*)(lb + lane * 4);
        #pragma unroll
        for (int rr = 0; rr < 8; ++rr) {
            int row = rr * 4 + wv;
            float4 xv = *(const float4*)&vt[row][lane * 4];
            float s = xv.x + xv.y + xv.z + xv.w;
            float sq = xv.x * xv.x + xv.y * xv.y + xv.z * xv.z + xv.w * xv.w;
            #pragma unroll
            for (int st = 1; st < 64; st <<= 1) {
                s += __shfl_xor(s, st);
                sq += __shfl_xor(sq, st);
            }
            float mean = s * (1.f / H_DIM);
            float var = sq * (1.f / H_DIM) - mean * mean;
            float rstd = rsqrtf(var + 1e-5f);
            float4 o;
            o.x = (xv.x - mean) * rstd * g4.x + b4.x;
            o.y = (xv.y - mean) * rstd * g4.y + b4.y;
            o.z = (xv.z - mean) * rstd * g4.z + b4.z;
            o.w = (xv.w - mean) * rstd * g4.w + b4.w;
            *(float4*)&vt[row][lane * 4] = o;
        }
    }
    __syncthreads();
    // transposed writeback: thread t -> xhl[b][t][l0..l0+31]
    {
        float* dst = xhl + ((size_t)b * H_DIM + threadIdx.x) * L_SEQ + l0;
        #pragma unroll
        for (int u4 = 0; u4 < 8; ++u4) {
            float4 o;
            o.x = vt[u4 * 4 + 0][threadIdx.x];
            o.y = vt[u4 * 4 + 1][threadIdx.x];
            o.z = vt[u4 * 4 + 2][threadIdx.x];
            o.w = vt[u4 * 4 + 3][threadIdx.x];
            *(float4*)(dst + u4 * 4) = o;
        }
    }
}

// ---------------------------------------------------------------------------
__global__ __launch_bounds__(256) void pool_mean(
    const float* __restrict__ x, float* __restrict__ meanb)
{
    __shared__ float red[256];
    const int bh = blockIdx.x;
    const float* row = x + (size_t)bh * L_SEQ;
    float s = 0.f;
    for (int i = threadIdx.x; i < L_SEQ; i += 256) s += row[i];
    red[threadIdx.x] = s;
    __syncthreads();
    for (int st = 128; st > 0; st >>= 1) {
        if (threadIdx.x < st) red[threadIdx.x] += red[threadIdx.x + st];
        __syncthreads();
    }
    if (threadIdx.x == 0) meanb[bh] = red[0] * (1.f / L_SEQ);
}

__global__ __launch_bounds__(256) void decode(
    const float* __restrict__ meanb, const float* __restrict__ dw,
    const float* __restrict__ db, float* __restrict__ out)
{
    int i = threadIdx.x;
    if (i >= BATCH * 10) return;
    int b = i / 10, d = i % 10;
    float s = db[d];
    for (int h = 0; h < H_DIM; ++h)
        s = fmaf(meanb[b * H_DIM + h], dw[d * H_DIM + h], s);
    out[i] = s;
}

// ---------------------------------------------------------------------------
extern "C" void kernel_launch(void* const* d_in, const int* in_sizes, int n_in,
                              void* d_out, int out_size, void* d_ws, size_t ws_size,
                              hipStream_t stream)
{
    const float* x_in = (const float*)d_in[0];
    const float* cw[3] = {(const float*)d_in[1], (const float*)d_in[7],  (const float*)d_in[13]};
    const float* cb[3] = {(const float*)d_in[2], (const float*)d_in[8],  (const float*)d_in[14]};
    const float* bg[3] = {(const float*)d_in[3], (const float*)d_in[9],  (const float*)d_in[15]};
    const float* bb[3] = {(const float*)d_in[4], (const float*)d_in[10], (const float*)d_in[16]};
    const float* bm[3] = {(const float*)d_in[5], (const float*)d_in[11], (const float*)d_in[17]};
    const float* bv[3] = {(const float*)d_in[6], (const float*)d_in[12], (const float*)d_in[18]};
    const float* log_dt   = (const float*)d_in[19];
    const float* A_re_log = (const float*)d_in[20];
    const float* A_im     = (const float*)d_in[21];
    const float* C_re     = (const float*)d_in[22];
    const float* C_im     = (const float*)d_in[23];
    const float* Dv       = (const float*)d_in[24];
    const float* out_w    = (const float*)d_in[25];
    const float* out_b    = (const float*)d_in[26];
    const float* ln_g     = (const float*)d_in[27];
    const float* ln_b     = (const float*)d_in[28];
    const float* dec_w    = (const float*)d_in[29];
    const float* dec_b    = (const float*)d_in[30];

    const size_t PLANE = (size_t)BATCH * H_DIM * L_SEQ;       // 16,777,216 floats
    float* ws = (float*)d_ws;
    float* xhl = ws;                                          // [B][256][L] fp32
    float* X   = ws + PLANE;            // conv temps -> per-layer matrices
    unsigned short* ybf = (unsigned short*)(ws + 2 * PLANE);  // [B][H][L] bf16
    float* Pbuf = ws + 2 * PLANE + PLANE / 2;                 // states/prefix
    float* tail = ws + 3 * PLANE + PLANE / 2;
    unsigned short* Wpk = (unsigned short*)tail;              // 1,048,576 us
    float* Ktab  = tail + 524288;
    float* wqbuf = Ktab + 32768;
    float* meanb = wqbuf + 32768;
    unsigned short* Wc2 = (unsigned short*)(meanb + 4096);    // 81,920 us
    float* Bs2 = (float*)(Wc2 + 81920);
    unsigned short* Wc3 = (unsigned short*)(Bs2 + 128);       // 196,608 us
    float* Bs3 = (float*)(Wc3 + 196608);

    unsigned short* X_us = (unsigned short*)X;
    unsigned short* Vpk = X_us;
    unsigned short* Epk = X_us + 8388608;
    unsigned short* Tpk = X_us + 16777216;

    precompute_wpk<<<256, 256, 0, stream>>>(out_w, Wpk);
    pack_conv<64, 5, 128><<<20, 256, 0, stream>>>(cw[1], bg[1], bv[1], cb[1], bm[1], bb[1], Wc2, Bs2);
    pack_conv<128, 3, 256><<<48, 256, 0, stream>>>(cw[2], bg[2], bv[2], cb[2], bm[2], bb[2], Wc3, Bs3);

    // Encoder: x_in -> c1p (padded) -> c2p (padded) -> xhl
    float* c1p = X;
    float* c2p = X + (size_t)BATCH * 64 * LPAD;
    conv_bn_relu_f<1, 7><<<dim3(16, 2, 16), 256, 0, stream>>>(
        x_in, c1p, cw[0], cb[0], bg[0], bb[0], bm[0], bv[0], 64);
    conv_mfma<64, 5, 128, true><<<dim3(128, 16), 256, 0, stream>>>(c1p, c2p, Wc2, Bs2);
    conv_mfma<128, 3, 256, false><<<dim3(128, 16), 256, 0, stream>>>(c2p, xhl, Wc3, Bs3);

    for (int l = 0; l < 4; ++l) {
        mats_gen<<<64, 256, 0, stream>>>(log_dt, A_re_log, A_im, C_re, C_im, Dv, l,
                                         Vpk, Epk, Ktab, wqbuf);
        tfill<<<2048, 256, 0, stream>>>(Ktab, Tpk);
        s4d_gemm_states<<<dim3(4, 256), 256, 0, stream>>>(xhl, Vpk, wqbuf, Pbuf);
        s4d_gemm_out<<<dim3(4, 256), 256, 0, stream>>>(xhl, Pbuf, Epk, Tpk, ybf);
        linear_glu_ln<<<dim3(128, 16), 256, 0, stream>>>(
            ybf, Wpk + (size_t)l * 262144, out_b + l * 512,
            ln_g + l * H_DIM, ln_b + l * H_DIM, xhl);
    }

    pool_mean<<<dim3(BATCH * H_DIM), 256, 0, stream>>>(xhl, meanb);
    decode<<<dim3(1), 256, 0, stream>>>(meanb, dec_w, dec_b, (float*)d_out);
}

// Round 8
// 1127.726 us; speedup vs baseline: 3.6443x; 1.1882x over previous
//
#include <hip/hip_runtime.h>
#include <cstdint>
#include <cstddef>

#define L_SEQ 4096
#define H_DIM 256
#define N_MODES 64
#define BATCH 16
#define QCH 128
#define NCHUNK 32
#define LPAD (L_SEQ + 8)

typedef __attribute__((ext_vector_type(8))) short short8v;
typedef __attribute__((ext_vector_type(16))) float f32x16;

#define MFMA32(a, b, c) __builtin_amdgcn_mfma_f32_32x32x16_bf16((a), (b), (c), 0, 0, 0)

__device__ __forceinline__ unsigned short f2bf(float f) {
    unsigned u = __float_as_uint(f);
    u = u + 0x7fff + ((u >> 16) & 1);
    return (unsigned short)(u >> 16);
}
__device__ __forceinline__ float bf2f(unsigned short h) {
    return __uint_as_float(((unsigned)h) << 16);
}
// convert 8 fp32 -> hi/lo bf16 fragments in registers
__device__ __forceinline__ void cvt8(float4 q0, float4 q1, short8v& hi8, short8v& lo8) {
    float f[8] = {q0.x, q0.y, q0.z, q0.w, q1.x, q1.y, q1.z, q1.w};
    #pragma unroll
    for (int j = 0; j < 8; ++j) {
        unsigned short h = f2bf(f[j]);
        hi8[j] = (short)h;
        lo8[j] = (short)f2bf(f[j] - bf2f(h));
    }
}

// packed B-fragment position for 32x32x16 bf16: entry (k, col)
__device__ __forceinline__ int bpos(int k, int col) {
    return ((col >> 5) * 8 + (k >> 4)) * 512 + ((col & 31) + 32 * ((k >> 3) & 1)) * 8 + (k & 7);
}
__device__ __forceinline__ void wpack(unsigned short* M, int k, int col, float v) {
    int p = bpos(k, col);
    unsigned short hi = f2bf(v);
    M[p] = hi;
    M[p + 16384] = f2bf(v - bf2f(hi));
}

// ---------------------------------------------------------------------------
// Per-layer S4D matrices: V (states), E (inter-chunk), Ktab (Toeplitz gen), wQ.
// ---------------------------------------------------------------------------
__global__ __launch_bounds__(256) void mats_gen(
    const float* __restrict__ log_dt, const float* __restrict__ A_re_log,
    const float* __restrict__ A_im, const float* __restrict__ C_re,
    const float* __restrict__ C_im, const float* __restrict__ Dv, int layer,
    unsigned short* __restrict__ Vpk, unsigned short* __restrict__ Epk,
    float* __restrict__ Ktab, float* __restrict__ wqbuf)
{
    const int wv = threadIdx.x >> 6, n = threadIdx.x & 63;
    const int h = blockIdx.x * 4 + wv;
    const int idx = (layer * H_DIM + h) * N_MODES + n;
    float dt = expf(log_dt[layer * H_DIM + h]);
    float Ar = -expf(A_re_log[idx]);
    float Ai = A_im[idx];
    float dr = Ar * dt, di = Ai * dt;
    float er = expf(dr);
    float wr = er * cosf(di), wi = er * sinf(di);
    float nr = wr - 1.f, ni = wi;
    float Cr = C_re[idx], Ci = C_im[idx];
    float pr_ = Cr * nr - Ci * ni;
    float pi_ = Cr * ni + Ci * nr;
    float inv = 1.f / (Ar * Ar + Ai * Ai);
    float c2r = 2.f * (pr_ * Ar + pi_ * Ai) * inv;
    float c2i = 2.f * (pi_ * Ar - pr_ * Ai) * inv;
    float Dh = Dv[layer * H_DIM + h];
    unsigned short* Vh = Vpk + h * 32768;
    unsigned short* Eh = Epk + h * 32768;
    float pr = 1.f, pi = 0.f;                       // p = w^d
    for (int d = 0; d <= QCH; ++d) {
        float qr = c2r * pr - c2i * pi;             // q = c2 * w^d
        float qi = c2r * pi + c2i * pr;
        if (d <= QCH - 1) {
            int t = QCH - 1 - d;
            wpack(Vh, t, 2 * n, pr);
            wpack(Vh, t, 2 * n + 1, pi);
            float s = qr;
            #pragma unroll
            for (int st = 1; st < 64; st <<= 1) s += __shfl_xor(s, st);
            if (n == 0) Ktab[h * QCH + d] = s + (d == 0 ? Dh : 0.f);
        }
        if (d >= 1) {
            int t = d - 1;
            wpack(Eh, 2 * n, t, qr);
            wpack(Eh, 2 * n + 1, t, -qi);
        }
        if (d == QCH) {
            wqbuf[(h * 64 + n) * 2 + 0] = pr;
            wqbuf[(h * 64 + n) * 2 + 1] = pi;
        }
        float npr = pr * wr - pi * wi;
        float npi = pr * wi + pi * wr;
        pr = npr; pi = npi;
    }
}

// ---------------------------------------------------------------------------
// Fill packed Toeplitz T from Ktab.
// ---------------------------------------------------------------------------
__global__ __launch_bounds__(256) void tfill(
    const float* __restrict__ Ktab, unsigned short* __restrict__ Tpk)
{
    int t0 = blockIdx.x * 256 + threadIdx.x;
    int h = t0 >> 11;
    int g = t0 & 2047;
    int nt = g >> 9;
    int ks = (g >> 6) & 7;
    int lane8 = g & 63;
    int col = nt * 32 + (lane8 & 31);
    int k0 = ks * 16 + (lane8 >> 5) * 8;
    const float* Kh = Ktab + h * QCH;
    union { unsigned short s[8]; uint4 v; } hi, lo;
    #pragma unroll
    for (int j = 0; j < 8; ++j) {
        int d = col - (k0 + j);
        float val = (d >= 0) ? Kh[d] : 0.f;
        hi.s[j] = f2bf(val);
        lo.s[j] = f2bf(val - bf2f(hi.s[j]));
    }
    unsigned short* dst = Tpk + h * 32768 + (nt * 8 + ks) * 512 + lane8 * 8;
    *(uint4*)dst = hi.v;
    *(uint4*)(dst + 16384) = lo.v;
}

// ---------------------------------------------------------------------------
// Conv weight pack (BN-folded) into MFMA B-frag order per shift k, + bias.
// ---------------------------------------------------------------------------
template<int CI, int K, int CO>
__global__ __launch_bounds__(256) void pack_conv(
    const float* __restrict__ wg, const float* __restrict__ g,
    const float* __restrict__ v, const float* __restrict__ cb,
    const float* __restrict__ m, const float* __restrict__ bb,
    unsigned short* __restrict__ Wc, float* __restrict__ Bs)
{
    constexpr int NT = CO / 32, KS = CI / 16;
    int t = blockIdx.x * 256 + threadIdx.x;
    if (t < CO) Bs[t] = (cb[t] - m[t]) * g[t] * rsqrtf(v[t] + 1e-5f) + bb[t];
    if (t >= K * NT * KS * 64) return;
    int lane = t & 63;
    int rest = t >> 6;
    int ks = rest % KS;
    int nt = (rest / KS) % NT;
    int k = rest / (KS * NT);
    int co = nt * 32 + (lane & 31);
    int ci0 = ks * 16 + (lane >> 5) * 8;
    float s = g[co] * rsqrtf(v[co] + 1e-5f);
    union { unsigned short s_[8]; uint4 v_; } hi, lo;
    #pragma unroll
    for (int j = 0; j < 8; ++j) {
        float f = wg[((size_t)co * CI + ci0 + j) * K + k] * s;
        hi.s_[j] = f2bf(f);
        lo.s_[j] = f2bf(f - bf2f(hi.s_[j]));
    }
    size_t base = ((size_t)(k * NT + nt) * KS + ks) * 512 + lane * 8;
    *(uint4*)(Wc + base) = hi.v_;
    *(uint4*)(Wc + base + (size_t)K * NT * KS * 512) = lo.v_;
}

// ---------------------------------------------------------------------------
// Conv1 (CI=1): validated VALU version.
// ---------------------------------------------------------------------------
template<int CI, int K>
__global__ __launch_bounds__(256) void conv_bn_relu_f(
    const float* __restrict__ in, float* __restrict__ out,
    const float* __restrict__ wg, const float* __restrict__ cb,
    const float* __restrict__ g, const float* __restrict__ bb,
    const float* __restrict__ m, const float* __restrict__ v, int CO)
{
    const int wv = threadIdx.x >> 6, lane = threadIdx.x & 63;
    const int b = blockIdx.z;
    const int co0 = __builtin_amdgcn_readfirstlane(blockIdx.y * 32 + wv * 8);
    const int l = blockIdx.x * 256 + lane * 4;
    const int OFF = K / 2;
    float acc[8][4] = {};
    const float* inb = in + (size_t)b * CI * L_SEQ;
    for (int ci = 0; ci < CI; ++ci) {
        const float* row = inb + (size_t)ci * L_SEQ;
        float win[12];
        #pragma unroll
        for (int d = 0; d < 12; ++d) {
            int li = l - 4 + d;
            win[d] = (li >= 0 && li < L_SEQ) ? row[li] : 0.f;
        }
        #pragma unroll
        for (int cc = 0; cc < 8; ++cc) {
            #pragma unroll
            for (int k = 0; k < K; ++k) {
                float wk = wg[((size_t)(co0 + cc) * CI + ci) * K + k];
                #pragma unroll
                for (int j = 0; j < 4; ++j)
                    acc[cc][j] = fmaf(win[4 + j + k - OFF], wk, acc[cc][j]);
            }
        }
    }
    #pragma unroll
    for (int cc = 0; cc < 8; ++cc) {
        int co = co0 + cc;
        float s = g[co] * rsqrtf(v[co] + 1e-5f);
        float sh = (cb[co] - m[co]) * s + bb[co];
        float* orow = out + ((size_t)b * CO + co) * LPAD + 4;
        float4 o4;
        o4.x = fmaxf(fmaf(acc[cc][0], s, sh), 0.f);
        o4.y = fmaxf(fmaf(acc[cc][1], s, sh), 0.f);
        o4.z = fmaxf(fmaf(acc[cc][2], s, sh), 0.f);
        o4.w = fmaxf(fmaf(acc[cc][3], s, sh), 0.f);
        *(float4*)(orow + l) = o4;
        if (blockIdx.x == 0 && lane == 0)
            *(float4*)(orow - 4) = make_float4(0.f, 0.f, 0.f, 0.f);
        if (blockIdx.x == gridDim.x - 1 && lane == 63)
            *(float4*)(orow + L_SEQ) = make_float4(0.f, 0.f, 0.f, 0.f);
    }
}

// ---------------------------------------------------------------------------
// Conv via MFMA implicit GEMM (validated round-6 version).
// ---------------------------------------------------------------------------
template<int CI, int K, int CO, bool POUT>
__global__ __launch_bounds__(256) void conv_mfma(
    const float* __restrict__ in, float* __restrict__ out,
    const unsigned short* __restrict__ Wc, const float* __restrict__ Bs)
{
    constexpr int NT = CO / 32, KS = CI / 16, OBS = NT / 4, OFF = K / 2;
    constexpr int PLSZ = K * NT * KS * 512;
    __shared__ __align__(16) unsigned short A0[40 * CI];
    __shared__ __align__(16) unsigned short A1[40 * CI];
    __shared__ float vt[32][CO + 4];
    const int b = blockIdx.y, l0 = blockIdx.x * 32;
    const int wv = threadIdx.x >> 6, lane = threadIdx.x & 63;
    const float* inb = in + (size_t)b * CI * LPAD + l0;
    for (int e = threadIdx.x; e < CI * 10; e += 256) {
        int ci = e / 10, f4 = e - ci * 10;
        float4 q = *(const float4*)(inb + (size_t)ci * LPAD + f4 * 4);
        #pragma unroll
        for (int j = 0; j < 4; ++j) {
            int row = f4 * 4 + j;
            int bo = ((row * CI + ci) * 2) ^ ((row & 7) << 4);
            float f = (&q.x)[j];
            unsigned short h = f2bf(f);
            *(unsigned short*)((char*)A0 + bo) = h;
            *(unsigned short*)((char*)A1 + bo) = f2bf(f - bf2f(h));
        }
    }
    __syncthreads();
    f32x16 acc0 = {}, acc1 = {};
    #pragma unroll
    for (int k = 0; k < K; ++k) {
        #pragma unroll
        for (int ks = 0; ks < KS; ++ks) {
            int row = (lane & 31) + 4 + k - OFF;
            int abyte = ((row * CI + ks * 16 + (lane >> 5) * 8) * 2) ^ ((row & 7) << 4);
            short8v ah = *(const short8v*)((const char*)A0 + abyte);
            short8v al = *(const short8v*)((const char*)A1 + abyte);
            {
                const unsigned short* wb = Wc + ((size_t)(k * NT + wv * OBS) * KS + ks) * 512 + lane * 8;
                short8v bh = *(const short8v*)wb;
                short8v bl = *(const short8v*)(wb + PLSZ);
                acc0 = MFMA32(ah, bh, acc0);
                acc0 = MFMA32(ah, bl, acc0);
                acc0 = MFMA32(al, bh, acc0);
            }
            if constexpr (OBS == 2) {
                const unsigned short* wb = Wc + ((size_t)(k * NT + wv * OBS + 1) * KS + ks) * 512 + lane * 8;
                short8v bh = *(const short8v*)wb;
                short8v bl = *(const short8v*)(wb + PLSZ);
                acc1 = MFMA32(ah, bh, acc1);
                acc1 = MFMA32(ah, bl, acc1);
                acc1 = MFMA32(al, bh, acc1);
            }
        }
    }
    {
        int co = (wv * OBS) * 32 + (lane & 31);
        float bs = Bs[co];
        #pragma unroll
        for (int r = 0; r < 16; ++r) {
            int lr = (r & 3) + 8 * (r >> 2) + 4 * (lane >> 5);
            vt[lr][co] = fmaxf(acc0[r] + bs, 0.f);
        }
        if constexpr (OBS == 2) {
            int co1 = co + 32;
            float bs1 = Bs[co1];
            #pragma unroll
            for (int r = 0; r < 16; ++r) {
                int lr = (r & 3) + 8 * (r >> 2) + 4 * (lane >> 5);
                vt[lr][co1] = fmaxf(acc1[r] + bs1, 0.f);
            }
        }
    }
    __syncthreads();
    if constexpr (CO == 256) {
        float* orow = out + ((size_t)b * CO + threadIdx.x) * (POUT ? LPAD : L_SEQ)
                      + (POUT ? 4 : 0) + l0;
        #pragma unroll
        for (int u4 = 0; u4 < 8; ++u4) {
            float4 o;
            o.x = vt[u4 * 4 + 0][threadIdx.x];
            o.y = vt[u4 * 4 + 1][threadIdx.x];
            o.z = vt[u4 * 4 + 2][threadIdx.x];
            o.w = vt[u4 * 4 + 3][threadIdx.x];
            *(float4*)(orow + u4 * 4) = o;
        }
    } else {
        int co = threadIdx.x & 127, lh = threadIdx.x >> 7;
        float* rowb = out + ((size_t)b * CO + co) * LPAD;
        float* orow = rowb + 4 + l0 + lh * 16;
        #pragma unroll
        for (int u4 = 0; u4 < 4; ++u4) {
            float4 o;
            o.x = vt[lh * 16 + u4 * 4 + 0][co];
            o.y = vt[lh * 16 + u4 * 4 + 1][co];
            o.z = vt[lh * 16 + u4 * 4 + 2][co];
            o.w = vt[lh * 16 + u4 * 4 + 3][co];
            *(float4*)(orow + u4 * 4) = o;
        }
        if (blockIdx.x == 0 && lh == 0)
            *(float4*)(rowb) = make_float4(0.f, 0.f, 0.f, 0.f);
        if (blockIdx.x == gridDim.x - 1 && lh == 1)
            *(float4*)(rowb + 4 + L_SEQ) = make_float4(0.f, 0.f, 0.f, 0.f);
    }
}

// ---------------------------------------------------------------------------
// Fused S4D core: S = u x V  ->  prefix(P)  ->  y = P x E + u x T  -> GELU.
// Block = (h, 4 b); wave = one b; everything wave-private (no __syncthreads).
// A-frags read directly from fp32 u with in-register bf16 hi/lo conversion.
// LDS: per-wave 16 KB prefix-transpose tile, XOR-swizzled (conflict-free).
// ---------------------------------------------------------------------------
__global__ __launch_bounds__(256) void s4d_fused(
    const float* __restrict__ u,             // [B][256][L] fp32
    const unsigned short* __restrict__ Vpk,
    const unsigned short* __restrict__ Epk,
    const unsigned short* __restrict__ Tpk,
    const float* __restrict__ wqbuf,
    unsigned short* __restrict__ ybf)        // [B][H][L] bf16
{
    __shared__ float Sl[4][4096];
    const int h = blockIdx.x;
    const int wv = threadIdx.x >> 6, lane = threadIdx.x & 63;
    const int b = blockIdx.y * 4 + wv;
    const float* urow = u + ((size_t)b * H_DIM + h) * L_SEQ;
    const int c = lane & 31;           // A-frag row (chunk)
    const int khalf = (lane >> 5) * 8; // A-frag k sub-offset
    float* Sw = Sl[wv];

    f32x16 acc0 = {}, acc1 = {}, acc2 = {}, acc3 = {};
    // ---- phase A: S = u x V
    {
        const unsigned short* Vh = Vpk + h * 32768;
        #pragma unroll
        for (int ks = 0; ks < 8; ++ks) {
            const float* up = urow + c * 128 + ks * 16 + khalf;
            short8v ah, al;
            cvt8(*(const float4*)up, *(const float4*)(up + 4), ah, al);
            const unsigned short* vb = Vh + ks * 512 + lane * 8;
            short8v b0h = *(const short8v*)(vb);
            short8v b1h = *(const short8v*)(vb + 4096);
            short8v b2h = *(const short8v*)(vb + 8192);
            short8v b3h = *(const short8v*)(vb + 12288);
            short8v b0l = *(const short8v*)(vb + 16384);
            short8v b1l = *(const short8v*)(vb + 20480);
            short8v b2l = *(const short8v*)(vb + 24576);
            short8v b3l = *(const short8v*)(vb + 28672);
            acc0 = MFMA32(ah, b0h, acc0);
            acc1 = MFMA32(ah, b1h, acc1);
            acc2 = MFMA32(ah, b2h, acc2);
            acc3 = MFMA32(ah, b3h, acc3);
            acc0 = MFMA32(ah, b0l, acc0);
            acc1 = MFMA32(ah, b1l, acc1);
            acc2 = MFMA32(ah, b2l, acc2);
            acc3 = MFMA32(ah, b3l, acc3);
            acc0 = MFMA32(al, b0h, acc0);
            acc1 = MFMA32(al, b1h, acc1);
            acc2 = MFMA32(al, b2h, acc2);
            acc3 = MFMA32(al, b3h, acc3);
        }
    }
    // ---- phase B: scatter C-frags to Sl (XOR-swizzled), serial prefix
    #pragma unroll
    for (int nt = 0; nt < 4; ++nt) {
        const f32x16& a = nt == 0 ? acc0 : nt == 1 ? acc1 : nt == 2 ? acc2 : acc3;
        int col = nt * 32 + (lane & 31);
        #pragma unroll
        for (int r = 0; r < 16; ++r) {
            int cc = (r & 3) + 8 * (r >> 2) + 4 * (lane >> 5);
            Sw[cc * 128 + (col ^ ((cc & 7) << 2))] = a[r];
        }
    }
    {
        const float2 wq = *(const float2*)(wqbuf + ((size_t)h * 64 + lane) * 2);
        float Pr = 0.f, Pi = 0.f;
        for (int cc = 0; cc < NCHUNK; ++cc) {
            int idx = cc * 128 + ((2 * lane) ^ ((cc & 7) << 2));
            float2 s = *(const float2*)(Sw + idx);
            *(float2*)(Sw + idx) = make_float2(Pr, Pi);
            float npr = fmaf(wq.x, Pr, fmaf(-wq.y, Pi, s.x));
            float npi = fmaf(wq.x, Pi, fmaf(wq.y, Pr, s.y));
            Pr = npr; Pi = npi;
        }
    }
    // ---- phase C: y = P x E
    acc0 = (f32x16){}; acc1 = (f32x16){}; acc2 = (f32x16){}; acc3 = (f32x16){};
    {
        const unsigned short* Eh = Epk + h * 32768;
        const int m2 = (c & 7) << 2;
        #pragma unroll
        for (int ks = 0; ks < 8; ++ks) {
            int g = ks * 16 + khalf;
            float4 p0 = *(const float4*)(Sw + c * 128 + ((g) ^ m2));
            float4 p1 = *(const float4*)(Sw + c * 128 + ((g + 4) ^ m2));
            short8v ah, al;
            cvt8(p0, p1, ah, al);
            const unsigned short* eb = Eh + ks * 512 + lane * 8;
            short8v b0h = *(const short8v*)(eb);
            short8v b1h = *(const short8v*)(eb + 4096);
            short8v b2h = *(const short8v*)(eb + 8192);
            short8v b3h = *(const short8v*)(eb + 12288);
            short8v b0l = *(const short8v*)(eb + 16384);
            short8v b1l = *(const short8v*)(eb + 20480);
            short8v b2l = *(const short8v*)(eb + 24576);
            short8v b3l = *(const short8v*)(eb + 28672);
            acc0 = MFMA32(ah, b0h, acc0);
            acc1 = MFMA32(ah, b1h, acc1);
            acc2 = MFMA32(ah, b2h, acc2);
            acc3 = MFMA32(ah, b3h, acc3);
            acc0 = MFMA32(ah, b0l, acc0);
            acc1 = MFMA32(ah, b1l, acc1);
            acc2 = MFMA32(ah, b2l, acc2);
            acc3 = MFMA32(ah, b3l, acc3);
            acc0 = MFMA32(al, b0h, acc0);
            acc1 = MFMA32(al, b1h, acc1);
            acc2 = MFMA32(al, b2h, acc2);
            acc3 = MFMA32(al, b3h, acc3);
        }
    }
    // ---- phase D: y += u x T
    {
        const unsigned short* Th = Tpk + h * 32768;
        #pragma unroll
        for (int ks = 0; ks < 8; ++ks) {
            const float* up = urow + c * 128 + ks * 16 + khalf;
            short8v ah, al;
            cvt8(*(const float4*)up, *(const float4*)(up + 4), ah, al);
            const unsigned short* tb = Th + ks * 512 + lane * 8;
            short8v b0h = *(const short8v*)(tb);
            short8v b1h = *(const short8v*)(tb + 4096);
            short8v b2h = *(const short8v*)(tb + 8192);
            short8v b3h = *(const short8v*)(tb + 12288);
            short8v b0l = *(const short8v*)(tb + 16384);
            short8v b1l = *(const short8v*)(tb + 20480);
            short8v b2l = *(const short8v*)(tb + 24576);
            short8v b3l = *(const short8v*)(tb + 28672);
            acc0 = MFMA32(ah, b0h, acc0);
            acc1 = MFMA32(ah, b1h, acc1);
            acc2 = MFMA32(ah, b2h, acc2);
            acc3 = MFMA32(ah, b3h, acc3);
            acc0 = MFMA32(ah, b0l, acc0);
            acc1 = MFMA32(ah, b1l, acc1);
            acc2 = MFMA32(ah, b2l, acc2);
            acc3 = MFMA32(ah, b3l, acc3);
            acc0 = MFMA32(al, b0h, acc0);
            acc1 = MFMA32(al, b1h, acc1);
            acc2 = MFMA32(al, b2h, acc2);
            acc3 = MFMA32(al, b3h, acc3);
        }
    }
    // ---- epilogue: GELU -> bf16 store
    unsigned short* yrow = ybf + ((size_t)b * H_DIM + h) * L_SEQ;
    #pragma unroll
    for (int nt = 0; nt < 4; ++nt) {
        const f32x16& a = nt == 0 ? acc0 : nt == 1 ? acc1 : nt == 2 ? acc2 : acc3;
        int t = nt * 32 + (lane & 31);
        #pragma unroll
        for (int r = 0; r < 16; ++r) {
            int cc = (r & 3) + 8 * (r >> 2) + 4 * (lane >> 5);
            float yv = a[r];
            float yc = fmaf(0.044715f * yv, yv * yv, yv);
            float tg = tanhf(0.79788456f * yc);
            float outv = 0.5f * yv * (1.f + tg);
            yrow[cc * QCH + t] = f2bf(outv);
        }
    }
}

// ---------------------------------------------------------------------------
// W -> packed MFMA B-fragment order (GLU linear).
// ---------------------------------------------------------------------------
__global__ __launch_bounds__(256) void precompute_wpk(
    const float* __restrict__ W, unsigned short* __restrict__ Wpk)
{
    int t = blockIdx.x * 256 + threadIdx.x;
    if (t >= 4 * 16 * 16 * 64) return;
    int lane = t & 63;
    int kk = (t >> 6) & 15;
    int ob = (t >> 10) & 15;
    int layer = t >> 14;
    int o = ob * 32 + (lane & 31);
    int k0 = kk * 16 + (lane >> 5) * 8;
    const float* src = W + ((size_t)layer * 512 + o) * H_DIM + k0;
    union { unsigned short s[8]; uint4 v; } hi, lo;
    #pragma unroll
    for (int j = 0; j < 8; ++j) {
        float f = src[j];
        hi.s[j] = f2bf(f);
        lo.s[j] = f2bf(f - bf2f(hi.s[j]));
    }
    size_t base = (size_t)layer * 262144 + ((size_t)((ob * 16 + kk) * 64 + lane) * 8);
    *(uint4*)(Wpk + base) = hi.v;
    *(uint4*)(Wpk + base + 131072) = lo.v;
}

// ---------------------------------------------------------------------------
// Output linear (H->2H) MFMA + GLU + residual + LayerNorm, fused (validated).
// ---------------------------------------------------------------------------
__global__ __launch_bounds__(256) void linear_glu_ln(
    const unsigned short* __restrict__ ybf,
    const unsigned short* __restrict__ Wpk,
    const float* __restrict__ bias,
    const float* __restrict__ lg, const float* __restrict__ lb,
    float* __restrict__ xhl)
{
    __shared__ __align__(16) unsigned short As[32 * 256];
    __shared__ float vt[32][260];
    const int lane = threadIdx.x & 63;
    const int wv = threadIdx.x >> 6;
    const int b = blockIdx.y;
    const int l0 = blockIdx.x * 32;

    const unsigned short* ybase = ybf + (size_t)b * H_DIM * L_SEQ + l0;
    #pragma unroll
    for (int p = 0; p < 4; ++p) {
        int e = threadIdx.x + p * 256;
        int hh = e >> 2, c4 = e & 3;
        union { uint4 v; unsigned short s[8]; } qv;
        qv.v = *(const uint4*)(ybase + (size_t)hh * L_SEQ + c4 * 8);
        #pragma unroll
        for (int j = 0; j < 8; ++j) {
            int lloc = c4 * 8 + j;
            int byteoff = (lloc << 9) + hh * 2;
            byteoff ^= ((lloc & 7) << 4);
            *(unsigned short*)((char*)As + byteoff) = qv.s[j];
        }
    }
    __syncthreads();

    const int ob0 = 2 * wv, ob1 = 2 * wv + 1;
    const int r = lane & 31;
    f32x16 acc0 = {}, acc1 = {}, acc2 = {}, acc3 = {};
    #pragma unroll 4
    for (int kk = 0; kk < 16; ++kk) {
        int abyte = (r << 9) | (kk * 32 + (lane >> 5) * 16);
        abyte ^= ((r & 7) << 4);
        short8v a = *(const short8v*)((char*)As + abyte);
        const unsigned short* w0 = Wpk + (((ob0 * 16 + kk) * 64 + lane) * 8);
        const unsigned short* w1 = Wpk + (((ob1 * 16 + kk) * 64 + lane) * 8);
        const unsigned short* w2 = Wpk + ((((ob0 + 8) * 16 + kk) * 64 + lane) * 8);
        const unsigned short* w3 = Wpk + ((((ob1 + 8) * 16 + kk) * 64 + lane) * 8);
        short8v h0 = *(const short8v*)w0;
        short8v h1 = *(const short8v*)w1;
        short8v h2 = *(const short8v*)w2;
        short8v h3 = *(const short8v*)w3;
        short8v e0 = *(const short8v*)(w0 + 131072);
        short8v e1 = *(const short8v*)(w1 + 131072);
        short8v e2 = *(const short8v*)(w2 + 131072);
        short8v e3 = *(const short8v*)(w3 + 131072);
        acc0 = MFMA32(a, h0, acc0);
        acc1 = MFMA32(a, h1, acc1);
        acc2 = MFMA32(a, h2, acc2);
        acc3 = MFMA32(a, h3, acc3);
        acc0 = MFMA32(a, e0, acc0);
        acc1 = MFMA32(a, e1, acc1);
        acc2 = MFMA32(a, e2, acc2);
        acc3 = MFMA32(a, e3, acc3);
    }
    #pragma unroll
    for (int p = 0; p < 2; ++p) {
        const f32x16& z1v = p ? acc1 : acc0;
        const f32x16& z2v = p ? acc3 : acc2;
        int o = (p ? ob1 : ob0) * 32 + (lane & 31);
        float b1 = bias[o], b2 = bias[o + 256];
        #pragma unroll
        for (int rr = 0; rr < 16; ++rr) {
            int lloc = (rr & 3) + 8 * (rr >> 2) + 4 * (lane >> 5);
            float z1 = z1v[rr] + b1;
            float z2 = z2v[rr] + b2;
            vt[lloc][o] = z1 / (1.f + expf(-z2));
        }
    }
    __syncthreads();
    {
        const float* xr = xhl + ((size_t)b * H_DIM + threadIdx.x) * L_SEQ + l0;
        #pragma unroll
        for (int u4 = 0; u4 < 8; ++u4) {
            float4 q = *(const float4*)(xr + u4 * 4);
            vt[u4 * 4 + 0][threadIdx.x] += q.x;
            vt[u4 * 4 + 1][threadIdx.x] += q.y;
            vt[u4 * 4 + 2][threadIdx.x] += q.z;
            vt[u4 * 4 + 3][threadIdx.x] += q.w;
        }
    }
    __syncthreads();
    {
        float4 g4 = *(const float4*)(lg + lane * 4);
        float4 b4 = *(const float4*)(lb + lane * 4);
        #pragma unroll
        for (int rr = 0; rr < 8; ++rr) {
            int row = rr * 4 + wv;
            float4 xv = *(const float4*)&vt[row][lane * 4];
            float s = xv.x + xv.y + xv.z + xv.w;
            float sq = xv.x * xv.x + xv.y * xv.y + xv.z * xv.z + xv.w * xv.w;
            #pragma unroll
            for (int st = 1; st < 64; st <<= 1) {
                s += __shfl_xor(s, st);
                sq += __shfl_xor(sq, st);
            }
            float mean = s * (1.f / H_DIM);
            float var = sq * (1.f / H_DIM) - mean * mean;
            float rstd = rsqrtf(var + 1e-5f);
            float4 o;
            o.x = (xv.x - mean) * rstd * g4.x + b4.x;
            o.y = (xv.y - mean) * rstd * g4.y + b4.y;
            o.z = (xv.z - mean) * rstd * g4.z + b4.z;
            o.w = (xv.w - mean) * rstd * g4.w + b4.w;
            *(float4*)&vt[row][lane * 4] = o;
        }
    }
    __syncthreads();
    {
        float* dst = xhl + ((size_t)b * H_DIM + threadIdx.x) * L_SEQ + l0;
        #pragma unroll
        for (int u4 = 0; u4 < 8; ++u4) {
            float4 o;
            o.x = vt[u4 * 4 + 0][threadIdx.x];
            o.y = vt[u4 * 4 + 1][threadIdx.x];
            o.z = vt[u4 * 4 + 2][threadIdx.x];
            o.w = vt[u4 * 4 + 3][threadIdx.x];
            *(float4*)(dst + u4 * 4) = o;
        }
    }
}

// ---------------------------------------------------------------------------
__global__ __launch_bounds__(256) void pool_mean(
    const float* __restrict__ x, float* __restrict__ meanb)
{
    __shared__ float red[256];
    const int bh = blockIdx.x;
    const float* row = x + (size_t)bh * L_SEQ;
    float s = 0.f;
    for (int i = threadIdx.x; i < L_SEQ; i += 256) s += row[i];
    red[threadIdx.x] = s;
    __syncthreads();
    for (int st = 128; st > 0; st >>= 1) {
        if (threadIdx.x < st) red[threadIdx.x] += red[threadIdx.x + st];
        __syncthreads();
    }
    if (threadIdx.x == 0) meanb[bh] = red[0] * (1.f / L_SEQ);
}

__global__ __launch_bounds__(256) void decode(
    const float* __restrict__ meanb, const float* __restrict__ dw,
    const float* __restrict__ db, float* __restrict__ out)
{
    int i = threadIdx.x;
    if (i >= BATCH * 10) return;
    int b = i / 10, d = i % 10;
    float s = db[d];
    for (int h = 0; h < H_DIM; ++h)
        s = fmaf(meanb[b * H_DIM + h], dw[d * H_DIM + h], s);
    out[i] = s;
}

// ---------------------------------------------------------------------------
extern "C" void kernel_launch(void* const* d_in, const int* in_sizes, int n_in,
                              void* d_out, int out_size, void* d_ws, size_t ws_size,
                              hipStream_t stream)
{
    const float* x_in = (const float*)d_in[0];
    const float* cw[3] = {(const float*)d_in[1], (const float*)d_in[7],  (const float*)d_in[13]};
    const float* cb[3] = {(const float*)d_in[2], (const float*)d_in[8],  (const float*)d_in[14]};
    const float* bg[3] = {(const float*)d_in[3], (const float*)d_in[9],  (const float*)d_in[15]};
    const float* bb[3] = {(const float*)d_in[4], (const float*)d_in[10], (const float*)d_in[16]};
    const float* bm[3] = {(const float*)d_in[5], (const float*)d_in[11], (const float*)d_in[17]};
    const float* bv[3] = {(const float*)d_in[6], (const float*)d_in[12], (const float*)d_in[18]};
    const float* log_dt   = (const float*)d_in[19];
    const float* A_re_log = (const float*)d_in[20];
    const float* A_im     = (const float*)d_in[21];
    const float* C_re     = (const float*)d_in[22];
    const float* C_im     = (const float*)d_in[23];
    const float* Dv       = (const float*)d_in[24];
    const float* out_w    = (const float*)d_in[25];
    const float* out_b    = (const float*)d_in[26];
    const float* ln_g     = (const float*)d_in[27];
    const float* ln_b     = (const float*)d_in[28];
    const float* dec_w    = (const float*)d_in[29];
    const float* dec_b    = (const float*)d_in[30];

    const size_t PLANE = (size_t)BATCH * H_DIM * L_SEQ;       // 16,777,216 floats
    float* ws = (float*)d_ws;
    float* xhl = ws;                                          // [B][256][L] fp32
    float* X   = ws + PLANE;            // conv temps -> per-layer matrices
    unsigned short* ybf = (unsigned short*)(ws + 2 * PLANE);  // [B][H][L] bf16
    float* tail = ws + 2 * PLANE + PLANE / 2;
    unsigned short* Wpk = (unsigned short*)tail;              // 1,048,576 us
    float* Ktab  = tail + 524288;
    float* wqbuf = Ktab + 32768;
    float* meanb = wqbuf + 32768;
    unsigned short* Wc2 = (unsigned short*)(meanb + 4096);
    float* Bs2 = (float*)(Wc2 + 81920);
    unsigned short* Wc3 = (unsigned short*)(Bs2 + 128);
    float* Bs3 = (float*)(Wc3 + 196608);

    unsigned short* X_us = (unsigned short*)X;
    unsigned short* Vpk = X_us;
    unsigned short* Epk = X_us + 8388608;
    unsigned short* Tpk = X_us + 16777216;

    precompute_wpk<<<256, 256, 0, stream>>>(out_w, Wpk);
    pack_conv<64, 5, 128><<<20, 256, 0, stream>>>(cw[1], bg[1], bv[1], cb[1], bm[1], bb[1], Wc2, Bs2);
    pack_conv<128, 3, 256><<<48, 256, 0, stream>>>(cw[2], bg[2], bv[2], cb[2], bm[2], bb[2], Wc3, Bs3);

    // Encoder: x_in -> c1p (padded) -> c2p (padded) -> xhl
    float* c1p = X;
    float* c2p = X + (size_t)BATCH * 64 * LPAD;
    conv_bn_relu_f<1, 7><<<dim3(16, 2, 16), 256, 0, stream>>>(
        x_in, c1p, cw[0], cb[0], bg[0], bb[0], bm[0], bv[0], 64);
    conv_mfma<64, 5, 128, true><<<dim3(128, 16), 256, 0, stream>>>(c1p, c2p, Wc2, Bs2);
    conv_mfma<128, 3, 256, false><<<dim3(128, 16), 256, 0, stream>>>(c2p, xhl, Wc3, Bs3);

    for (int l = 0; l < 4; ++l) {
        mats_gen<<<64, 256, 0, stream>>>(log_dt, A_re_log, A_im, C_re, C_im, Dv, l,
                                         Vpk, Epk, Ktab, wqbuf);
        tfill<<<2048, 256, 0, stream>>>(Ktab, Tpk);
        s4d_fused<<<dim3(256, 4), 256, 0, stream>>>(xhl, Vpk, Epk, Tpk, wqbuf, ybf);
        linear_glu_ln<<<dim3(128, 16), 256, 0, stream>>>(
            ybf, Wpk + (size_t)l * 262144, out_b + l * 512,
            ln_g + l * H_DIM, ln_b + l * H_DIM, xhl);
    }

    pool_mean<<<dim3(BATCH * H_DIM), 256, 0, stream>>>(xhl, meanb);
    decode<<<dim3(1), 256, 0, stream>>>(meanb, dec_w, dec_b, (float*)d_out);
}